// Round 1
// baseline (2141.020 us; speedup 1.0000x reference)
//
#include <hip/hip_runtime.h>
#include <math.h>

constexpr int B = 2, L = 2048, D = 1024, H = 16, DH = 64, FFD = 4096;
constexpr int S = 40;   // sample_k
constexpr int U = 40;   // n_top
constexpr float EPS = 1e-5f;
constexpr int NCHUNK = 16;
constexpr int CHLEN = L / NCHUNK;   // 128

// ---------------- fp32 tiled GEMM: C = act(A[M,K] @ W[K,N] + bias) ----------
template<bool RELU>
__global__ __launch_bounds__(256) void gemm_bias_kernel(
    const float* __restrict__ A, const float* __restrict__ W,
    const float* __restrict__ bias, float* __restrict__ C,
    int M, int N, int K) {
  constexpr int BM = 128, BN = 128, BK = 16;
  __shared__ float As[BK][BM];   // As[k][m]
  __shared__ float Bs[BK][BN];   // Bs[k][n]
  const int tid = threadIdx.x;
  const int bm = blockIdx.y * BM;
  const int bn = blockIdx.x * BN;
  const int tx = tid & 15, ty = tid >> 4;
  const int m0 = ty * 8, n0 = tx * 8;
  float acc[8][8] = {};

  const int ar = tid >> 1;            // 0..127
  const int ac = (tid & 1) * 8;       // 0 or 8
  const int br = tid >> 4;            // 0..15
  const int bc = (tid & 15) * 8;      // 0..120

  for (int k0 = 0; k0 < K; k0 += BK) {
    const float* ap = A + (size_t)(bm + ar) * K + k0 + ac;
    float4 a0 = *(const float4*)(ap);
    float4 a1 = *(const float4*)(ap + 4);
    const float* bp = W + (size_t)(k0 + br) * N + bn + bc;
    float4 b0 = *(const float4*)(bp);
    float4 b1 = *(const float4*)(bp + 4);
    As[ac+0][ar]=a0.x; As[ac+1][ar]=a0.y; As[ac+2][ar]=a0.z; As[ac+3][ar]=a0.w;
    As[ac+4][ar]=a1.x; As[ac+5][ar]=a1.y; As[ac+6][ar]=a1.z; As[ac+7][ar]=a1.w;
    *(float4*)&Bs[br][bc]   = b0;
    *(float4*)&Bs[br][bc+4] = b1;
    __syncthreads();
    #pragma unroll
    for (int k = 0; k < BK; ++k) {
      float av[8], bv[8];
      *(float4*)&av[0] = *(const float4*)&As[k][m0];
      *(float4*)&av[4] = *(const float4*)&As[k][m0+4];
      *(float4*)&bv[0] = *(const float4*)&Bs[k][n0];
      *(float4*)&bv[4] = *(const float4*)&Bs[k][n0+4];
      #pragma unroll
      for (int i = 0; i < 8; ++i)
        #pragma unroll
        for (int j = 0; j < 8; ++j)
          acc[i][j] = fmaf(av[i], bv[j], acc[i][j]);
    }
    __syncthreads();
  }
  float bv8[8];
  *(float4*)&bv8[0] = *(const float4*)(bias + bn + n0);
  *(float4*)&bv8[4] = *(const float4*)(bias + bn + n0 + 4);
  #pragma unroll
  for (int i = 0; i < 8; ++i) {
    float vals[8];
    #pragma unroll
    for (int j = 0; j < 8; ++j) {
      float v = acc[i][j] + bv8[j];
      if (RELU) v = fmaxf(v, 0.f);
      vals[j] = v;
    }
    float* crow = C + (size_t)(bm + m0 + i) * N + bn + n0;
    *(float4*)crow     = *(float4*)&vals[0];
    *(float4*)(crow+4) = *(float4*)&vals[4];
  }
}

// ------------- M[b,h,l] = max_s(Q[l]·K[idx[l,s]]) - sum_s(...)/L ------------
__global__ __launch_bounds__(256) void prob_m_kernel(
    const float* __restrict__ Q, const float* __restrict__ K_,
    const int* __restrict__ idx, float* __restrict__ M_) {
  const int bl = blockIdx.x;           // b*L + l
  const int b = bl / L, l = bl % L;
  const int tid = threadIdx.x;
  __shared__ float dots[H][S];
  __shared__ int sidx[S];
  if (tid < S) sidx[tid] = idx[l * S + tid];
  __syncthreads();
  const int h = tid >> 4;              // 0..15
  const int dsub = (tid & 15) * 4;     // 0..60
  float4 q = *(const float4*)(Q + (size_t)bl * D + h * DH + dsub);
  for (int s = 0; s < S; ++s) {
    const float4 kv = *(const float4*)(K_ + ((size_t)b * L + sidx[s]) * D + h * DH + dsub);
    float p = q.x*kv.x + q.y*kv.y + q.z*kv.z + q.w*kv.w;
    p += __shfl_xor(p, 1);
    p += __shfl_xor(p, 2);
    p += __shfl_xor(p, 4);
    p += __shfl_xor(p, 8);
    if ((tid & 15) == 0) dots[h][s] = p;
  }
  __syncthreads();
  if (tid < H) {
    float mx = -INFINITY, sm = 0.f;
    for (int s = 0; s < S; ++s) { float v = dots[tid][s]; mx = fmaxf(mx, v); sm += v; }
    M_[((size_t)b * H + tid) * L + l] = mx - sm / (float)L;
  }
}

// ------------------------- exact top-k (k=40, n=2048) -----------------------
__global__ __launch_bounds__(256) void topk_kernel(
    const float* __restrict__ M_, int* __restrict__ Mtop) {
  const int bh = blockIdx.x;
  const float* row = M_ + (size_t)bh * L;
  __shared__ float vals[L];
  __shared__ float rv[256];
  __shared__ int   ri[256];
  const int tid = threadIdx.x;
  for (int i = tid; i < L; i += 256) vals[i] = row[i];
  __syncthreads();
  for (int u = 0; u < U; ++u) {
    float best = -INFINITY; int bi = 0x7fffffff;
    for (int i = tid; i < L; i += 256) {
      float v = vals[i];
      if (v > best || (v == best && i < bi)) { best = v; bi = i; }
    }
    rv[tid] = best; ri[tid] = bi;
    __syncthreads();
    for (int off = 128; off > 0; off >>= 1) {
      if (tid < off) {
        float v2 = rv[tid+off]; int i2 = ri[tid+off];
        if (v2 > rv[tid] || (v2 == rv[tid] && i2 < ri[tid])) { rv[tid]=v2; ri[tid]=i2; }
      }
      __syncthreads();
    }
    if (tid == 0) { Mtop[bh * U + u] = ri[0]; vals[ri[0]] = -INFINITY; }
    __syncthreads();
  }
}

// -------- per (b,h,u): scores -> masked softmax -> upd = attn @ V -----------
__global__ __launch_bounds__(256) void attn_upd_kernel(
    const float* __restrict__ Q, const float* __restrict__ K_,
    const float* __restrict__ V, const int* __restrict__ Mtop,
    float* __restrict__ upd) {
  const int bid = blockIdx.x;          // (b*H + h)*U + u
  const int u = bid % U, bh = bid / U;
  const int h = bh % H, b = bh / H;
  const int tid = threadIdx.x;
  const int mtop = Mtop[bh * U + u];
  __shared__ float qs[DH];
  __shared__ float w[L];
  __shared__ float red[256];
  __shared__ float part[4][DH];
  if (tid < DH) qs[tid] = Q[((size_t)b * L + mtop) * D + h * DH + tid];
  __syncthreads();
  const int jgrp = tid >> 4;           // 0..15
  const int dsub = (tid & 15) * 4;
  const float4 q4 = *(const float4*)&qs[dsub];
  const float scale = 0.125f;          // 1/sqrt(64)
  for (int j0 = 0; j0 < L; j0 += 16) {
    const int j = j0 + jgrp;
    const float4 kv = *(const float4*)(K_ + ((size_t)b * L + j) * D + h * DH + dsub);
    float p = q4.x*kv.x + q4.y*kv.y + q4.z*kv.z + q4.w*kv.w;
    p += __shfl_xor(p, 1);
    p += __shfl_xor(p, 2);
    p += __shfl_xor(p, 4);
    p += __shfl_xor(p, 8);
    if ((tid & 15) == 0) w[j] = (j <= mtop) ? p * scale : -INFINITY;
  }
  __syncthreads();
  float mx = -INFINITY;
  for (int i = tid; i < L; i += 256) mx = fmaxf(mx, w[i]);
  red[tid] = mx; __syncthreads();
  for (int off = 128; off > 0; off >>= 1) {
    if (tid < off) red[tid] = fmaxf(red[tid], red[tid+off]);
    __syncthreads();
  }
  mx = red[0]; __syncthreads();
  float sm = 0.f;
  for (int i = tid; i < L; i += 256) {
    float wi = w[i];
    float e = (wi == -INFINITY) ? 0.f : expf(wi - mx);
    w[i] = e; sm += e;
  }
  red[tid] = sm; __syncthreads();
  for (int off = 128; off > 0; off >>= 1) {
    if (tid < off) red[tid] += red[tid+off];
    __syncthreads();
  }
  const float inv = 1.0f / red[0];
  __syncthreads();
  const int d = tid & 63, g = tid >> 6;
  float acc = 0.f;
  for (int j = g; j < L; j += 4) acc += w[j] * V[((size_t)b * L + j) * D + h * DH + d];
  part[g][d] = acc; __syncthreads();
  if (tid < DH) {
    float r = (part[0][tid] + part[1][tid] + part[2][tid] + part[3][tid]) * inv;
    upd[((size_t)bh * U + u) * DH + tid] = r;
  }
}

// ------------------------ cumsum(V) over l, two-pass ------------------------
__global__ __launch_bounds__(256) void cumsum_pass1(
    const float* __restrict__ V, float* __restrict__ ctx, float* __restrict__ csums) {
  const int c = blockIdx.x * 256 + threadIdx.x;   // column in [0,D)
  const int ch = blockIdx.y, b = blockIdx.z;
  size_t base = ((size_t)b * L + (size_t)ch * CHLEN) * D + c;
  float acc = 0.f;
  for (int i = 0; i < CHLEN; ++i) {
    acc += V[base + (size_t)i * D];
    ctx[base + (size_t)i * D] = acc;
  }
  csums[((size_t)b * NCHUNK + ch) * D + c] = acc;
}

__global__ __launch_bounds__(256) void cumsum_pass2(
    float* __restrict__ ctx, const float* __restrict__ csums) {
  const int c = blockIdx.x * 256 + threadIdx.x;
  const int ch = blockIdx.y + 1, b = blockIdx.z;
  float off = 0.f;
  for (int j = 0; j < ch; ++j) off += csums[((size_t)b * NCHUNK + j) * D + c];
  size_t base = ((size_t)b * L + (size_t)ch * CHLEN) * D + c;
  for (int i = 0; i < CHLEN; ++i) ctx[base + (size_t)i * D] += off;
}

// ------------------- scatter: ctx[b, Mtop[u], h, :] = upd -------------------
__global__ __launch_bounds__(256) void scatter_kernel(
    float* __restrict__ ctx, const float* __restrict__ upd, const int* __restrict__ Mtop) {
  const int i = blockIdx.x * 256 + threadIdx.x;
  if (i >= B * H * U * DH) return;
  const int d = i % DH, u = (i / DH) % U, bh = i / (DH * U);
  const int h = bh % H, b = bh / H;
  const int l = Mtop[bh * U + u];
  ctx[((size_t)b * L + l) * D + h * DH + d] = upd[i];
}

// ----------------------- out = LayerNorm(a + r) * g + be --------------------
__global__ __launch_bounds__(256) void add_ln_kernel(
    const float* __restrict__ a, const float* __restrict__ r,
    const float* __restrict__ g, const float* __restrict__ be,
    float* __restrict__ out) {
  const int row = blockIdx.x;
  const int tid = threadIdx.x;
  __shared__ float buf[D];
  __shared__ float red[256];
  const float* pa = a + (size_t)row * D;
  const float* pr = r + (size_t)row * D;
  float s = 0.f;
  for (int i = tid; i < D; i += 256) { float v = pa[i] + pr[i]; buf[i] = v; s += v; }
  red[tid] = s; __syncthreads();
  for (int off = 128; off > 0; off >>= 1) {
    if (tid < off) red[tid] += red[tid+off];
    __syncthreads();
  }
  const float mu = red[0] / (float)D;
  __syncthreads();
  float s2 = 0.f;
  for (int i = tid; i < D; i += 256) { float dv = buf[i] - mu; s2 += dv * dv; }
  red[tid] = s2; __syncthreads();
  for (int off = 128; off > 0; off >>= 1) {
    if (tid < off) red[tid] += red[tid+off];
    __syncthreads();
  }
  const float rstd = rsqrtf(red[0] / (float)D + EPS);
  __syncthreads();
  float* po = out + (size_t)row * D;
  for (int i = tid; i < D; i += 256) po[i] = (buf[i] - mu) * rstd * g[i] + be[i];
}

// ----------------------------------------------------------------------------
extern "C" void kernel_launch(void* const* d_in, const int* in_sizes, int n_in,
                              void* d_out, int out_size, void* d_ws, size_t ws_size,
                              hipStream_t stream) {
  const float* x   = (const float*)d_in[0];
  const float* Wq  = (const float*)d_in[1];
  const float* bq  = (const float*)d_in[2];
  const float* Wk  = (const float*)d_in[3];
  const float* bk  = (const float*)d_in[4];
  const float* Wv  = (const float*)d_in[5];
  const float* bv  = (const float*)d_in[6];
  const float* Wo  = (const float*)d_in[7];
  const float* bo  = (const float*)d_in[8];
  const float* g1  = (const float*)d_in[9];
  const float* be1 = (const float*)d_in[10];
  const float* W1  = (const float*)d_in[11];
  const float* b1  = (const float*)d_in[12];
  const float* W2  = (const float*)d_in[13];
  const float* b2  = (const float*)d_in[14];
  const float* g2  = (const float*)d_in[15];
  const float* be2 = (const float*)d_in[16];
  const int*   idx = (const int*)d_in[17];
  float* out = (float*)d_out;

  float* ws = (float*)d_ws;
  const size_t NROW = (size_t)B * L;          // 4096
  const size_t SZ_BLD = NROW * D;             // 4,194,304
  float* Qb   = ws;
  float* Kb   = Qb + SZ_BLD;
  float* Vb   = Kb + SZ_BLD;
  float* ctxb = Vb + SZ_BLD;
  float* ff1  = ctxb + SZ_BLD;                // B*L*FF = 16,777,216
  float* Mbuf = ff1 + NROW * FFD;             // B*H*L  = 65,536
  float* csum = Mbuf + (size_t)B * H * L;     // B*NCHUNK*D = 32,768
  float* updb = csum + (size_t)B * NCHUNK * D;// B*H*U*DH = 163,840
  int*   Mtop = (int*)(updb + (size_t)B * H * U * DH);  // 1,280 ints
  // buffer reuse after attention:
  float* AO  = Qb;   // attn_out
  float* x1  = Kb;   // LN1 output
  float* ff2 = Vb;   // FF second GEMM output

  dim3 blk(256);
  const int M = B * L;   // 4096

  // Q, K, V projections (fp32 — Q/K precision required for exact top-k)
  gemm_bias_kernel<false><<<dim3(D/128, M/128), blk, 0, stream>>>(x, Wq, bq, Qb, M, D, D);
  gemm_bias_kernel<false><<<dim3(D/128, M/128), blk, 0, stream>>>(x, Wk, bk, Kb, M, D, D);
  gemm_bias_kernel<false><<<dim3(D/128, M/128), blk, 0, stream>>>(x, Wv, bv, Vb, M, D, D);

  // ProbSparse attention
  prob_m_kernel<<<B*L, blk, 0, stream>>>(Qb, Kb, idx, Mbuf);
  topk_kernel<<<B*H, blk, 0, stream>>>(Mbuf, Mtop);
  attn_upd_kernel<<<B*H*U, blk, 0, stream>>>(Qb, Kb, Vb, Mtop, updb);
  cumsum_pass1<<<dim3(D/256, NCHUNK, B), blk, 0, stream>>>(Vb, ctxb, csum);
  cumsum_pass2<<<dim3(D/256, NCHUNK-1, B), blk, 0, stream>>>(ctxb, csum);
  scatter_kernel<<<(B*H*U*DH + 255)/256, blk, 0, stream>>>(ctxb, updb, Mtop);

  // output projection + LN1
  gemm_bias_kernel<false><<<dim3(D/128, M/128), blk, 0, stream>>>(ctxb, Wo, bo, AO, M, D, D);
  add_ln_kernel<<<B*L, blk, 0, stream>>>(x, AO, g1, be1, x1);

  // FFN + LN2
  gemm_bias_kernel<true ><<<dim3(FFD/128, M/128), blk, 0, stream>>>(x1, W1, b1, ff1, M, FFD, D);
  gemm_bias_kernel<false><<<dim3(D/128,  M/128), blk, 0, stream>>>(ff1, W2, b2, ff2, M, D, FFD);
  add_ln_kernel<<<B*L, blk, 0, stream>>>(x1, ff2, g2, be2, out);
}

// Round 2
// 1117.539 us; speedup vs baseline: 1.9158x; 1.9158x over previous
//
#include <hip/hip_runtime.h>
#include <hip/hip_bf16.h>
#include <math.h>

constexpr int B = 2, L = 2048, D = 1024, H = 16, DH = 64, FFD = 4096;
constexpr int S = 40;   // sample_k
constexpr int U = 40;   // n_top
constexpr float EPS = 1e-5f;
constexpr int NCHUNK = 16;
constexpr int CHLEN = L / NCHUNK;   // 128

typedef __attribute__((ext_vector_type(8))) short short8;   // 8 bf16 (4 VGPRs)
typedef __attribute__((ext_vector_type(4))) float f32x4;

__device__ __forceinline__ unsigned short f2bf(float v) {
  __hip_bfloat16 h = __float2bfloat16(v);
  return __builtin_bit_cast(unsigned short, h);
}

__device__ __forceinline__ void gload16(const void* g, void* l) {
  __builtin_amdgcn_global_load_lds(
      (const __attribute__((address_space(1))) void*)g,
      (__attribute__((address_space(3))) void*)l, 16, 0, 0);
}

// ---------------- fp32 tiled GEMM: C = act(A[M,K] @ W[K,N] + bias) ----------
// (kept for Q/K/V projections: exact top-k + cumsum need fp32 precision)
template<bool RELU>
__global__ __launch_bounds__(256) void gemm_bias_kernel(
    const float* __restrict__ A, const float* __restrict__ W,
    const float* __restrict__ bias, float* __restrict__ C,
    int M, int N, int K) {
  constexpr int BM = 128, BN = 128, BK = 16;
  __shared__ float As[BK][BM];
  __shared__ float Bs[BK][BN];
  const int tid = threadIdx.x;
  const int bm = blockIdx.y * BM;
  const int bn = blockIdx.x * BN;
  const int tx = tid & 15, ty = tid >> 4;
  const int m0 = ty * 8, n0 = tx * 8;
  float acc[8][8] = {};

  const int ar = tid >> 1;
  const int ac = (tid & 1) * 8;
  const int br = tid >> 4;
  const int bc = (tid & 15) * 8;

  for (int k0 = 0; k0 < K; k0 += BK) {
    const float* ap = A + (size_t)(bm + ar) * K + k0 + ac;
    float4 a0 = *(const float4*)(ap);
    float4 a1 = *(const float4*)(ap + 4);
    const float* bp = W + (size_t)(k0 + br) * N + bn + bc;
    float4 b0 = *(const float4*)(bp);
    float4 b1 = *(const float4*)(bp + 4);
    As[ac+0][ar]=a0.x; As[ac+1][ar]=a0.y; As[ac+2][ar]=a0.z; As[ac+3][ar]=a0.w;
    As[ac+4][ar]=a1.x; As[ac+5][ar]=a1.y; As[ac+6][ar]=a1.z; As[ac+7][ar]=a1.w;
    *(float4*)&Bs[br][bc]   = b0;
    *(float4*)&Bs[br][bc+4] = b1;
    __syncthreads();
    #pragma unroll
    for (int k = 0; k < BK; ++k) {
      float av[8], bv[8];
      *(float4*)&av[0] = *(const float4*)&As[k][m0];
      *(float4*)&av[4] = *(const float4*)&As[k][m0+4];
      *(float4*)&bv[0] = *(const float4*)&Bs[k][n0];
      *(float4*)&bv[4] = *(const float4*)&Bs[k][n0+4];
      #pragma unroll
      for (int i = 0; i < 8; ++i)
        #pragma unroll
        for (int j = 0; j < 8; ++j)
          acc[i][j] = fmaf(av[i], bv[j], acc[i][j]);
    }
    __syncthreads();
  }
  float bv8[8];
  *(float4*)&bv8[0] = *(const float4*)(bias + bn + n0);
  *(float4*)&bv8[4] = *(const float4*)(bias + bn + n0 + 4);
  #pragma unroll
  for (int i = 0; i < 8; ++i) {
    float vals[8];
    #pragma unroll
    for (int j = 0; j < 8; ++j) {
      float v = acc[i][j] + bv8[j];
      if (RELU) v = fmaxf(v, 0.f);
      vals[j] = v;
    }
    float* crow = C + (size_t)(bm + m0 + i) * N + bn + n0;
    *(float4*)crow     = *(float4*)&vals[0];
    *(float4*)(crow+4) = *(float4*)&vals[4];
  }
}

// ------------- bf16 MFMA GEMM: C = act(A[M,K] @ Bt[N,K]^T + bias) -----------
// m97 structure: 128x128x32 tile, 4 waves (2x2), 16x16x32 MFMA, 4x4 frags/wave,
// global_load_lds width-16 staging, LDS linear + source-side swizzle
// (slot ^= (row>>1)&3) so frag ds_read_b128 is 2-way (free) instead of 8-way.
template<bool RELU, bool OUT_BF16>
__global__ __launch_bounds__(256) void gemm_bf16_kernel(
    const unsigned short* __restrict__ A,    // [M][K] bf16 bits
    const unsigned short* __restrict__ Bt,   // [N][K] bf16 bits (B transposed)
    const float* __restrict__ bias,          // [N]
    void* __restrict__ C, int M, int N, int K) {
  constexpr int BM = 128, BN = 128, BK = 32;
  __shared__ short As[BM * BK];   // [row][32] linear, 8KB
  __shared__ short Bs[BN * BK];
  const int tid  = threadIdx.x;
  const int lane = tid & 63;
  const int wid  = tid >> 6;           // 0..3
  const int wr = wid >> 1, wc = wid & 1;
  const int bm = blockIdx.y * BM, bn = blockIdx.x * BN;

  // staging: thread t covers LDS row sr=t/4 (and sr+64), 16B slot ss=t%4.
  // LDS slot (r,s) holds global k-slot s ^ ((r>>1)&3)  (inverse == same, XOR)
  const int sr = tid >> 2;
  const int ss = tid & 3;
  const int sw0 = ss ^ ((sr >> 1) & 3);            // note: ((sr+64)>>1)&3 == same
  const unsigned short* Ap0 = A  + (size_t)(bm + sr)      * K + (sw0 << 3);
  const unsigned short* Ap1 = A  + (size_t)(bm + sr + 64) * K + (sw0 << 3);
  const unsigned short* Bp0 = Bt + (size_t)(bn + sr)      * K + (sw0 << 3);
  const unsigned short* Bp1 = Bt + (size_t)(bn + sr + 64) * K + (sw0 << 3);
  // wave-uniform LDS dests (dest = base + lane*16B)
  short* AsW0 = As + (wid << 9);
  short* AsW1 = As + 2048 + (wid << 9);
  short* BsW0 = Bs + (wid << 9);
  short* BsW1 = Bs + 2048 + (wid << 9);

  const int r16 = lane & 15, g = lane >> 4;        // frag row/col, k-slot

  f32x4 acc[4][4] = {};

  for (int k0 = 0; k0 < K; k0 += BK) {
    gload16(Ap0, AsW0); gload16(Ap1, AsW1);
    gload16(Bp0, BsW0); gload16(Bp1, BsW1);
    Ap0 += BK; Ap1 += BK; Bp0 += BK; Bp1 += BK;
    __syncthreads();                                // drains vmcnt before barrier
    short8 av[4], bv[4];
    #pragma unroll
    for (int mi = 0; mi < 4; ++mi) {
      const int row = wr * 64 + mi * 16 + r16;
      av[mi] = *(const short8*)&As[row * 32 + ((g ^ ((row >> 1) & 3)) << 3)];
    }
    #pragma unroll
    for (int ni = 0; ni < 4; ++ni) {
      const int row = wc * 64 + ni * 16 + r16;
      bv[ni] = *(const short8*)&Bs[row * 32 + ((g ^ ((row >> 1) & 3)) << 3)];
    }
    #pragma unroll
    for (int mi = 0; mi < 4; ++mi)
      #pragma unroll
      for (int ni = 0; ni < 4; ++ni)
        acc[mi][ni] = __builtin_amdgcn_mfma_f32_16x16x32_bf16(
            av[mi], bv[ni], acc[mi][ni], 0, 0, 0);
    __syncthreads();                                // reads done before next stage
  }

  // epilogue: C/D layout col=lane&15, row=(lane>>4)*4+reg  [m89/m91 verified]
  #pragma unroll
  for (int ni = 0; ni < 4; ++ni) {
    const int col = bn + wc * 64 + ni * 16 + r16;
    const float bcol = bias[col];
    #pragma unroll
    for (int mi = 0; mi < 4; ++mi) {
      #pragma unroll
      for (int j = 0; j < 4; ++j) {
        const int rowg = bm + wr * 64 + mi * 16 + (g << 2) + j;
        float v = acc[mi][ni][j] + bcol;
        if (RELU) v = fmaxf(v, 0.f);
        if (OUT_BF16) ((unsigned short*)C)[(size_t)rowg * N + col] = f2bf(v);
        else          ((float*)C)[(size_t)rowg * N + col] = v;
      }
    }
  }
}

// ----------- W[K][N] fp32 -> Wt[N][K] bf16 (transpose + convert) ------------
__global__ __launch_bounds__(256) void transpose_bf16_kernel(
    const float* __restrict__ W, unsigned short* __restrict__ Wt, int K, int N) {
  __shared__ float tile[32][33];
  const int bx = blockIdx.x * 32;   // N offset
  const int by = blockIdx.y * 32;   // K offset
  const int tx = threadIdx.x & 31, ty = threadIdx.x >> 5;   // ty 0..7
  #pragma unroll
  for (int i = ty; i < 32; i += 8)
    tile[i][tx] = W[(size_t)(by + i) * N + bx + tx];
  __syncthreads();
  #pragma unroll
  for (int i = ty; i < 32; i += 8)
    Wt[(size_t)(bx + i) * K + by + tx] = f2bf(tile[tx][i]);
}

// --------------------------- fp32 -> bf16 flat ------------------------------
__global__ __launch_bounds__(256) void cvt_bf16_kernel(
    const float* __restrict__ in, unsigned short* __restrict__ out, int n) {
  const int i = (blockIdx.x * 256 + threadIdx.x) * 4;
  if (i >= n) return;
  float4 v = *(const float4*)(in + i);
  ushort4 o;
  o.x = f2bf(v.x); o.y = f2bf(v.y); o.z = f2bf(v.z); o.w = f2bf(v.w);
  *(ushort4*)(out + i) = o;
}

// ------------- M[b,h,l] = max_s(Q[l]·K[idx[l,s]]) - sum_s(...)/L ------------
__global__ __launch_bounds__(256) void prob_m_kernel(
    const float* __restrict__ Q, const float* __restrict__ K_,
    const int* __restrict__ idx, float* __restrict__ M_) {
  const int bl = blockIdx.x;
  const int b = bl / L, l = bl % L;
  const int tid = threadIdx.x;
  __shared__ float dots[H][S];
  __shared__ int sidx[S];
  if (tid < S) sidx[tid] = idx[l * S + tid];
  __syncthreads();
  const int h = tid >> 4;
  const int dsub = (tid & 15) * 4;
  float4 q = *(const float4*)(Q + (size_t)bl * D + h * DH + dsub);
  for (int s = 0; s < S; ++s) {
    const float4 kv = *(const float4*)(K_ + ((size_t)b * L + sidx[s]) * D + h * DH + dsub);
    float p = q.x*kv.x + q.y*kv.y + q.z*kv.z + q.w*kv.w;
    p += __shfl_xor(p, 1);
    p += __shfl_xor(p, 2);
    p += __shfl_xor(p, 4);
    p += __shfl_xor(p, 8);
    if ((tid & 15) == 0) dots[h][s] = p;
  }
  __syncthreads();
  if (tid < H) {
    float mx = -INFINITY, sm = 0.f;
    for (int s = 0; s < S; ++s) { float v = dots[tid][s]; mx = fmaxf(mx, v); sm += v; }
    M_[((size_t)b * H + tid) * L + l] = mx - sm / (float)L;
  }
}

// ------------------------- exact top-k (k=40, n=2048) -----------------------
__global__ __launch_bounds__(256) void topk_kernel(
    const float* __restrict__ M_, int* __restrict__ Mtop) {
  const int bh = blockIdx.x;
  const float* row = M_ + (size_t)bh * L;
  __shared__ float vals[L];
  __shared__ float rv[256];
  __shared__ int   ri[256];
  const int tid = threadIdx.x;
  for (int i = tid; i < L; i += 256) vals[i] = row[i];
  __syncthreads();
  for (int u = 0; u < U; ++u) {
    float best = -INFINITY; int bi = 0x7fffffff;
    for (int i = tid; i < L; i += 256) {
      float v = vals[i];
      if (v > best || (v == best && i < bi)) { best = v; bi = i; }
    }
    rv[tid] = best; ri[tid] = bi;
    __syncthreads();
    for (int off = 128; off > 0; off >>= 1) {
      if (tid < off) {
        float v2 = rv[tid+off]; int i2 = ri[tid+off];
        if (v2 > rv[tid] || (v2 == rv[tid] && i2 < ri[tid])) { rv[tid]=v2; ri[tid]=i2; }
      }
      __syncthreads();
    }
    if (tid == 0) { Mtop[bh * U + u] = ri[0]; vals[ri[0]] = -INFINITY; }
    __syncthreads();
  }
}

// -------- per (b,h,u): scores -> masked softmax -> upd = attn @ V -----------
__global__ __launch_bounds__(256) void attn_upd_kernel(
    const float* __restrict__ Q, const float* __restrict__ K_,
    const float* __restrict__ V, const int* __restrict__ Mtop,
    float* __restrict__ upd) {
  const int bid = blockIdx.x;
  const int u = bid % U, bh = bid / U;
  const int h = bh % H, b = bh / H;
  const int tid = threadIdx.x;
  const int mtop = Mtop[bh * U + u];
  __shared__ float qs[DH];
  __shared__ float w[L];
  __shared__ float red[256];
  __shared__ float part[4][DH];
  if (tid < DH) qs[tid] = Q[((size_t)b * L + mtop) * D + h * DH + tid];
  __syncthreads();
  const int jgrp = tid >> 4;
  const int dsub = (tid & 15) * 4;
  const float4 q4 = *(const float4*)&qs[dsub];
  const float scale = 0.125f;
  for (int j0 = 0; j0 < L; j0 += 16) {
    const int j = j0 + jgrp;
    const float4 kv = *(const float4*)(K_ + ((size_t)b * L + j) * D + h * DH + dsub);
    float p = q4.x*kv.x + q4.y*kv.y + q4.z*kv.z + q4.w*kv.w;
    p += __shfl_xor(p, 1);
    p += __shfl_xor(p, 2);
    p += __shfl_xor(p, 4);
    p += __shfl_xor(p, 8);
    if ((tid & 15) == 0) w[j] = (j <= mtop) ? p * scale : -INFINITY;
  }
  __syncthreads();
  float mx = -INFINITY;
  for (int i = tid; i < L; i += 256) mx = fmaxf(mx, w[i]);
  red[tid] = mx; __syncthreads();
  for (int off = 128; off > 0; off >>= 1) {
    if (tid < off) red[tid] = fmaxf(red[tid], red[tid+off]);
    __syncthreads();
  }
  mx = red[0]; __syncthreads();
  float sm = 0.f;
  for (int i = tid; i < L; i += 256) {
    float wi = w[i];
    float e = (wi == -INFINITY) ? 0.f : expf(wi - mx);
    w[i] = e; sm += e;
  }
  red[tid] = sm; __syncthreads();
  for (int off = 128; off > 0; off >>= 1) {
    if (tid < off) red[tid] += red[tid+off];
    __syncthreads();
  }
  const float inv = 1.0f / red[0];
  __syncthreads();
  const int d = tid & 63, gq = tid >> 6;
  float acc = 0.f;
  for (int j = gq; j < L; j += 4) acc += w[j] * V[((size_t)b * L + j) * D + h * DH + d];
  part[gq][d] = acc; __syncthreads();
  if (tid < DH) {
    float r = (part[0][tid] + part[1][tid] + part[2][tid] + part[3][tid]) * inv;
    upd[((size_t)bh * U + u) * DH + tid] = r;
  }
}

// ------------------------ cumsum(V) over l, two-pass ------------------------
__global__ __launch_bounds__(256) void cumsum_pass1(
    const float* __restrict__ V, float* __restrict__ ctx, float* __restrict__ csums) {
  const int c = blockIdx.x * 256 + threadIdx.x;
  const int ch = blockIdx.y, b = blockIdx.z;
  size_t base = ((size_t)b * L + (size_t)ch * CHLEN) * D + c;
  float acc = 0.f;
  for (int i = 0; i < CHLEN; ++i) {
    acc += V[base + (size_t)i * D];
    ctx[base + (size_t)i * D] = acc;
  }
  csums[((size_t)b * NCHUNK + ch) * D + c] = acc;
}

__global__ __launch_bounds__(256) void cumsum_pass2(
    float* __restrict__ ctx, const float* __restrict__ csums) {
  const int c = blockIdx.x * 256 + threadIdx.x;
  const int ch = blockIdx.y + 1, b = blockIdx.z;
  float off = 0.f;
  for (int j = 0; j < ch; ++j) off += csums[((size_t)b * NCHUNK + j) * D + c];
  size_t base = ((size_t)b * L + (size_t)ch * CHLEN) * D + c;
  for (int i = 0; i < CHLEN; ++i) ctx[base + (size_t)i * D] += off;
}

// ------------------- scatter: ctx[b, Mtop[u], h, :] = upd -------------------
__global__ __launch_bounds__(256) void scatter_kernel(
    float* __restrict__ ctx, const float* __restrict__ upd, const int* __restrict__ Mtop) {
  const int i = blockIdx.x * 256 + threadIdx.x;
  if (i >= B * H * U * DH) return;
  const int d = i % DH, u = (i / DH) % U, bh = i / (DH * U);
  const int h = bh % H, b = bh / H;
  const int l = Mtop[bh * U + u];
  ctx[((size_t)b * L + l) * D + h * DH + d] = upd[i];
}

// ------- out = LayerNorm(a + r) * g + be  (+ optional bf16 copy) ------------
__global__ __launch_bounds__(256) void add_ln_kernel(
    const float* __restrict__ a, const float* __restrict__ r,
    const float* __restrict__ g, const float* __restrict__ be,
    float* __restrict__ out, unsigned short* __restrict__ out16) {
  const int row = blockIdx.x;
  const int tid = threadIdx.x;
  __shared__ float buf[D];
  __shared__ float red[256];
  const float* pa = a + (size_t)row * D;
  const float* pr = r + (size_t)row * D;
  float s = 0.f;
  for (int i = tid; i < D; i += 256) { float v = pa[i] + pr[i]; buf[i] = v; s += v; }
  red[tid] = s; __syncthreads();
  for (int off = 128; off > 0; off >>= 1) {
    if (tid < off) red[tid] += red[tid+off];
    __syncthreads();
  }
  const float mu = red[0] / (float)D;
  __syncthreads();
  float s2 = 0.f;
  for (int i = tid; i < D; i += 256) { float dv = buf[i] - mu; s2 += dv * dv; }
  red[tid] = s2; __syncthreads();
  for (int off = 128; off > 0; off >>= 1) {
    if (tid < off) red[tid] += red[tid+off];
    __syncthreads();
  }
  const float rstd = rsqrtf(red[0] / (float)D + EPS);
  __syncthreads();
  float* po = out + (size_t)row * D;
  for (int i = tid; i < D; i += 256) {
    float v = (buf[i] - mu) * rstd * g[i] + be[i];
    po[i] = v;
    if (out16) out16[(size_t)row * D + i] = f2bf(v);
  }
}

// ----------------------------------------------------------------------------
extern "C" void kernel_launch(void* const* d_in, const int* in_sizes, int n_in,
                              void* d_out, int out_size, void* d_ws, size_t ws_size,
                              hipStream_t stream) {
  const float* x   = (const float*)d_in[0];
  const float* Wq  = (const float*)d_in[1];
  const float* bq  = (const float*)d_in[2];
  const float* Wk  = (const float*)d_in[3];
  const float* bk  = (const float*)d_in[4];
  const float* Wv  = (const float*)d_in[5];
  const float* bv  = (const float*)d_in[6];
  const float* Wo  = (const float*)d_in[7];
  const float* bo  = (const float*)d_in[8];
  const float* g1  = (const float*)d_in[9];
  const float* be1 = (const float*)d_in[10];
  const float* W1  = (const float*)d_in[11];
  const float* b1  = (const float*)d_in[12];
  const float* W2  = (const float*)d_in[13];
  const float* b2  = (const float*)d_in[14];
  const float* g2  = (const float*)d_in[15];
  const float* be2 = (const float*)d_in[16];
  const int*   idx = (const int*)d_in[17];
  float* out = (float*)d_out;

  const size_t SZ = (size_t)B * L * D;            // 4,194,304
  char* base = (char*)d_ws;
  float* Qb   = (float*)base;                      base += SZ * 4;
  float* Kb   = (float*)base;                      base += SZ * 4;
  float* Vb   = (float*)base;                      base += SZ * 4;
  float* ctxb = (float*)base;                      base += SZ * 4;
  unsigned short* ff1b = (unsigned short*)base;    base += (size_t)B*L*FFD * 2;
  unsigned short* W1t  = (unsigned short*)base;    base += (size_t)D*FFD * 2;
  unsigned short* W2t  = (unsigned short*)base;    base += (size_t)D*FFD * 2;
  unsigned short* Wot  = (unsigned short*)base;    base += (size_t)D*D * 2;
  unsigned short* x1b  = (unsigned short*)base;    base += SZ * 2;
  float* Mbuf = (float*)base;                      base += (size_t)B*H*L * 4;
  float* csum = (float*)base;                      base += (size_t)B*NCHUNK*D * 4;
  float* updb = (float*)base;                      base += (size_t)B*H*U*DH * 4;
  int*   Mtop = (int*)base;
  // aliases (stream-ordered lifetimes):
  unsigned short* ctx16 = ff1b;  // consumed by Wo GEMM before ff1b is written
  float* AO  = Qb;               // Qb dead after prob_m/attn_upd
  float* x1  = Kb;               // Kb dead after attn_upd
  float* ff2 = Vb;               // Vb dead after attn_upd/cumsum_pass1

  dim3 blk(256);
  const int M = B * L;   // 4096

  // weight prep: transpose+convert to bf16 [N][K]
  transpose_bf16_kernel<<<dim3(FFD/32, D/32),  blk, 0, stream>>>(W1, W1t, D, FFD);
  transpose_bf16_kernel<<<dim3(D/32,  FFD/32), blk, 0, stream>>>(W2, W2t, FFD, D);
  transpose_bf16_kernel<<<dim3(D/32,  D/32),   blk, 0, stream>>>(Wo, Wot, D, D);

  // Q, K, V projections (fp32: top-k selection + cumsum precision)
  gemm_bias_kernel<false><<<dim3(D/128, M/128), blk, 0, stream>>>(x, Wq, bq, Qb, M, D, D);
  gemm_bias_kernel<false><<<dim3(D/128, M/128), blk, 0, stream>>>(x, Wk, bk, Kb, M, D, D);
  gemm_bias_kernel<false><<<dim3(D/128, M/128), blk, 0, stream>>>(x, Wv, bv, Vb, M, D, D);

  // ProbSparse attention
  prob_m_kernel<<<B*L, blk, 0, stream>>>(Qb, Kb, idx, Mbuf);
  topk_kernel<<<B*H, blk, 0, stream>>>(Mbuf, Mtop);
  attn_upd_kernel<<<B*H*U, blk, 0, stream>>>(Qb, Kb, Vb, Mtop, updb);
  cumsum_pass1<<<dim3(D/256, NCHUNK, B), blk, 0, stream>>>(Vb, ctxb, csum);
  cumsum_pass2<<<dim3(D/256, NCHUNK-1, B), blk, 0, stream>>>(ctxb, csum);
  scatter_kernel<<<(B*H*U*DH + 255)/256, blk, 0, stream>>>(ctxb, updb, Mtop);

  // output projection (bf16 MFMA) + LN1
  cvt_bf16_kernel<<<(int)(SZ/4 + 255)/256, blk, 0, stream>>>(ctxb, ctx16, (int)SZ);
  gemm_bf16_kernel<false,false><<<dim3(D/128, M/128), blk, 0, stream>>>(ctx16, Wot, bo, AO, M, D, D);
  add_ln_kernel<<<B*L, blk, 0, stream>>>(x, AO, g1, be1, x1, x1b);

  // FFN (bf16 MFMA) + LN2
  gemm_bf16_kernel<true, true ><<<dim3(FFD/128, M/128), blk, 0, stream>>>(x1b, W1t, b1, ff1b, M, FFD, D);
  gemm_bf16_kernel<false,false><<<dim3(D/128,  M/128), blk, 0, stream>>>(ff1b, W2t, b2, ff2, M, D, FFD);
  add_ln_kernel<<<B*L, blk, 0, stream>>>(x1, ff2, g2, be2, out, (unsigned short*)nullptr);
}

// Round 3
// 561.654 us; speedup vs baseline: 3.8120x; 1.9897x over previous
//
#include <hip/hip_runtime.h>
#include <hip/hip_bf16.h>
#include <hip/hip_fp16.h>
#include <math.h>

constexpr int B = 2, L = 2048, D = 1024, H = 16, DH = 64, FFD = 4096;
constexpr int S = 40;   // sample_k
constexpr int U = 40;   // n_top
constexpr float EPS = 1e-5f;
constexpr int NCHUNK = 16;
constexpr int CHLEN = L / NCHUNK;   // 128
constexpr int LD3 = 3 * D;          // QKV fused row stride (3072)
constexpr int JT = 128;             // attn j-chunk
constexpr int NJC = L / JT;         // 16

typedef __attribute__((ext_vector_type(8))) short short8;      // 8 bf16/f16 bits
typedef __attribute__((ext_vector_type(8))) _Float16 half8;
typedef __attribute__((ext_vector_type(4))) float f32x4;

__device__ __forceinline__ unsigned short f2bf(float v) {
  __hip_bfloat16 h = __float2bfloat16(v);
  return __builtin_bit_cast(unsigned short, h);
}
__device__ __forceinline__ float bf2f(unsigned short u) {
  unsigned int x = ((unsigned int)u) << 16;
  return __builtin_bit_cast(float, x);
}
__device__ __forceinline__ unsigned short f2h(float v) {
  __half h = __float2half(v);
  return __builtin_bit_cast(unsigned short, h);
}
__device__ __forceinline__ float h2f(unsigned short u) {
  return __half2float(__builtin_bit_cast(__half, u));
}

__device__ __forceinline__ void gload16(const void* g, void* l) {
  __builtin_amdgcn_global_load_lds(
      (const __attribute__((address_space(1))) void*)g,
      (__attribute__((address_space(3))) void*)l, 16, 0, 0);
}

// ---------- MFMA GEMM: C = act(A[M,K] @ Bt[N,K]^T + bias), bf16 or f16 ------
// m97 structure: 128x128x32 tile, 4 waves (2x2), 16x16x32 MFMA, 4x4 frags/wave,
// global_load_lds width-16 staging, LDS linear + source-side swizzle.
template<bool RELU, bool OUT_BF16, bool F16>
__global__ __launch_bounds__(256) void gemm_mfma_kernel(
    const unsigned short* __restrict__ A,    // [M][K] bits
    const unsigned short* __restrict__ Bt,   // [N][K] bits
    const float* __restrict__ bias,          // [N]
    void* __restrict__ C, int M, int N, int K) {
  constexpr int BM = 128, BN = 128, BK = 32;
  __shared__ short As[BM * BK];
  __shared__ short Bs[BN * BK];
  const int tid  = threadIdx.x;
  const int lane = tid & 63;
  const int wid  = tid >> 6;
  const int wr = wid >> 1, wc = wid & 1;
  const int bm = blockIdx.y * BM, bn = blockIdx.x * BN;

  const int sr = tid >> 2;
  const int ss = tid & 3;
  const int sw0 = ss ^ ((sr >> 1) & 3);
  const unsigned short* Ap0 = A  + (size_t)(bm + sr)      * K + (sw0 << 3);
  const unsigned short* Ap1 = A  + (size_t)(bm + sr + 64) * K + (sw0 << 3);
  const unsigned short* Bp0 = Bt + (size_t)(bn + sr)      * K + (sw0 << 3);
  const unsigned short* Bp1 = Bt + (size_t)(bn + sr + 64) * K + (sw0 << 3);
  short* AsW0 = As + (wid << 9);
  short* AsW1 = As + 2048 + (wid << 9);
  short* BsW0 = Bs + (wid << 9);
  short* BsW1 = Bs + 2048 + (wid << 9);

  const int r16 = lane & 15, g = lane >> 4;

  f32x4 acc[4][4] = {};

  for (int k0 = 0; k0 < K; k0 += BK) {
    gload16(Ap0, AsW0); gload16(Ap1, AsW1);
    gload16(Bp0, BsW0); gload16(Bp1, BsW1);
    Ap0 += BK; Ap1 += BK; Bp0 += BK; Bp1 += BK;
    __syncthreads();
    short8 av[4], bv[4];
    #pragma unroll
    for (int mi = 0; mi < 4; ++mi) {
      const int row = wr * 64 + mi * 16 + r16;
      av[mi] = *(const short8*)&As[row * 32 + ((g ^ ((row >> 1) & 3)) << 3)];
    }
    #pragma unroll
    for (int ni = 0; ni < 4; ++ni) {
      const int row = wc * 64 + ni * 16 + r16;
      bv[ni] = *(const short8*)&Bs[row * 32 + ((g ^ ((row >> 1) & 3)) << 3)];
    }
    #pragma unroll
    for (int mi = 0; mi < 4; ++mi)
      #pragma unroll
      for (int ni = 0; ni < 4; ++ni) {
        if constexpr (F16)
          acc[mi][ni] = __builtin_amdgcn_mfma_f32_16x16x32_f16(
              __builtin_bit_cast(half8, av[mi]), __builtin_bit_cast(half8, bv[ni]),
              acc[mi][ni], 0, 0, 0);
        else
          acc[mi][ni] = __builtin_amdgcn_mfma_f32_16x16x32_bf16(
              av[mi], bv[ni], acc[mi][ni], 0, 0, 0);
      }
    __syncthreads();
  }

  #pragma unroll
  for (int ni = 0; ni < 4; ++ni) {
    const int col = bn + wc * 64 + ni * 16 + r16;
    const float bcol = bias[col];
    #pragma unroll
    for (int mi = 0; mi < 4; ++mi) {
      #pragma unroll
      for (int j = 0; j < 4; ++j) {
        const int rowg = bm + wr * 64 + mi * 16 + (g << 2) + j;
        float v = acc[mi][ni][j] + bcol;
        if (RELU) v = fmaxf(v, 0.f);
        if (OUT_BF16) ((unsigned short*)C)[(size_t)rowg * N + col] = f2bf(v);
        else          ((float*)C)[(size_t)rowg * N + col] = v;
      }
    }
  }
}

// ---------- x[M][D] f32 -> A2[M][3D] f16 bits: [hi | hi | lo] ---------------
__global__ __launch_bounds__(256) void split_x_f16_kernel(
    const float* __restrict__ x, unsigned short* __restrict__ A2) {
  const int i = (blockIdx.x * 256 + threadIdx.x) * 4;
  if (i >= B * L * D) return;
  const int m = i / D, k = i % D;
  const float4 v = *(const float4*)(x + i);
  ushort4 hi, lo;
  hi.x = f2h(v.x); lo.x = f2h(v.x - h2f(hi.x));
  hi.y = f2h(v.y); lo.y = f2h(v.y - h2f(hi.y));
  hi.z = f2h(v.z); lo.z = f2h(v.z - h2f(hi.z));
  hi.w = f2h(v.w); lo.w = f2h(v.w - h2f(hi.w));
  unsigned short* row = A2 + (size_t)m * LD3;
  *(ushort4*)(row + k)         = hi;
  *(ushort4*)(row + D + k)     = hi;
  *(ushort4*)(row + 2 * D + k) = lo;
}

// ------ W[D][D] f32 -> B2rows[n][3D] f16 bits: [hi(k) | lo(k) | hi(k)] ------
__global__ __launch_bounds__(256) void wsplit_f16_kernel(
    const float* __restrict__ W, unsigned short* __restrict__ B2r) {
  __shared__ float tile[32][33];
  const int bx = blockIdx.x * 32;   // n
  const int by = blockIdx.y * 32;   // k
  const int tx = threadIdx.x & 31, ty = threadIdx.x >> 5;
  #pragma unroll
  for (int i = ty; i < 32; i += 8)
    tile[i][tx] = W[(size_t)(by + i) * D + bx + tx];
  __syncthreads();
  #pragma unroll
  for (int i = ty; i < 32; i += 8) {
    const float v = tile[tx][i];    // W[by+tx][bx+i]
    const unsigned short hi = f2h(v);
    const unsigned short lo = f2h(v - h2f(hi));
    unsigned short* r = B2r + (size_t)(bx + i) * LD3 + (by + tx);
    r[0]     = hi;
    r[D]     = lo;
    r[2 * D] = hi;
  }
}

// ----------- W[K][N] fp32 -> Wt[N][K] bf16 (transpose + convert) ------------
__global__ __launch_bounds__(256) void transpose_bf16_kernel(
    const float* __restrict__ W, unsigned short* __restrict__ Wt, int K, int N) {
  __shared__ float tile[32][33];
  const int bx = blockIdx.x * 32;
  const int by = blockIdx.y * 32;
  const int tx = threadIdx.x & 31, ty = threadIdx.x >> 5;
  #pragma unroll
  for (int i = ty; i < 32; i += 8)
    tile[i][tx] = W[(size_t)(by + i) * N + bx + tx];
  __syncthreads();
  #pragma unroll
  for (int i = ty; i < 32; i += 8)
    Wt[(size_t)(bx + i) * K + by + tx] = f2bf(tile[tx][i]);
}

// --------------------------- fp32 -> bf16 flat ------------------------------
__global__ __launch_bounds__(256) void cvt_bf16_kernel(
    const float* __restrict__ in, unsigned short* __restrict__ out, int n) {
  const int i = (blockIdx.x * 256 + threadIdx.x) * 4;
  if (i >= n) return;
  float4 v = *(const float4*)(in + i);
  ushort4 o;
  o.x = f2bf(v.x); o.y = f2bf(v.y); o.z = f2bf(v.z); o.w = f2bf(v.w);
  *(ushort4*)(out + i) = o;
}

// ------------------ concat 3 bias vectors of length D -----------------------
__global__ __launch_bounds__(256) void concat3_kernel(
    const float* __restrict__ a, const float* __restrict__ b,
    const float* __restrict__ c, float* __restrict__ o) {
  const int i = blockIdx.x * 256 + threadIdx.x;
  if (i < D) o[i] = a[i];
  else if (i < 2 * D) o[i] = b[i - D];
  else if (i < 3 * D) o[i] = c[i - 2 * D];
}

// ------------- M[b,h,l] = max_s(Q[l]·K[idx[l,s]]) - sum_s(...)/L ------------
__global__ __launch_bounds__(256) void prob_m_kernel(
    const float* __restrict__ QKV, const int* __restrict__ idx,
    float* __restrict__ M_) {
  const int bl = blockIdx.x;
  const int b = bl / L, l = bl % L;
  const int tid = threadIdx.x;
  __shared__ float dots[H][S];
  __shared__ int sidx[S];
  if (tid < S) sidx[tid] = idx[l * S + tid];
  __syncthreads();
  const int h = tid >> 4;
  const int dsub = (tid & 15) * 4;
  float4 q = *(const float4*)(QKV + (size_t)bl * LD3 + h * DH + dsub);
  for (int s = 0; s < S; ++s) {
    const float4 kv = *(const float4*)(QKV + ((size_t)b * L + sidx[s]) * LD3 + D + h * DH + dsub);
    float p = q.x*kv.x + q.y*kv.y + q.z*kv.z + q.w*kv.w;
    p += __shfl_xor(p, 1);
    p += __shfl_xor(p, 2);
    p += __shfl_xor(p, 4);
    p += __shfl_xor(p, 8);
    if ((tid & 15) == 0) dots[h][s] = p;
  }
  __syncthreads();
  if (tid < H) {
    float mx = -INFINITY, sm = 0.f;
    for (int s = 0; s < S; ++s) { float v = dots[tid][s]; mx = fmaxf(mx, v); sm += v; }
    M_[((size_t)b * H + tid) * L + l] = mx - sm / (float)L;
  }
}

// ------------------------- exact top-k (k=40, n=2048) -----------------------
__global__ __launch_bounds__(256) void topk_kernel(
    const float* __restrict__ M_, int* __restrict__ Mtop) {
  const int bh = blockIdx.x;
  const float* row = M_ + (size_t)bh * L;
  __shared__ float vals[L];
  __shared__ float rv[256];
  __shared__ int   ri[256];
  const int tid = threadIdx.x;
  for (int i = tid; i < L; i += 256) vals[i] = row[i];
  __syncthreads();
  for (int u = 0; u < U; ++u) {
    float best = -INFINITY; int bi = 0x7fffffff;
    for (int i = tid; i < L; i += 256) {
      float v = vals[i];
      if (v > best || (v == best && i < bi)) { best = v; bi = i; }
    }
    rv[tid] = best; ri[tid] = bi;
    __syncthreads();
    for (int off = 128; off > 0; off >>= 1) {
      if (tid < off) {
        float v2 = rv[tid+off]; int i2 = ri[tid+off];
        if (v2 > rv[tid] || (v2 == rv[tid] && i2 < ri[tid])) { rv[tid]=v2; ri[tid]=i2; }
      }
      __syncthreads();
    }
    if (tid == 0) { Mtop[bh * U + u] = ri[0]; vals[ri[0]] = -INFINITY; }
    __syncthreads();
  }
}

// ------- attn phase 1: per (b,h,jc) partial softmax + PV over 128 keys ------
__global__ __launch_bounds__(320) void attn_p1_kernel(
    const float* __restrict__ QKV, const int* __restrict__ Mtop,
    float* __restrict__ pmax, float* __restrict__ psum, float* __restrict__ pv) {
  const int jc = blockIdx.x, h = blockIdx.y, b = blockIdx.z;
  const int bh = b * H + h;
  const int tid = threadIdx.x;
  const int j0 = jc * JT;
  __shared__ float Qs[U][68];
  __shared__ float KVs[JT][68];
  __shared__ unsigned short ws[U][JT];

  for (int i = tid; i < U * 16; i += 320) {
    const int u = i >> 4, dq = (i & 15) << 2;
    const int row = Mtop[bh * U + u];
    *(float4*)&Qs[u][dq] =
        *(const float4*)(QKV + ((size_t)b * L + row) * LD3 + h * DH + dq);
  }
  for (int i = tid; i < JT * 16; i += 320) {
    const int j = i >> 4, dq = (i & 15) << 2;
    *(float4*)&KVs[j][dq] =
        *(const float4*)(QKV + ((size_t)b * L + j0 + j) * LD3 + D + h * DH + dq);
  }
  __syncthreads();

  const int u = tid >> 3, jg = tid & 7;
  const int mt = Mtop[bh * U + u];
  float sc[16];
  #pragma unroll
  for (int jt = 0; jt < 16; ++jt) sc[jt] = 0.f;
  for (int dq = 0; dq < 64; dq += 4) {
    const float4 q = *(const float4*)&Qs[u][dq];
    #pragma unroll
    for (int jt = 0; jt < 16; ++jt) {
      const float4 k = *(const float4*)&KVs[jt * 8 + jg][dq];
      sc[jt] += q.x*k.x + q.y*k.y + q.z*k.z + q.w*k.w;
    }
  }
  float m = -INFINITY;
  #pragma unroll
  for (int jt = 0; jt < 16; ++jt) {
    const int j = j0 + jt * 8 + jg;
    sc[jt] = (j <= mt) ? sc[jt] * 0.125f : -INFINITY;
    m = fmaxf(m, sc[jt]);
  }
  m = fmaxf(m, __shfl_xor(m, 1));
  m = fmaxf(m, __shfl_xor(m, 2));
  m = fmaxf(m, __shfl_xor(m, 4));
  float sum = 0.f;
  #pragma unroll
  for (int jt = 0; jt < 16; ++jt) {
    const float e = (sc[jt] == -INFINITY) ? 0.f : expf(sc[jt] - m);
    sum += e;
    ws[u][jt * 8 + jg] = f2bf(e);
  }
  sum += __shfl_xor(sum, 1);
  sum += __shfl_xor(sum, 2);
  sum += __shfl_xor(sum, 4);
  if (jg == 0) {
    pmax[(size_t)(bh * NJC + jc) * U + u] = m;
    psum[(size_t)(bh * NJC + jc) * U + u] = sum;
  }
  __syncthreads();
  // reload LDS with V chunk
  for (int i = tid; i < JT * 16; i += 320) {
    const int j = i >> 4, dq = (i & 15) << 2;
    *(float4*)&KVs[j][dq] =
        *(const float4*)(QKV + ((size_t)b * L + j0 + j) * LD3 + 2 * D + h * DH + dq);
  }
  __syncthreads();
  // PV: thread = (ug 0..4, d 0..63); u = ug + 5k
  const int d = tid & 63, ug = tid >> 6;
  float acc[8] = {};
  for (int j = 0; j < JT; j += 2) {
    const float v0 = KVs[j][d], v1 = KVs[j + 1][d];
    #pragma unroll
    for (int k = 0; k < 8; ++k) {
      const int uu = ug + k * 5;
      const unsigned int wp = *(const unsigned int*)&ws[uu][j];
      acc[k] = fmaf(bf2f((unsigned short)(wp & 0xffff)), v0, acc[k]);
      acc[k] = fmaf(bf2f((unsigned short)(wp >> 16)), v1, acc[k]);
    }
  }
  #pragma unroll
  for (int k = 0; k < 8; ++k) {
    const int uu = ug + k * 5;
    pv[((size_t)(bh * NJC + jc) * U + uu) * DH + d] = acc[k];
  }
}

// ------- attn phase 2: combine 16 chunks per (b,h,u) ------------------------
__global__ __launch_bounds__(64) void attn_p2_kernel(
    const float* __restrict__ pmax, const float* __restrict__ psum,
    const float* __restrict__ pv, float* __restrict__ upd) {
  const int bid = blockIdx.x;          // bh*U + u
  const int u = bid % U, bh = bid / U;
  const int d = threadIdx.x;
  float gmax = -INFINITY;
  for (int c = 0; c < NJC; ++c)
    gmax = fmaxf(gmax, pmax[(size_t)(bh * NJC + c) * U + u]);
  float den = 0.f, num = 0.f;
  for (int c = 0; c < NJC; ++c) {
    const float m = pmax[(size_t)(bh * NJC + c) * U + u];
    if (m == -INFINITY) continue;
    const float s = expf(m - gmax);
    den += psum[(size_t)(bh * NJC + c) * U + u] * s;
    num += pv[((size_t)(bh * NJC + c) * U + u) * DH + d] * s;
  }
  upd[((size_t)bh * U + u) * DH + d] = num / den;
}

// ------------------------ cumsum(V) over l, two-pass ------------------------
__global__ __launch_bounds__(256) void cumsum_pass1(
    const float* __restrict__ QKV, float* __restrict__ ctx, float* __restrict__ csums) {
  const int c = blockIdx.x * 256 + threadIdx.x;
  const int ch = blockIdx.y, b = blockIdx.z;
  size_t bv_ = ((size_t)b * L + (size_t)ch * CHLEN) * LD3 + 2 * D + c;
  size_t bc_ = ((size_t)b * L + (size_t)ch * CHLEN) * D + c;
  float acc = 0.f;
  for (int i = 0; i < CHLEN; ++i) {
    acc += QKV[bv_ + (size_t)i * LD3];
    ctx[bc_ + (size_t)i * D] = acc;
  }
  csums[((size_t)b * NCHUNK + ch) * D + c] = acc;
}

__global__ __launch_bounds__(256) void cumsum_pass2(
    float* __restrict__ ctx, const float* __restrict__ csums) {
  const int c = blockIdx.x * 256 + threadIdx.x;
  const int ch = blockIdx.y + 1, b = blockIdx.z;
  float off = 0.f;
  for (int j = 0; j < ch; ++j) off += csums[((size_t)b * NCHUNK + j) * D + c];
  size_t base = ((size_t)b * L + (size_t)ch * CHLEN) * D + c;
  for (int i = 0; i < CHLEN; ++i) ctx[base + (size_t)i * D] += off;
}

// ------------------- scatter: ctx[b, Mtop[u], h, :] = upd -------------------
__global__ __launch_bounds__(256) void scatter_kernel(
    float* __restrict__ ctx, const float* __restrict__ upd, const int* __restrict__ Mtop) {
  const int i = blockIdx.x * 256 + threadIdx.x;
  if (i >= B * H * U * DH) return;
  const int d = i % DH, u = (i / DH) % U, bh = i / (DH * U);
  const int h = bh % H, b = bh / H;
  const int l = Mtop[bh * U + u];
  ctx[((size_t)b * L + l) * D + h * DH + d] = upd[i];
}

// ------- out = LayerNorm(a + r) * g + be  (+ optional bf16 copy) ------------
__global__ __launch_bounds__(256) void add_ln_kernel(
    const float* __restrict__ a, const float* __restrict__ r,
    const float* __restrict__ g, const float* __restrict__ be,
    float* __restrict__ out, unsigned short* __restrict__ out16) {
  const int row = blockIdx.x;
  const int tid = threadIdx.x;
  __shared__ float buf[D];
  __shared__ float red[256];
  const float* pa = a + (size_t)row * D;
  const float* pr = r + (size_t)row * D;
  float s = 0.f;
  for (int i = tid; i < D; i += 256) { float v = pa[i] + pr[i]; buf[i] = v; s += v; }
  red[tid] = s; __syncthreads();
  for (int off = 128; off > 0; off >>= 1) {
    if (tid < off) red[tid] += red[tid+off];
    __syncthreads();
  }
  const float mu = red[0] / (float)D;
  __syncthreads();
  float s2 = 0.f;
  for (int i = tid; i < D; i += 256) { float dv = buf[i] - mu; s2 += dv * dv; }
  red[tid] = s2; __syncthreads();
  for (int off = 128; off > 0; off >>= 1) {
    if (tid < off) red[tid] += red[tid+off];
    __syncthreads();
  }
  const float rstd = rsqrtf(red[0] / (float)D + EPS);
  __syncthreads();
  float* po = out + (size_t)row * D;
  for (int i = tid; i < D; i += 256) {
    float v = (buf[i] - mu) * rstd * g[i] + be[i];
    po[i] = v;
    if (out16) out16[(size_t)row * D + i] = f2bf(v);
  }
}

// ----------------------------------------------------------------------------
extern "C" void kernel_launch(void* const* d_in, const int* in_sizes, int n_in,
                              void* d_out, int out_size, void* d_ws, size_t ws_size,
                              hipStream_t stream) {
  const float* x   = (const float*)d_in[0];
  const float* Wq  = (const float*)d_in[1];
  const float* bq  = (const float*)d_in[2];
  const float* Wk  = (const float*)d_in[3];
  const float* bk  = (const float*)d_in[4];
  const float* Wv  = (const float*)d_in[5];
  const float* bv  = (const float*)d_in[6];
  const float* Wo  = (const float*)d_in[7];
  const float* bo  = (const float*)d_in[8];
  const float* g1  = (const float*)d_in[9];
  const float* be1 = (const float*)d_in[10];
  const float* W1  = (const float*)d_in[11];
  const float* b1  = (const float*)d_in[12];
  const float* W2  = (const float*)d_in[13];
  const float* b2  = (const float*)d_in[14];
  const float* g2  = (const float*)d_in[15];
  const float* be2 = (const float*)d_in[16];
  const int*   idx = (const int*)d_in[17];
  float* out = (float*)d_out;

  const size_t SZ   = (size_t)B * L * D;        // 4,194,304
  const size_t SZ4  = SZ * 4;                   // 16 MB
  // ---- workspace layout (bytes) ----
  char* p = (char*)d_ws;
  unsigned short* A2  = (unsigned short*)p;               // 25,165,824
  char* pB2  = p + 25165824;                               // 18,874,368
  char* pQKV = pB2 + 18874368;                             // 50,331,648
  char* pFF1 = pQKV + 50331648;                            // 33,554,432
  char* pCTX = pFF1 + 33554432;                            // 16,777,216
  unsigned short* B2  = (unsigned short*)pB2;
  float* QKVb = (float*)pQKV;
  unsigned short* ff1b = (unsigned short*)pFF1;
  float* ctxb = (float*)pCTX;
  // aliases in B2 region (dead after QKV GEMM):
  unsigned short* Wot = (unsigned short*)pB2;
  unsigned short* W1t = Wot + (size_t)D * D;
  unsigned short* W2t = W1t + (size_t)D * FFD;
  // aliases in A2 region (dead after QKV GEMM):
  unsigned short* ctx16 = A2;
  unsigned short* x1b   = (unsigned short*)((char*)A2 + 8388608);
  // aliases in QKV region (dead after cumsum/attn):
  float* AO  = (float*)pQKV;
  float* x1  = (float*)(pQKV + SZ4);
  float* ff2 = (float*)(pQKV + 2 * SZ4);
  // scratch inside FF1 region (dead before FF1 GEMM):
  char* q = pFF1;
  float* qkvbias = (float*)q;                 q += 16384;
  float* Mbuf    = (float*)q;                 q += (size_t)B*H*L*4;       // 262,144
  float* csum    = (float*)q;                 q += (size_t)B*NCHUNK*D*4;  // 131,072
  float* updb    = (float*)q;                 q += (size_t)B*H*U*DH*4;    // 327,680
  int*   Mtop    = (int*)q;                   q += 8192;
  float* pmax    = (float*)q;                 q += (size_t)B*H*NJC*U*4;   // 81,920
  float* psum    = (float*)q;                 q += (size_t)B*H*NJC*U*4;
  float* pv      = (float*)q;                                            // 5,242,880

  dim3 blk(256);
  const int M = B * L;   // 4096

  // ---- QKV via f16 hi/lo split MFMA (fp32-accurate) ----
  split_x_f16_kernel<<<(int)(SZ/4 + 255)/256, blk, 0, stream>>>(x, A2);
  wsplit_f16_kernel<<<dim3(D/32, D/32), blk, 0, stream>>>(Wq, B2);
  wsplit_f16_kernel<<<dim3(D/32, D/32), blk, 0, stream>>>(Wk, B2 + (size_t)D * LD3);
  wsplit_f16_kernel<<<dim3(D/32, D/32), blk, 0, stream>>>(Wv, B2 + (size_t)2 * D * LD3);
  concat3_kernel<<<12, blk, 0, stream>>>(bq, bk, bv, qkvbias);
  gemm_mfma_kernel<false,false,true><<<dim3(LD3/128, M/128), blk, 0, stream>>>(
      A2, B2, qkvbias, QKVb, M, LD3, LD3);

  // ---- FF/Wo weight prep (overwrites B2 region) ----
  transpose_bf16_kernel<<<dim3(D/32,  D/32),   blk, 0, stream>>>(Wo, Wot, D, D);
  transpose_bf16_kernel<<<dim3(FFD/32, D/32),  blk, 0, stream>>>(W1, W1t, D, FFD);
  transpose_bf16_kernel<<<dim3(D/32,  FFD/32), blk, 0, stream>>>(W2, W2t, FFD, D);

  // ---- ProbSparse attention ----
  prob_m_kernel<<<B*L, blk, 0, stream>>>(QKVb, idx, Mbuf);
  topk_kernel<<<B*H, blk, 0, stream>>>(Mbuf, Mtop);
  attn_p1_kernel<<<dim3(NJC, H, B), dim3(320), 0, stream>>>(QKVb, Mtop, pmax, psum, pv);
  attn_p2_kernel<<<B*H*U, dim3(64), 0, stream>>>(pmax, psum, pv, updb);
  cumsum_pass1<<<dim3(D/256, NCHUNK, B), blk, 0, stream>>>(QKVb, ctxb, csum);
  cumsum_pass2<<<dim3(D/256, NCHUNK-1, B), blk, 0, stream>>>(ctxb, csum);
  scatter_kernel<<<(B*H*U*DH + 255)/256, blk, 0, stream>>>(ctxb, updb, Mtop);

  // ---- output projection (bf16 MFMA) + LN1 ----
  cvt_bf16_kernel<<<(int)(SZ/4 + 255)/256, blk, 0, stream>>>(ctxb, ctx16, (int)SZ);
  gemm_mfma_kernel<false,false,false><<<dim3(D/128, M/128), blk, 0, stream>>>(
      ctx16, Wot, bo, AO, M, D, D);
  add_ln_kernel<<<B*L, blk, 0, stream>>>(x, AO, g1, be1, x1, x1b);

  // ---- FFN (bf16 MFMA) + LN2 ----
  gemm_mfma_kernel<true, true, false><<<dim3(FFD/128, M/128), blk, 0, stream>>>(
      x1b, W1t, b1, ff1b, M, FFD, D);
  gemm_mfma_kernel<false,false,false><<<dim3(D/128, M/128), blk, 0, stream>>>(
      ff1b, W2t, b2, ff2, M, D, FFD);
  add_ln_kernel<<<B*L, blk, 0, stream>>>(x1, ff2, g2, be2, out, (unsigned short*)nullptr);
}

// Round 4
// 542.375 us; speedup vs baseline: 3.9475x; 1.0355x over previous
//
#include <hip/hip_runtime.h>
#include <hip/hip_bf16.h>
#include <hip/hip_fp16.h>
#include <math.h>

constexpr int B = 2, L = 2048, D = 1024, H = 16, DH = 64, FFD = 4096;
constexpr int S = 40;   // sample_k
constexpr int U = 40;   // n_top
constexpr float EPS = 1e-5f;
constexpr int NCHUNK = 16;
constexpr int CHLEN = L / NCHUNK;   // 128
constexpr int LD3 = 3 * D;          // QK split GEMM K' (3072)
constexpr int LD2 = 2 * D;          // QK output row stride
constexpr int JT = 128;             // attn j-chunk
constexpr int NJC = L / JT;         // 16

typedef __attribute__((ext_vector_type(8))) short short8;      // 8 bf16/f16 bits
typedef __attribute__((ext_vector_type(8))) _Float16 half8;
typedef __attribute__((ext_vector_type(4))) float f32x4;

__device__ __forceinline__ unsigned short f2bf(float v) {
  __hip_bfloat16 h = __float2bfloat16(v);
  return __builtin_bit_cast(unsigned short, h);
}
__device__ __forceinline__ float bf2f(unsigned short u) {
  unsigned int x = ((unsigned int)u) << 16;
  return __builtin_bit_cast(float, x);
}
__device__ __forceinline__ unsigned short f2h(float v) {
  __half h = __float2half(v);
  return __builtin_bit_cast(unsigned short, h);
}
__device__ __forceinline__ float h2f(unsigned short u) {
  return __half2float(__builtin_bit_cast(__half, u));
}

__device__ __forceinline__ void gload16(const void* g, void* l) {
  __builtin_amdgcn_global_load_lds(
      (const __attribute__((address_space(1))) void*)g,
      (__attribute__((address_space(3))) void*)l, 16, 0, 0);
}

// ======== pipelined MFMA GEMM: 256x128 tile, BK=64, triple-buffered LDS, ====
// counted vmcnt (never drained in-loop), raw s_barrier, T2-style XOR swizzle,
// T5 setprio, XCD-aware block swizzle. C = act(A[M,K] @ Bt[N,K]^T + bias).
template<bool RELU, bool OUT_BF16, bool F16>
__global__ __launch_bounds__(512, 2) void gemm_8ph_kernel(
    const unsigned short* __restrict__ A,    // [M][K] bits
    const unsigned short* __restrict__ Bt,   // [N][K] bits
    const float* __restrict__ bias,          // [N]
    void* __restrict__ C, int M, int N, int K) {
  constexpr int GBM = 256, GBN = 128, GBK = 64;
  constexpr int ABUF = GBM * GBK;    // 16384 shorts
  constexpr int BBUF = GBN * GBK;    // 8192 shorts
  constexpr int BUFS = ABUF + BBUF;  // 24576 shorts
  __shared__ short lds[3 * BUFS];    // 144 KB

  const int tid  = threadIdx.x;
  const int lane = tid & 63;
  const int wid  = tid >> 6;          // 0..7
  const int wr = wid >> 1;            // 0..3  (64-row band of A)
  const int wc = wid & 1;             // 0..1  (64-col band of B)

  // XCD-aware bijective block swizzle (nwg % 8 == 0 for all our shapes)
  const int nwg  = gridDim.x * gridDim.y;
  const int orig = blockIdx.y * gridDim.x + blockIdx.x;
  const int wg   = (orig & 7) * (nwg >> 3) + (orig >> 3);
  const int bm = (wg / gridDim.x) * GBM;
  const int bn = (wg % gridDim.x) * GBN;

  // staging: lane covers row (wid*8 + lane>>3) (+ r*64 per round),
  // physical 16B slot (lane&7) holds logical slot (lane&7)^(row&7)  [T2/G21]
  const int srow  = lane >> 3;                 // 0..7 == row&7
  const int sslot = (lane & 7) ^ srow;         // pre-swizzled source slot
  const unsigned short* aS = A  + (size_t)(bm + wid * 8 + srow) * K + sslot * 8;
  const unsigned short* bS = Bt + (size_t)(bn + wid * 8 + srow) * K + sslot * 8;
  short* ldsAst = lds + wid * 8 * GBK;         // + buf*BUFS + r*64*GBK
  short* ldsBst = lds + ABUF + wid * 8 * GBK;

  auto STAGE = [&](int buf, int kt) {          // 6 vmem ops / thread / tile
    const unsigned short* ap = aS + (size_t)kt * GBK;
    const unsigned short* bp = bS + (size_t)kt * GBK;
    short* la = ldsAst + buf * BUFS;
    short* lb = ldsBst + buf * BUFS;
    gload16(ap,                  la);
    gload16(ap + (size_t)64 * K, la + 64 * GBK);
    gload16(ap + (size_t)128 * K, la + 128 * GBK);
    gload16(ap + (size_t)192 * K, la + 192 * GBK);
    gload16(bp,                  lb);
    gload16(bp + (size_t)64 * K, lb + 64 * GBK);
  };

  const int fr = lane & 15, g = lane >> 4;
  const int nt = K / GBK;

  STAGE(0, 0);
  STAGE(1, 1);

  f32x4 acc[4][4] = {};
  int bc = 0;
  for (int t = 0; t < nt; ++t) {
    const int bs = (bc + 2 >= 3) ? bc - 1 : bc + 2;   // (bc+2)%3, != bc, != bc+1
    const int kt = (t + 2 < nt) ? t + 2 : nt - 1;     // clamp keeps vmcnt uniform
    STAGE(bs, kt);
    asm volatile("s_waitcnt vmcnt(12)" ::: "memory"); // tile t landed; t+1,t+2 in flight
    __builtin_amdgcn_sched_barrier(0);
    __builtin_amdgcn_s_barrier();

    const short* la = lds + bc * BUFS;
    const short* lb = la + ABUF;
    short8 av[2][4], bv[2][4];
    #pragma unroll
    for (int kk = 0; kk < 2; ++kk)
      #pragma unroll
      for (int mi = 0; mi < 4; ++mi) {
        const int row = wr * 64 + mi * 16 + fr;
        av[kk][mi] = *(const short8*)&la[row * GBK + ((((kk << 2) | g) ^ (fr & 7)) << 3)];
      }
    #pragma unroll
    for (int kk = 0; kk < 2; ++kk)
      #pragma unroll
      for (int ni = 0; ni < 4; ++ni) {
        const int row = wc * 64 + ni * 16 + fr;
        bv[kk][ni] = *(const short8*)&lb[row * GBK + ((((kk << 2) | g) ^ (fr & 7)) << 3)];
      }
    __builtin_amdgcn_s_setprio(1);
    #pragma unroll
    for (int kk = 0; kk < 2; ++kk)
      #pragma unroll
      for (int mi = 0; mi < 4; ++mi)
        #pragma unroll
        for (int ni = 0; ni < 4; ++ni) {
          if constexpr (F16)
            acc[mi][ni] = __builtin_amdgcn_mfma_f32_16x16x32_f16(
                __builtin_bit_cast(half8, av[kk][mi]),
                __builtin_bit_cast(half8, bv[kk][ni]), acc[mi][ni], 0, 0, 0);
          else
            acc[mi][ni] = __builtin_amdgcn_mfma_f32_16x16x32_bf16(
                av[kk][mi], bv[kk][ni], acc[mi][ni], 0, 0, 0);
        }
    __builtin_amdgcn_s_setprio(0);
    asm volatile("s_waitcnt lgkmcnt(0)" ::: "memory"); // block-wide: reads of bc done
    __builtin_amdgcn_sched_barrier(0);
    __builtin_amdgcn_s_barrier();
    bc = (bc + 1 == 3) ? 0 : bc + 1;
  }

  // epilogue: C/D layout col=lane&15, row=(lane>>4)*4+reg  [m89/m91 verified]
  #pragma unroll
  for (int ni = 0; ni < 4; ++ni) {
    const int col = bn + wc * 64 + ni * 16 + fr;
    const float bcol = bias[col];
    #pragma unroll
    for (int mi = 0; mi < 4; ++mi) {
      #pragma unroll
      for (int j = 0; j < 4; ++j) {
        const int rowg = bm + wr * 64 + mi * 16 + (g << 2) + j;
        float v = acc[mi][ni][j] + bcol;
        if (RELU) v = fmaxf(v, 0.f);
        if (OUT_BF16) ((unsigned short*)C)[(size_t)rowg * N + col] = f2bf(v);
        else          ((float*)C)[(size_t)rowg * N + col] = v;
      }
    }
  }
}

// ---------- m97-style MFMA GEMM (128x128x32) for small-N shapes -------------
template<bool RELU, bool OUT_BF16, bool F16>
__global__ __launch_bounds__(256) void gemm_mfma_kernel(
    const unsigned short* __restrict__ A, const unsigned short* __restrict__ Bt,
    const float* __restrict__ bias, void* __restrict__ C, int M, int N, int K) {
  constexpr int BM = 128, BN = 128, BK = 32;
  __shared__ short As[BM * BK];
  __shared__ short Bs[BN * BK];
  const int tid  = threadIdx.x;
  const int lane = tid & 63;
  const int wid  = tid >> 6;
  const int wr = wid >> 1, wc = wid & 1;
  const int bm = blockIdx.y * BM, bn = blockIdx.x * BN;

  const int sr = tid >> 2;
  const int ss = tid & 3;
  const int sw0 = ss ^ ((sr >> 1) & 3);
  const unsigned short* Ap0 = A  + (size_t)(bm + sr)      * K + (sw0 << 3);
  const unsigned short* Ap1 = A  + (size_t)(bm + sr + 64) * K + (sw0 << 3);
  const unsigned short* Bp0 = Bt + (size_t)(bn + sr)      * K + (sw0 << 3);
  const unsigned short* Bp1 = Bt + (size_t)(bn + sr + 64) * K + (sw0 << 3);
  short* AsW0 = As + (wid << 9);
  short* AsW1 = As + 2048 + (wid << 9);
  short* BsW0 = Bs + (wid << 9);
  short* BsW1 = Bs + 2048 + (wid << 9);

  const int r16 = lane & 15, g = lane >> 4;
  f32x4 acc[4][4] = {};

  for (int k0 = 0; k0 < K; k0 += BK) {
    gload16(Ap0, AsW0); gload16(Ap1, AsW1);
    gload16(Bp0, BsW0); gload16(Bp1, BsW1);
    Ap0 += BK; Ap1 += BK; Bp0 += BK; Bp1 += BK;
    __syncthreads();
    short8 av[4], bv[4];
    #pragma unroll
    for (int mi = 0; mi < 4; ++mi) {
      const int row = wr * 64 + mi * 16 + r16;
      av[mi] = *(const short8*)&As[row * 32 + ((g ^ ((row >> 1) & 3)) << 3)];
    }
    #pragma unroll
    for (int ni = 0; ni < 4; ++ni) {
      const int row = wc * 64 + ni * 16 + r16;
      bv[ni] = *(const short8*)&Bs[row * 32 + ((g ^ ((row >> 1) & 3)) << 3)];
    }
    #pragma unroll
    for (int mi = 0; mi < 4; ++mi)
      #pragma unroll
      for (int ni = 0; ni < 4; ++ni) {
        if constexpr (F16)
          acc[mi][ni] = __builtin_amdgcn_mfma_f32_16x16x32_f16(
              __builtin_bit_cast(half8, av[mi]), __builtin_bit_cast(half8, bv[ni]),
              acc[mi][ni], 0, 0, 0);
        else
          acc[mi][ni] = __builtin_amdgcn_mfma_f32_16x16x32_bf16(
              av[mi], bv[ni], acc[mi][ni], 0, 0, 0);
      }
    __syncthreads();
  }
  #pragma unroll
  for (int ni = 0; ni < 4; ++ni) {
    const int col = bn + wc * 64 + ni * 16 + r16;
    const float bcol = bias[col];
    #pragma unroll
    for (int mi = 0; mi < 4; ++mi) {
      #pragma unroll
      for (int j = 0; j < 4; ++j) {
        const int rowg = bm + wr * 64 + mi * 16 + (g << 2) + j;
        float v = acc[mi][ni][j] + bcol;
        if (RELU) v = fmaxf(v, 0.f);
        if (OUT_BF16) ((unsigned short*)C)[(size_t)rowg * N + col] = f2bf(v);
        else          ((float*)C)[(size_t)rowg * N + col] = v;
      }
    }
  }
}

// ---- x[M][D] f32 -> A2[M][3D] f16 [hi|hi|lo]  AND  xb[M][D] bf16 -----------
__global__ __launch_bounds__(256) void split_x_f16_kernel(
    const float* __restrict__ x, unsigned short* __restrict__ A2,
    unsigned short* __restrict__ xb) {
  const int i = (blockIdx.x * 256 + threadIdx.x) * 4;
  if (i >= B * L * D) return;
  const int m = i / D, k = i % D;
  const float4 v = *(const float4*)(x + i);
  ushort4 hi, lo, bb;
  hi.x = f2h(v.x); lo.x = f2h(v.x - h2f(hi.x)); bb.x = f2bf(v.x);
  hi.y = f2h(v.y); lo.y = f2h(v.y - h2f(hi.y)); bb.y = f2bf(v.y);
  hi.z = f2h(v.z); lo.z = f2h(v.z - h2f(hi.z)); bb.z = f2bf(v.z);
  hi.w = f2h(v.w); lo.w = f2h(v.w - h2f(hi.w)); bb.w = f2bf(v.w);
  unsigned short* row = A2 + (size_t)m * LD3;
  *(ushort4*)(row + k)         = hi;
  *(ushort4*)(row + D + k)     = hi;
  *(ushort4*)(row + 2 * D + k) = lo;
  *(ushort4*)(xb + i) = bb;
}

// ------ W[D][D] f32 -> B2rows[n][3D] f16 bits: [hi(k) | lo(k) | hi(k)] ------
__global__ __launch_bounds__(256) void wsplit_f16_kernel(
    const float* __restrict__ W, unsigned short* __restrict__ B2r) {
  __shared__ float tile[32][33];
  const int bx = blockIdx.x * 32;   // n
  const int by = blockIdx.y * 32;   // k
  const int tx = threadIdx.x & 31, ty = threadIdx.x >> 5;
  #pragma unroll
  for (int i = ty; i < 32; i += 8)
    tile[i][tx] = W[(size_t)(by + i) * D + bx + tx];
  __syncthreads();
  #pragma unroll
  for (int i = ty; i < 32; i += 8) {
    const float v = tile[tx][i];    // W[by+tx][bx+i]
    const unsigned short hi = f2h(v);
    const unsigned short lo = f2h(v - h2f(hi));
    unsigned short* r = B2r + (size_t)(bx + i) * LD3 + (by + tx);
    r[0]     = hi;
    r[D]     = lo;
    r[2 * D] = hi;
  }
}

// ----------- W[K][N] fp32 -> Wt[N][K] bf16 (transpose + convert) ------------
__global__ __launch_bounds__(256) void transpose_bf16_kernel(
    const float* __restrict__ W, unsigned short* __restrict__ Wt, int K, int N) {
  __shared__ float tile[32][33];
  const int bx = blockIdx.x * 32;
  const int by = blockIdx.y * 32;
  const int tx = threadIdx.x & 31, ty = threadIdx.x >> 5;
  #pragma unroll
  for (int i = ty; i < 32; i += 8)
    tile[i][tx] = W[(size_t)(by + i) * N + bx + tx];
  __syncthreads();
  #pragma unroll
  for (int i = ty; i < 32; i += 8)
    Wt[(size_t)(bx + i) * K + by + tx] = f2bf(tile[tx][i]);
}

// --------------------------- fp32 -> bf16 flat ------------------------------
__global__ __launch_bounds__(256) void cvt_bf16_kernel(
    const float* __restrict__ in, unsigned short* __restrict__ out, int n) {
  const int i = (blockIdx.x * 256 + threadIdx.x) * 4;
  if (i >= n) return;
  float4 v = *(const float4*)(in + i);
  ushort4 o;
  o.x = f2bf(v.x); o.y = f2bf(v.y); o.z = f2bf(v.z); o.w = f2bf(v.w);
  *(ushort4*)(out + i) = o;
}

// ------------------ concat 2 bias vectors of length D -----------------------
__global__ __launch_bounds__(256) void concat2_kernel(
    const float* __restrict__ a, const float* __restrict__ b, float* __restrict__ o) {
  const int i = blockIdx.x * 256 + threadIdx.x;
  if (i < D) o[i] = a[i];
  else if (i < 2 * D) o[i] = b[i - D];
}

// ------------- M[b,h,l] = max_s(Q[l]·K[idx[l,s]]) - sum_s(...)/L ------------
__global__ __launch_bounds__(256) void prob_m_kernel(
    const float* __restrict__ QK, const int* __restrict__ idx,
    float* __restrict__ M_) {
  const int bl = blockIdx.x;
  const int b = bl / L, l = bl % L;
  const int tid = threadIdx.x;
  __shared__ float dots[H][S];
  __shared__ int sidx[S];
  if (tid < S) sidx[tid] = idx[l * S + tid];
  __syncthreads();
  const int h = tid >> 4;
  const int dsub = (tid & 15) * 4;
  float4 q = *(const float4*)(QK + (size_t)bl * LD2 + h * DH + dsub);
  for (int s = 0; s < S; ++s) {
    const float4 kv = *(const float4*)(QK + ((size_t)b * L + sidx[s]) * LD2 + D + h * DH + dsub);
    float p = q.x*kv.x + q.y*kv.y + q.z*kv.z + q.w*kv.w;
    p += __shfl_xor(p, 1);
    p += __shfl_xor(p, 2);
    p += __shfl_xor(p, 4);
    p += __shfl_xor(p, 8);
    if ((tid & 15) == 0) dots[h][s] = p;
  }
  __syncthreads();
  if (tid < H) {
    float mx = -INFINITY, sm = 0.f;
    for (int s = 0; s < S; ++s) { float v = dots[tid][s]; mx = fmaxf(mx, v); sm += v; }
    M_[((size_t)b * H + tid) * L + l] = mx - sm / (float)L;
  }
}

// ------------------------- exact top-k (k=40, n=2048) -----------------------
__global__ __launch_bounds__(256) void topk_kernel(
    const float* __restrict__ M_, int* __restrict__ Mtop) {
  const int bh = blockIdx.x;
  const float* row = M_ + (size_t)bh * L;
  __shared__ float vals[L];
  __shared__ float rv[256];
  __shared__ int   ri[256];
  const int tid = threadIdx.x;
  for (int i = tid; i < L; i += 256) vals[i] = row[i];
  __syncthreads();
  for (int u = 0; u < U; ++u) {
    float best = -INFINITY; int bi = 0x7fffffff;
    for (int i = tid; i < L; i += 256) {
      float v = vals[i];
      if (v > best || (v == best && i < bi)) { best = v; bi = i; }
    }
    rv[tid] = best; ri[tid] = bi;
    __syncthreads();
    for (int off = 128; off > 0; off >>= 1) {
      if (tid < off) {
        float v2 = rv[tid+off]; int i2 = ri[tid+off];
        if (v2 > rv[tid] || (v2 == rv[tid] && i2 < ri[tid])) { rv[tid]=v2; ri[tid]=i2; }
      }
      __syncthreads();
    }
    if (tid == 0) { Mtop[bh * U + u] = ri[0]; vals[ri[0]] = -INFINITY; }
    __syncthreads();
  }
}

// ------- attn phase 1: per (b,h,jc) partial softmax + PV over 128 keys ------
__global__ __launch_bounds__(320) void attn_p1_kernel(
    const float* __restrict__ QK, const float* __restrict__ V,
    const int* __restrict__ Mtop,
    float* __restrict__ pmax, float* __restrict__ psum, float* __restrict__ pv) {
  const int jc = blockIdx.x, h = blockIdx.y, b = blockIdx.z;
  const int bh = b * H + h;
  const int tid = threadIdx.x;
  const int j0 = jc * JT;
  __shared__ float Qs[U][68];
  __shared__ float KVs[JT][68];
  __shared__ unsigned short ws[U][JT];

  for (int i = tid; i < U * 16; i += 320) {
    const int u = i >> 4, dq = (i & 15) << 2;
    const int row = Mtop[bh * U + u];
    *(float4*)&Qs[u][dq] =
        *(const float4*)(QK + ((size_t)b * L + row) * LD2 + h * DH + dq);
  }
  for (int i = tid; i < JT * 16; i += 320) {
    const int j = i >> 4, dq = (i & 15) << 2;
    *(float4*)&KVs[j][dq] =
        *(const float4*)(QK + ((size_t)b * L + j0 + j) * LD2 + D + h * DH + dq);
  }
  __syncthreads();

  const int u = tid >> 3, jg = tid & 7;
  const int mt = Mtop[bh * U + u];
  float sc[16];
  #pragma unroll
  for (int jt = 0; jt < 16; ++jt) sc[jt] = 0.f;
  for (int dq = 0; dq < 64; dq += 4) {
    const float4 q = *(const float4*)&Qs[u][dq];
    #pragma unroll
    for (int jt = 0; jt < 16; ++jt) {
      const float4 k = *(const float4*)&KVs[jt * 8 + jg][dq];
      sc[jt] += q.x*k.x + q.y*k.y + q.z*k.z + q.w*k.w;
    }
  }
  float m = -INFINITY;
  #pragma unroll
  for (int jt = 0; jt < 16; ++jt) {
    const int j = j0 + jt * 8 + jg;
    sc[jt] = (j <= mt) ? sc[jt] * 0.125f : -INFINITY;
    m = fmaxf(m, sc[jt]);
  }
  m = fmaxf(m, __shfl_xor(m, 1));
  m = fmaxf(m, __shfl_xor(m, 2));
  m = fmaxf(m, __shfl_xor(m, 4));
  float sum = 0.f;
  #pragma unroll
  for (int jt = 0; jt < 16; ++jt) {
    const float e = (sc[jt] == -INFINITY) ? 0.f : expf(sc[jt] - m);
    sum += e;
    ws[u][jt * 8 + jg] = f2bf(e);
  }
  sum += __shfl_xor(sum, 1);
  sum += __shfl_xor(sum, 2);
  sum += __shfl_xor(sum, 4);
  if (jg == 0) {
    pmax[(size_t)(bh * NJC + jc) * U + u] = m;
    psum[(size_t)(bh * NJC + jc) * U + u] = sum;
  }
  __syncthreads();
  // reload LDS with V chunk
  for (int i = tid; i < JT * 16; i += 320) {
    const int j = i >> 4, dq = (i & 15) << 2;
    *(float4*)&KVs[j][dq] =
        *(const float4*)(V + ((size_t)b * L + j0 + j) * D + h * DH + dq);
  }
  __syncthreads();
  const int d = tid & 63, ug = tid >> 6;
  float acc[8] = {};
  for (int j = 0; j < JT; j += 2) {
    const float v0 = KVs[j][d], v1 = KVs[j + 1][d];
    #pragma unroll
    for (int k = 0; k < 8; ++k) {
      const int uu = ug + k * 5;
      const unsigned int wp = *(const unsigned int*)&ws[uu][j];
      acc[k] = fmaf(bf2f((unsigned short)(wp & 0xffff)), v0, acc[k]);
      acc[k] = fmaf(bf2f((unsigned short)(wp >> 16)), v1, acc[k]);
    }
  }
  #pragma unroll
  for (int k = 0; k < 8; ++k) {
    const int uu = ug + k * 5;
    pv[((size_t)(bh * NJC + jc) * U + uu) * DH + d] = acc[k];
  }
}

// ------- attn phase 2: combine 16 chunks per (b,h,u) ------------------------
__global__ __launch_bounds__(64) void attn_p2_kernel(
    const float* __restrict__ pmax, const float* __restrict__ psum,
    const float* __restrict__ pv, float* __restrict__ upd) {
  const int bid = blockIdx.x;          // bh*U + u
  const int u = bid % U, bh = bid / U;
  const int d = threadIdx.x;
  float gmax = -INFINITY;
  for (int c = 0; c < NJC; ++c)
    gmax = fmaxf(gmax, pmax[(size_t)(bh * NJC + c) * U + u]);
  float den = 0.f, num = 0.f;
  for (int c = 0; c < NJC; ++c) {
    const float m = pmax[(size_t)(bh * NJC + c) * U + u];
    if (m == -INFINITY) continue;
    const float s = expf(m - gmax);
    den += psum[(size_t)(bh * NJC + c) * U + u] * s;
    num += pv[((size_t)(bh * NJC + c) * U + u) * DH + d] * s;
  }
  upd[((size_t)bh * U + u) * DH + d] = num / den;
}

// ------------------------ cumsum(V) over l, two-pass ------------------------
__global__ __launch_bounds__(256) void cumsum_pass1(
    const float* __restrict__ V, float* __restrict__ ctx, float* __restrict__ csums) {
  const int c = blockIdx.x * 256 + threadIdx.x;
  const int ch = blockIdx.y, b = blockIdx.z;
  size_t base = ((size_t)b * L + (size_t)ch * CHLEN) * D + c;
  float acc = 0.f;
  for (int i = 0; i < CHLEN; ++i) {
    acc += V[base + (size_t)i * D];
    ctx[base + (size_t)i * D] = acc;
  }
  csums[((size_t)b * NCHUNK + ch) * D + c] = acc;
}

__global__ __launch_bounds__(256) void cumsum_pass2(
    float* __restrict__ ctx, const float* __restrict__ csums) {
  const int c = blockIdx.x * 256 + threadIdx.x;
  const int ch = blockIdx.y + 1, b = blockIdx.z;
  float off = 0.f;
  for (int j = 0; j < ch; ++j) off += csums[((size_t)b * NCHUNK + j) * D + c];
  size_t base = ((size_t)b * L + (size_t)ch * CHLEN) * D + c;
  for (int i = 0; i < CHLEN; ++i) ctx[base + (size_t)i * D] += off;
}

// ------------------- scatter: ctx[b, Mtop[u], h, :] = upd -------------------
__global__ __launch_bounds__(256) void scatter_kernel(
    float* __restrict__ ctx, const float* __restrict__ upd, const int* __restrict__ Mtop) {
  const int i = blockIdx.x * 256 + threadIdx.x;
  if (i >= B * H * U * DH) return;
  const int d = i % DH, u = (i / DH) % U, bh = i / (DH * U);
  const int h = bh % H, b = bh / H;
  const int l = Mtop[bh * U + u];
  ctx[((size_t)b * L + l) * D + h * DH + d] = upd[i];
}

// ------- out = LayerNorm(a + r) * g + be  (+ optional bf16 copy) ------------
__global__ __launch_bounds__(256) void add_ln_kernel(
    const float* __restrict__ a, const float* __restrict__ r,
    const float* __restrict__ g, const float* __restrict__ be,
    float* __restrict__ out, unsigned short* __restrict__ out16) {
  const int row = blockIdx.x;
  const int tid = threadIdx.x;
  __shared__ float buf[D];
  __shared__ float red[256];
  const float* pa = a + (size_t)row * D;
  const float* pr = r + (size_t)row * D;
  float s = 0.f;
  for (int i = tid; i < D; i += 256) { float v = pa[i] + pr[i]; buf[i] = v; s += v; }
  red[tid] = s; __syncthreads();
  for (int off = 128; off > 0; off >>= 1) {
    if (tid < off) red[tid] += red[tid+off];
    __syncthreads();
  }
  const float mu = red[0] / (float)D;
  __syncthreads();
  float s2 = 0.f;
  for (int i = tid; i < D; i += 256) { float dv = buf[i] - mu; s2 += dv * dv; }
  red[tid] = s2; __syncthreads();
  for (int off = 128; off > 0; off >>= 1) {
    if (tid < off) red[tid] += red[tid+off];
    __syncthreads();
  }
  const float rstd = rsqrtf(red[0] / (float)D + EPS);
  __syncthreads();
  float* po = out + (size_t)row * D;
  for (int i = tid; i < D; i += 256) {
    float v = (buf[i] - mu) * rstd * g[i] + be[i];
    po[i] = v;
    if (out16) out16[(size_t)row * D + i] = f2bf(v);
  }
}

// ----------------------------------------------------------------------------
extern "C" void kernel_launch(void* const* d_in, const int* in_sizes, int n_in,
                              void* d_out, int out_size, void* d_ws, size_t ws_size,
                              hipStream_t stream) {
  const float* x   = (const float*)d_in[0];
  const float* Wq  = (const float*)d_in[1];
  const float* bq  = (const float*)d_in[2];
  const float* Wk  = (const float*)d_in[3];
  const float* bk  = (const float*)d_in[4];
  const float* Wv  = (const float*)d_in[5];
  const float* bv  = (const float*)d_in[6];
  const float* Wo  = (const float*)d_in[7];
  const float* bo  = (const float*)d_in[8];
  const float* g1  = (const float*)d_in[9];
  const float* be1 = (const float*)d_in[10];
  const float* W1  = (const float*)d_in[11];
  const float* b1  = (const float*)d_in[12];
  const float* W2  = (const float*)d_in[13];
  const float* b2  = (const float*)d_in[14];
  const float* g2  = (const float*)d_in[15];
  const float* be2 = (const float*)d_in[16];
  const int*   idx = (const int*)d_in[17];
  float* out = (float*)d_out;

  const size_t SZ = (size_t)B * L * D;            // 4,194,304
  char* p = (char*)d_ws;
  // ---- workspace (byte offsets; lifetimes verified stream-order) ----
  unsigned short* A2    = (unsigned short*)p;               // [0, 25165824) QK GEMM A
  unsigned short* Wvt   = (unsigned short*)p;               // alias, after QK GEMM
  unsigned short* Wot   = (unsigned short*)(p + 2097152);
  unsigned short* W1t   = (unsigned short*)(p + 4194304);
  unsigned short* W2t   = (unsigned short*)(p + 12582912);
  unsigned short* xb    = (unsigned short*)(p + 25165824);  // 8MB, dead after V GEMM
  unsigned short* B2    = (unsigned short*)(p + 33554432);  // 12.6MB, dead after QK GEMM
  unsigned short* ctx16 = (unsigned short*)(p + 33554432);  // alias (post-QK)
  float* QKb  = (float*)(p + 46137344);   // 33.5MB [Q|K], dead after attn_p1
  float* ctxb = (float*)(p + 46137344);   // alias (written after attn_p1)
  float* ff2  = (float*)(p + 46137344);   // alias (written after cvt/Wo/LN1/FF1)
  float* AO   = (float*)(p + 62914560);   // 16MB (QKb tail, dead)
  float* Vb   = (float*)(p + 79691776);   // 16MB, dead after cumsum_pass1
  float* x1   = (float*)(p + 79691776);   // alias (written at LN1, Vb dead)
  unsigned short* x1b  = (unsigned short*)(p + 96468992);   // 8MB
  unsigned short* ff1b = (unsigned short*)(p + 104857600);  // 33.5MB
  char* scr = p + 138412032;                                // 6.29MB scratch
  float* qkbias = (float*)scr;
  float* Mbuf   = (float*)(scr + 8192);
  float* csum   = (float*)(scr + 270336);
  float* updb   = (float*)(scr + 401408);
  int*   Mtop   = (int*)  (scr + 729088);
  float* pmax   = (float*)(scr + 737280);
  float* psum   = (float*)(scr + 819200);
  float* pv     = (float*)(scr + 901120);

  dim3 blk(256);
  const int M = B * L;   // 4096

  // ---- inputs prep ----
  split_x_f16_kernel<<<(int)(SZ/4 + 255)/256, blk, 0, stream>>>(x, A2, xb);
  wsplit_f16_kernel<<<dim3(D/32, D/32), blk, 0, stream>>>(Wq, B2);
  wsplit_f16_kernel<<<dim3(D/32, D/32), blk, 0, stream>>>(Wk, B2 + (size_t)D * LD3);
  concat2_kernel<<<8, blk, 0, stream>>>(bq, bk, qkbias);

  // ---- QK via f16 hi/lo split (fp32-accurate, feeds exact top-k) ----
  gemm_8ph_kernel<false,false,true><<<dim3(LD2/128, M/256), dim3(512), 0, stream>>>(
      A2, B2, qkbias, QKb, M, LD2, LD3);

  // ---- weight prep (A2 region dead) + V projection (bf16: LN renorm makes
  //      cumsum error relative, ~0.6% — safe) ----
  transpose_bf16_kernel<<<dim3(D/32,  D/32),   blk, 0, stream>>>(Wv, Wvt, D, D);
  transpose_bf16_kernel<<<dim3(D/32,  D/32),   blk, 0, stream>>>(Wo, Wot, D, D);
  transpose_bf16_kernel<<<dim3(FFD/32, D/32),  blk, 0, stream>>>(W1, W1t, D, FFD);
  transpose_bf16_kernel<<<dim3(D/32,  FFD/32), blk, 0, stream>>>(W2, W2t, FFD, D);
  gemm_mfma_kernel<false,false,false><<<dim3(D/128, M/128), blk, 0, stream>>>(
      xb, Wvt, bv, Vb, M, D, D);

  // ---- ProbSparse attention ----
  prob_m_kernel<<<B*L, blk, 0, stream>>>(QKb, idx, Mbuf);
  topk_kernel<<<B*H, blk, 0, stream>>>(Mbuf, Mtop);
  attn_p1_kernel<<<dim3(NJC, H, B), dim3(320), 0, stream>>>(QKb, Vb, Mtop, pmax, psum, pv);
  attn_p2_kernel<<<B*H*U, dim3(64), 0, stream>>>(pmax, psum, pv, updb);
  cumsum_pass1<<<dim3(D/256, NCHUNK, B), blk, 0, stream>>>(Vb, ctxb, csum);
  cumsum_pass2<<<dim3(D/256, NCHUNK-1, B), blk, 0, stream>>>(ctxb, csum);
  scatter_kernel<<<(B*H*U*DH + 255)/256, blk, 0, stream>>>(ctxb, updb, Mtop);

  // ---- output projection (bf16 MFMA) + LN1 ----
  cvt_bf16_kernel<<<(int)(SZ/4 + 255)/256, blk, 0, stream>>>(ctxb, ctx16, (int)SZ);
  gemm_mfma_kernel<false,false,false><<<dim3(D/128, M/128), blk, 0, stream>>>(
      ctx16, Wot, bo, AO, M, D, D);
  add_ln_kernel<<<B*L, blk, 0, stream>>>(x, AO, g1, be1, x1, x1b);

  // ---- FFN + LN2 ----
  gemm_8ph_kernel<true,true,false><<<dim3(FFD/128, M/256), dim3(512), 0, stream>>>(
      x1b, W1t, b1, ff1b, M, FFD, D);
  gemm_mfma_kernel<false,false,false><<<dim3(D/128, M/128), blk, 0, stream>>>(
      ff1b, W2t, b2, ff2, M, D, FFD);
  add_ln_kernel<<<B*L, blk, 0, stream>>>(x1, ff2, g2, be2, out, (unsigned short*)nullptr);
}

// Round 5
// 423.063 us; speedup vs baseline: 5.0608x; 1.2820x over previous
//
#include <hip/hip_runtime.h>
#include <hip/hip_bf16.h>
#include <hip/hip_fp16.h>
#include <math.h>

constexpr int B = 2, L = 2048, D = 1024, H = 16, DH = 64, FFD = 4096;
constexpr int S = 40;   // sample_k
constexpr int U = 40;   // n_top
constexpr float EPS = 1e-5f;
constexpr int NCHUNK = 32;
constexpr int CHLEN = L / NCHUNK;   // 64
constexpr int LD3 = 3 * D;          // QK split GEMM K' (3072)
constexpr int LD2 = 2 * D;          // QK output row stride
constexpr int JT = 128;             // attn j-chunk
constexpr int NJC = L / JT;         // 16

typedef __attribute__((ext_vector_type(8))) short short8;      // 8 bf16/f16 bits
typedef __attribute__((ext_vector_type(8))) _Float16 half8;
typedef __attribute__((ext_vector_type(4))) float f32x4;

__device__ __forceinline__ unsigned short f2bf(float v) {
  __hip_bfloat16 h = __float2bfloat16(v);
  return __builtin_bit_cast(unsigned short, h);
}
__device__ __forceinline__ float bf2f(unsigned short u) {
  unsigned int x = ((unsigned int)u) << 16;
  return __builtin_bit_cast(float, x);
}
__device__ __forceinline__ unsigned short f2h(float v) {
  __half h = __float2half(v);
  return __builtin_bit_cast(unsigned short, h);
}
__device__ __forceinline__ float h2f(unsigned short u) {
  return __half2float(__builtin_bit_cast(__half, u));
}

__device__ __forceinline__ void gload16(const void* g, void* l) {
  __builtin_amdgcn_global_load_lds(
      (const __attribute__((address_space(1))) void*)g,
      (__attribute__((address_space(3))) void*)l, 16, 0, 0);
}

// ======== pipelined MFMA GEMM: 256x128 tile, BK=64, triple-buffered LDS, ====
// counted vmcnt (never drained in-loop), raw s_barrier, T2-style XOR swizzle,
// T5 setprio, XCD-aware block swizzle. SPLITK>1: blockIdx.z owns K-slice,
// writes fp32 partial (no bias) to C + z*M*N; consumers fuse the reduction.
template<bool RELU, bool OUT_BF16, bool F16, int SPLITK>
__global__ __launch_bounds__(512, 2) void gemm_8ph_kernel(
    const unsigned short* __restrict__ A,    // [M][K] bits
    const unsigned short* __restrict__ Bt,   // [N][K] bits
    const float* __restrict__ bias,          // [N] (SPLITK==1 only)
    void* __restrict__ C, int M, int N, int K) {
  constexpr int GBM = 256, GBN = 128, GBK = 64;
  constexpr int ABUF = GBM * GBK;    // 16384 shorts
  constexpr int BBUF = GBN * GBK;    // 8192 shorts
  constexpr int BUFS = ABUF + BBUF;  // 24576 shorts
  __shared__ short lds[3 * BUFS];    // 144 KB

  const int tid  = threadIdx.x;
  const int lane = tid & 63;
  const int wid  = tid >> 6;          // 0..7
  const int wr = wid >> 1;            // 0..3  (64-row band of A)
  const int wc = wid & 1;             // 0..1  (64-col band of B)

  // XCD-aware bijective block swizzle (nwg % 8 == 0 for all our shapes)
  const int nwg  = gridDim.x * gridDim.y;
  const int orig = blockIdx.y * gridDim.x + blockIdx.x;
  const int wg   = (orig & 7) * (nwg >> 3) + (orig >> 3);
  const int bm = (wg / gridDim.x) * GBM;
  const int bn = (wg % gridDim.x) * GBN;

  const int kslice = K / SPLITK;
  const int kbase  = (SPLITK > 1) ? blockIdx.z * kslice : 0;

  // staging: lane covers row (wid*8 + lane>>3) (+ r*64 per round),
  // physical 16B slot (lane&7) holds logical slot (lane&7)^(row&7)  [T2/G21]
  const int srow  = lane >> 3;                 // 0..7 == row&7
  const int sslot = (lane & 7) ^ srow;         // pre-swizzled source slot
  const unsigned short* aS = A  + (size_t)(bm + wid * 8 + srow) * K + kbase + sslot * 8;
  const unsigned short* bS = Bt + (size_t)(bn + wid * 8 + srow) * K + kbase + sslot * 8;
  short* ldsAst = lds + wid * 8 * GBK;
  short* ldsBst = lds + ABUF + wid * 8 * GBK;

  auto STAGE = [&](int buf, int kt) {          // 6 vmem ops / thread / tile
    const unsigned short* ap = aS + (size_t)kt * GBK;
    const unsigned short* bp = bS + (size_t)kt * GBK;
    short* la = ldsAst + buf * BUFS;
    short* lb = ldsBst + buf * BUFS;
    gload16(ap,                   la);
    gload16(ap + (size_t)64 * K,  la + 64 * GBK);
    gload16(ap + (size_t)128 * K, la + 128 * GBK);
    gload16(ap + (size_t)192 * K, la + 192 * GBK);
    gload16(bp,                   lb);
    gload16(bp + (size_t)64 * K,  lb + 64 * GBK);
  };

  const int fr = lane & 15, g = lane >> 4;
  const int nt = kslice / GBK;

  STAGE(0, 0);
  STAGE(1, 1);

  f32x4 acc[4][4] = {};
  int bc = 0;
  for (int t = 0; t < nt; ++t) {
    const int bs = (bc + 2 >= 3) ? bc - 1 : bc + 2;   // (bc+2)%3
    const int kt = (t + 2 < nt) ? t + 2 : nt - 1;     // clamp keeps vmcnt uniform
    STAGE(bs, kt);
    asm volatile("s_waitcnt vmcnt(12)" ::: "memory"); // tile t landed; t+1,t+2 in flight
    __builtin_amdgcn_sched_barrier(0);
    __builtin_amdgcn_s_barrier();

    const short* la = lds + bc * BUFS;
    const short* lb = la + ABUF;
    short8 av[2][4], bv[2][4];
    #pragma unroll
    for (int kk = 0; kk < 2; ++kk)
      #pragma unroll
      for (int mi = 0; mi < 4; ++mi) {
        const int row = wr * 64 + mi * 16 + fr;
        av[kk][mi] = *(const short8*)&la[row * GBK + ((((kk << 2) | g) ^ (fr & 7)) << 3)];
      }
    #pragma unroll
    for (int kk = 0; kk < 2; ++kk)
      #pragma unroll
      for (int ni = 0; ni < 4; ++ni) {
        const int row = wc * 64 + ni * 16 + fr;
        bv[kk][ni] = *(const short8*)&lb[row * GBK + ((((kk << 2) | g) ^ (fr & 7)) << 3)];
      }
    __builtin_amdgcn_s_setprio(1);
    #pragma unroll
    for (int kk = 0; kk < 2; ++kk)
      #pragma unroll
      for (int mi = 0; mi < 4; ++mi)
        #pragma unroll
        for (int ni = 0; ni < 4; ++ni) {
          if constexpr (F16)
            acc[mi][ni] = __builtin_amdgcn_mfma_f32_16x16x32_f16(
                __builtin_bit_cast(half8, av[kk][mi]),
                __builtin_bit_cast(half8, bv[kk][ni]), acc[mi][ni], 0, 0, 0);
          else
            acc[mi][ni] = __builtin_amdgcn_mfma_f32_16x16x32_bf16(
                av[kk][mi], bv[kk][ni], acc[mi][ni], 0, 0, 0);
        }
    __builtin_amdgcn_s_setprio(0);
    asm volatile("s_waitcnt lgkmcnt(0)" ::: "memory");
    __builtin_amdgcn_sched_barrier(0);
    __builtin_amdgcn_s_barrier();
    bc = (bc + 1 == 3) ? 0 : bc + 1;
  }

  // epilogue: C/D layout col=lane&15, row=(lane>>4)*4+reg  [m89/m91 verified]
  #pragma unroll
  for (int ni = 0; ni < 4; ++ni) {
    const int col = bn + wc * 64 + ni * 16 + fr;
    float bcol = 0.f;
    if constexpr (SPLITK == 1) bcol = bias[col];
    #pragma unroll
    for (int mi = 0; mi < 4; ++mi) {
      #pragma unroll
      for (int j = 0; j < 4; ++j) {
        const int rowg = bm + wr * 64 + mi * 16 + (g << 2) + j;
        if constexpr (SPLITK > 1) {
          float* Cp = (float*)C + (size_t)blockIdx.z * M * N;
          Cp[(size_t)rowg * N + col] = acc[mi][ni][j];
        } else {
          float v = acc[mi][ni][j] + bcol;
          if (RELU) v = fmaxf(v, 0.f);
          if (OUT_BF16) ((unsigned short*)C)[(size_t)rowg * N + col] = f2bf(v);
          else          ((float*)C)[(size_t)rowg * N + col] = v;
        }
      }
    }
  }
}

// ---- x[M][D] f32 -> A2[M][3D] f16 [hi|hi|lo]  AND  xb[M][D] bf16 -----------
__global__ __launch_bounds__(256) void split_x_f16_kernel(
    const float* __restrict__ x, unsigned short* __restrict__ A2,
    unsigned short* __restrict__ xb) {
  const int i = (blockIdx.x * 256 + threadIdx.x) * 4;
  if (i >= B * L * D) return;
  const int m = i / D, k = i % D;
  const float4 v = *(const float4*)(x + i);
  ushort4 hi, lo, bb;
  hi.x = f2h(v.x); lo.x = f2h(v.x - h2f(hi.x)); bb.x = f2bf(v.x);
  hi.y = f2h(v.y); lo.y = f2h(v.y - h2f(hi.y)); bb.y = f2bf(v.y);
  hi.z = f2h(v.z); lo.z = f2h(v.z - h2f(hi.z)); bb.z = f2bf(v.z);
  hi.w = f2h(v.w); lo.w = f2h(v.w - h2f(hi.w)); bb.w = f2bf(v.w);
  unsigned short* row = A2 + (size_t)m * LD3;
  *(ushort4*)(row + k)         = hi;
  *(ushort4*)(row + D + k)     = hi;
  *(ushort4*)(row + 2 * D + k) = lo;
  *(ushort4*)(xb + i) = bb;
}

// ------ W[D][D] f32 -> B2rows[n][3D] f16 bits: [hi(k) | lo(k) | hi(k)] ------
__global__ __launch_bounds__(256) void wsplit_f16_kernel(
    const float* __restrict__ W, unsigned short* __restrict__ B2r) {
  __shared__ float tile[32][33];
  const int bx = blockIdx.x * 32;   // n
  const int by = blockIdx.y * 32;   // k
  const int tx = threadIdx.x & 31, ty = threadIdx.x >> 5;
  #pragma unroll
  for (int i = ty; i < 32; i += 8)
    tile[i][tx] = W[(size_t)(by + i) * D + bx + tx];
  __syncthreads();
  #pragma unroll
  for (int i = ty; i < 32; i += 8) {
    const float v = tile[tx][i];    // W[by+tx][bx+i]
    const unsigned short hi = f2h(v);
    const unsigned short lo = f2h(v - h2f(hi));
    unsigned short* r = B2r + (size_t)(bx + i) * LD3 + (by + tx);
    r[0]     = hi;
    r[D]     = lo;
    r[2 * D] = hi;
  }
}

// ----------- W[K][N] fp32 -> Wt[N][K] bf16 (transpose + convert) ------------
__global__ __launch_bounds__(256) void transpose_bf16_kernel(
    const float* __restrict__ W, unsigned short* __restrict__ Wt, int K, int N) {
  __shared__ float tile[32][33];
  const int bx = blockIdx.x * 32;
  const int by = blockIdx.y * 32;
  const int tx = threadIdx.x & 31, ty = threadIdx.x >> 5;
  #pragma unroll
  for (int i = ty; i < 32; i += 8)
    tile[i][tx] = W[(size_t)(by + i) * N + bx + tx];
  __syncthreads();
  #pragma unroll
  for (int i = ty; i < 32; i += 8)
    Wt[(size_t)(bx + i) * K + by + tx] = f2bf(tile[tx][i]);
}

// --------------------------- fp32 -> bf16 flat ------------------------------
__global__ __launch_bounds__(256) void cvt_bf16_kernel(
    const float* __restrict__ in, unsigned short* __restrict__ out, int n) {
  const int i = (blockIdx.x * 256 + threadIdx.x) * 4;
  if (i >= n) return;
  float4 v = *(const float4*)(in + i);
  ushort4 o;
  o.x = f2bf(v.x); o.y = f2bf(v.y); o.z = f2bf(v.z); o.w = f2bf(v.w);
  *(ushort4*)(out + i) = o;
}

// ------------------ concat 2 bias vectors of length D -----------------------
__global__ __launch_bounds__(256) void concat2_kernel(
    const float* __restrict__ a, const float* __restrict__ b, float* __restrict__ o) {
  const int i = blockIdx.x * 256 + threadIdx.x;
  if (i < D) o[i] = a[i];
  else if (i < 2 * D) o[i] = b[i - D];
}

// ------------- M[b,h,l] = max_s(Q[l]·K[idx[l,s]]) - sum_s(...)/L ------------
__global__ __launch_bounds__(256) void prob_m_kernel(
    const float* __restrict__ QK, const int* __restrict__ idx,
    float* __restrict__ M_) {
  const int bl = blockIdx.x;
  const int b = bl / L, l = bl % L;
  const int tid = threadIdx.x;
  __shared__ float dots[H][S];
  __shared__ int sidx[S];
  if (tid < S) sidx[tid] = idx[l * S + tid];
  __syncthreads();
  const int h = tid >> 4;
  const int dsub = (tid & 15) * 4;
  float4 q = *(const float4*)(QK + (size_t)bl * LD2 + h * DH + dsub);
  for (int s = 0; s < S; ++s) {
    const float4 kv = *(const float4*)(QK + ((size_t)b * L + sidx[s]) * LD2 + D + h * DH + dsub);
    float p = q.x*kv.x + q.y*kv.y + q.z*kv.z + q.w*kv.w;
    p += __shfl_xor(p, 1);
    p += __shfl_xor(p, 2);
    p += __shfl_xor(p, 4);
    p += __shfl_xor(p, 8);
    if ((tid & 15) == 0) dots[h][s] = p;
  }
  __syncthreads();
  if (tid < H) {
    float mx = -INFINITY, sm = 0.f;
    for (int s = 0; s < S; ++s) { float v = dots[tid][s]; mx = fmaxf(mx, v); sm += v; }
    M_[((size_t)b * H + tid) * L + l] = mx - sm / (float)L;
  }
}

// ---------- exact top-k (k=40, n=2048), register-resident argmax ------------
__global__ __launch_bounds__(256) void topk_kernel(
    const float* __restrict__ M_, int* __restrict__ Mtop) {
  const int bh = blockIdx.x;
  const float* row = M_ + (size_t)bh * L;
  const int tid = threadIdx.x;
  const int lane = tid & 63, w = tid >> 6;
  float v[8];
  #pragma unroll
  for (int k = 0; k < 8; ++k) v[k] = row[tid + k * 256];
  __shared__ float wv[4];
  __shared__ int   wi[4];
  __shared__ int   winner;
  for (int u = 0; u < U; ++u) {
    float best = v[0]; int bk = 0;
    #pragma unroll
    for (int k = 1; k < 8; ++k)
      if (v[k] > best) { best = v[k]; bk = k; }          // strict >: lower index wins
    int bidx = bk * 256 + tid;
    #pragma unroll
    for (int off = 1; off < 64; off <<= 1) {
      const float ov = __shfl_xor(best, off);
      const int   oi = __shfl_xor(bidx, off);
      if (ov > best || (ov == best && oi < bidx)) { best = ov; bidx = oi; }
    }
    if (lane == 0) { wv[w] = best; wi[w] = bidx; }
    __syncthreads();
    if (tid == 0) {
      float bb = wv[0]; int bi = wi[0];
      #pragma unroll
      for (int q2 = 1; q2 < 4; ++q2)
        if (wv[q2] > bb || (wv[q2] == bb && wi[q2] < bi)) { bb = wv[q2]; bi = wi[q2]; }
      Mtop[bh * U + u] = bi;
      winner = bi;
    }
    __syncthreads();
    const int wn = winner;
    if ((wn & 255) == tid) {
      const int kk = wn >> 8;
      #pragma unroll
      for (int k = 0; k < 8; ++k) if (k == kk) v[k] = -INFINITY;   // static idx
    }
  }
}

// ------- attn phase 1: per (b,h,jc) partial softmax + PV over 128 keys ------
// V comes as two split-K partials (Vp0 + Vp1), summed at stage time.
__global__ __launch_bounds__(320) void attn_p1_kernel(
    const float* __restrict__ QK, const float* __restrict__ Vp,
    const int* __restrict__ Mtop,
    float* __restrict__ pmax, float* __restrict__ psum, float* __restrict__ pv) {
  const int jc = blockIdx.x, h = blockIdx.y, b = blockIdx.z;
  const int bh = b * H + h;
  const int tid = threadIdx.x;
  const int j0 = jc * JT;
  const float* Vp1 = Vp + (size_t)B * L * D;
  __shared__ float Qs[U][68];
  __shared__ float KVs[JT][68];
  __shared__ unsigned short ws[U][JT];

  for (int i = tid; i < U * 16; i += 320) {
    const int u = i >> 4, dq = (i & 15) << 2;
    const int row = Mtop[bh * U + u];
    *(float4*)&Qs[u][dq] =
        *(const float4*)(QK + ((size_t)b * L + row) * LD2 + h * DH + dq);
  }
  for (int i = tid; i < JT * 16; i += 320) {
    const int j = i >> 4, dq = (i & 15) << 2;
    *(float4*)&KVs[j][dq] =
        *(const float4*)(QK + ((size_t)b * L + j0 + j) * LD2 + D + h * DH + dq);
  }
  __syncthreads();

  const int u = tid >> 3, jg = tid & 7;
  const int mt = Mtop[bh * U + u];
  float sc[16];
  #pragma unroll
  for (int jt = 0; jt < 16; ++jt) sc[jt] = 0.f;
  for (int dq = 0; dq < 64; dq += 4) {
    const float4 q = *(const float4*)&Qs[u][dq];
    #pragma unroll
    for (int jt = 0; jt < 16; ++jt) {
      const float4 k = *(const float4*)&KVs[jt * 8 + jg][dq];
      sc[jt] += q.x*k.x + q.y*k.y + q.z*k.z + q.w*k.w;
    }
  }
  float m = -INFINITY;
  #pragma unroll
  for (int jt = 0; jt < 16; ++jt) {
    const int j = j0 + jt * 8 + jg;
    sc[jt] = (j <= mt) ? sc[jt] * 0.125f : -INFINITY;
    m = fmaxf(m, sc[jt]);
  }
  m = fmaxf(m, __shfl_xor(m, 1));
  m = fmaxf(m, __shfl_xor(m, 2));
  m = fmaxf(m, __shfl_xor(m, 4));
  float sum = 0.f;
  #pragma unroll
  for (int jt = 0; jt < 16; ++jt) {
    const float e = (sc[jt] == -INFINITY) ? 0.f : expf(sc[jt] - m);
    sum += e;
    ws[u][jt * 8 + jg] = f2bf(e);
  }
  sum += __shfl_xor(sum, 1);
  sum += __shfl_xor(sum, 2);
  sum += __shfl_xor(sum, 4);
  if (jg == 0) {
    pmax[(size_t)(bh * NJC + jc) * U + u] = m;
    psum[(size_t)(bh * NJC + jc) * U + u] = sum;
  }
  __syncthreads();
  // reload LDS with V chunk (sum of split-K partials)
  for (int i = tid; i < JT * 16; i += 320) {
    const int j = i >> 4, dq = (i & 15) << 2;
    const size_t off = ((size_t)b * L + j0 + j) * D + h * DH + dq;
    const float4 a = *(const float4*)(Vp + off);
    const float4 c = *(const float4*)(Vp1 + off);
    float4 r; r.x = a.x + c.x; r.y = a.y + c.y; r.z = a.z + c.z; r.w = a.w + c.w;
    *(float4*)&KVs[j][dq] = r;
  }
  __syncthreads();
  const int d = tid & 63, ug = tid >> 6;
  float acc[8] = {};
  for (int j = 0; j < JT; j += 2) {
    const float v0 = KVs[j][d], v1 = KVs[j + 1][d];
    #pragma unroll
    for (int k = 0; k < 8; ++k) {
      const int uu = ug + k * 5;
      const unsigned int wp = *(const unsigned int*)&ws[uu][j];
      acc[k] = fmaf(bf2f((unsigned short)(wp & 0xffff)), v0, acc[k]);
      acc[k] = fmaf(bf2f((unsigned short)(wp >> 16)), v1, acc[k]);
    }
  }
  #pragma unroll
  for (int k = 0; k < 8; ++k) {
    const int uu = ug + k * 5;
    pv[((size_t)(bh * NJC + jc) * U + uu) * DH + d] = acc[k];
  }
}

// ------- attn phase 2: combine 16 chunks per (b,h,u) ------------------------
__global__ __launch_bounds__(64) void attn_p2_kernel(
    const float* __restrict__ pmax, const float* __restrict__ psum,
    const float* __restrict__ pv, float* __restrict__ upd) {
  const int bid = blockIdx.x;          // bh*U + u
  const int u = bid % U, bh = bid / U;
  const int d = threadIdx.x;
  float gmax = -INFINITY;
  for (int c = 0; c < NJC; ++c)
    gmax = fmaxf(gmax, pmax[(size_t)(bh * NJC + c) * U + u]);
  float den = 0.f, num = 0.f;
  for (int c = 0; c < NJC; ++c) {
    const float m = pmax[(size_t)(bh * NJC + c) * U + u];
    if (m == -INFINITY) continue;
    const float s = expf(m - gmax);
    den += psum[(size_t)(bh * NJC + c) * U + u] * s;
    num += pv[((size_t)(bh * NJC + c) * U + u) * DH + d] * s;
  }
  upd[((size_t)bh * U + u) * DH + d] = num / den;
}

// -------------- cumsum(V) over l, two-pass (V = Vp0 + Vp1) ------------------
__global__ __launch_bounds__(256) void cumsum_pass1(
    const float* __restrict__ Vp, float* __restrict__ ctx, float* __restrict__ csums) {
  const int c = blockIdx.x * 256 + threadIdx.x;
  const int ch = blockIdx.y, b = blockIdx.z;
  const float* Vp1 = Vp + (size_t)B * L * D;
  size_t base = ((size_t)b * L + (size_t)ch * CHLEN) * D + c;
  float acc = 0.f;
  for (int i = 0; i < CHLEN; ++i) {
    const size_t o = base + (size_t)i * D;
    acc += Vp[o] + Vp1[o];
    ctx[o] = acc;
  }
  csums[((size_t)b * NCHUNK + ch) * D + c] = acc;
}

__global__ __launch_bounds__(256) void cumsum_pass2(
    float* __restrict__ ctx, const float* __restrict__ csums) {
  const int c = blockIdx.x * 256 + threadIdx.x;
  const int ch = blockIdx.y + 1, b = blockIdx.z;
  float off = 0.f;
  for (int j = 0; j < ch; ++j) off += csums[((size_t)b * NCHUNK + j) * D + c];
  size_t base = ((size_t)b * L + (size_t)ch * CHLEN) * D + c;
  for (int i = 0; i < CHLEN; ++i) ctx[base + (size_t)i * D] += off;
}

// ------------------- scatter: ctx[b, Mtop[u], h, :] = upd -------------------
__global__ __launch_bounds__(256) void scatter_kernel(
    float* __restrict__ ctx, const float* __restrict__ upd, const int* __restrict__ Mtop) {
  const int i = blockIdx.x * 256 + threadIdx.x;
  if (i >= B * H * U * DH) return;
  const int d = i % DH, u = (i / DH) % U, bh = i / (DH * U);
  const int h = bh % H, b = bh / H;
  const int l = Mtop[bh * U + u];
  ctx[((size_t)b * L + l) * D + h * DH + d] = upd[i];
}

// -- out = LayerNorm(a + p0 + p1 + bias) * g + be  (+ optional bf16 copy) ----
__global__ __launch_bounds__(256) void add2_ln_kernel(
    const float* __restrict__ a, const float* __restrict__ p0,
    const float* __restrict__ p1, const float* __restrict__ bias,
    const float* __restrict__ g, const float* __restrict__ be,
    float* __restrict__ out, unsigned short* __restrict__ out16) {
  const int row = blockIdx.x;
  const int tid = threadIdx.x;
  __shared__ float buf[D];
  __shared__ float red[256];
  const float* pa = a  + (size_t)row * D;
  const float* q0 = p0 + (size_t)row * D;
  const float* q1 = p1 + (size_t)row * D;
  float s = 0.f;
  for (int i = tid; i < D; i += 256) {
    float v = pa[i] + q0[i] + q1[i] + bias[i];
    buf[i] = v; s += v;
  }
  red[tid] = s; __syncthreads();
  for (int off = 128; off > 0; off >>= 1) {
    if (tid < off) red[tid] += red[tid+off];
    __syncthreads();
  }
  const float mu = red[0] / (float)D;
  __syncthreads();
  float s2 = 0.f;
  for (int i = tid; i < D; i += 256) { float dv = buf[i] - mu; s2 += dv * dv; }
  red[tid] = s2; __syncthreads();
  for (int off = 128; off > 0; off >>= 1) {
    if (tid < off) red[tid] += red[tid+off];
    __syncthreads();
  }
  const float rstd = rsqrtf(red[0] / (float)D + EPS);
  __syncthreads();
  float* po = out + (size_t)row * D;
  for (int i = tid; i < D; i += 256) {
    float v = (buf[i] - mu) * rstd * g[i] + be[i];
    po[i] = v;
    if (out16) out16[(size_t)row * D + i] = f2bf(v);
  }
}

// ----------------------------------------------------------------------------
extern "C" void kernel_launch(void* const* d_in, const int* in_sizes, int n_in,
                              void* d_out, int out_size, void* d_ws, size_t ws_size,
                              hipStream_t stream) {
  const float* x   = (const float*)d_in[0];
  const float* Wq  = (const float*)d_in[1];
  const float* bq  = (const float*)d_in[2];
  const float* Wk  = (const float*)d_in[3];
  const float* bk  = (const float*)d_in[4];
  const float* Wv  = (const float*)d_in[5];
  const float* bv  = (const float*)d_in[6];
  const float* Wo  = (const float*)d_in[7];
  const float* bo  = (const float*)d_in[8];
  const float* g1  = (const float*)d_in[9];
  const float* be1 = (const float*)d_in[10];
  const float* W1  = (const float*)d_in[11];
  const float* b1  = (const float*)d_in[12];
  const float* W2  = (const float*)d_in[13];
  const float* b2  = (const float*)d_in[14];
  const float* g2  = (const float*)d_in[15];
  const float* be2 = (const float*)d_in[16];
  const int*   idx = (const int*)d_in[17];
  float* out = (float*)d_out;

  const size_t SZ = (size_t)B * L * D;            // 4,194,304
  char* p = (char*)d_ws;
  // ---- workspace (stream-ordered lifetimes; see region comments) ----
  // R1 [0, 25165824): A2 (live steps 1-3) -> Wvt/Wot/W1t/W2t (4+)
  unsigned short* A2  = (unsigned short*)p;
  unsigned short* Wvt = (unsigned short*)p;
  unsigned short* Wot = (unsigned short*)(p + 2097152);
  unsigned short* W1t = (unsigned short*)(p + 4194304);
  unsigned short* W2t = (unsigned short*)(p + 12582912);
  // R2 [25165824, 33554432): xb (1-5) -> ctx16 (12-13) -> x1b (14-15)
  unsigned short* xb    = (unsigned short*)(p + 25165824);
  unsigned short* ctx16 = (unsigned short*)(p + 25165824);
  unsigned short* x1b   = (unsigned short*)(p + 25165824);
  // R3 [33554432, 46137344): B2 (2-3) -> scratch (6-11)
  unsigned short* B2 = (unsigned short*)(p + 33554432);
  char* scr = p + 33554432;
  float* Mbuf = (float*)(scr);             // 262,144
  float* csum = (float*)(scr + 262144);    // 262,144
  float* updb = (float*)(scr + 524288);    // 327,680
  int*   Mtop = (int*)  (scr + 860160);    // 5,120 (pad 8192)
  float* pmax = (float*)(scr + 868352);    // 81,920
  float* psum = (float*)(scr + 950272);    // 81,920
  float* pv   = (float*)(scr + 1032192);   // 5,242,880  -> ends 6,275,072 OK
  // R4 [46137344, 79691776): QKb (3-8) -> WoP (13-14) -> ff1b (15-16)
  float* QKb = (float*)(p + 46137344);
  float* WoP = (float*)(p + 46137344);
  unsigned short* ff1b = (unsigned short*)(p + 46137344);
  // R5 [79691776, 113246208): Vp 2x16MB (5-10) -> FFP 2x16MB (16-17)
  float* Vp  = (float*)(p + 79691776);
  float* FFP = (float*)(p + 79691776);
  // R6 [113246208, 130023424): ctxb (10-12) -> x1 (14-17)
  float* ctxb = (float*)(p + 113246208);
  float* x1   = (float*)(p + 113246208);
  // tail: qk bias
  float* qkbias = (float*)(p + 130023424);

  dim3 blk(256);
  const int M = B * L;   // 4096

  // 1) inputs prep
  split_x_f16_kernel<<<(int)(SZ/4 + 255)/256, blk, 0, stream>>>(x, A2, xb);
  // 2) QK weight split
  wsplit_f16_kernel<<<dim3(D/32, D/32), blk, 0, stream>>>(Wq, B2);
  wsplit_f16_kernel<<<dim3(D/32, D/32), blk, 0, stream>>>(Wk, B2 + (size_t)D * LD3);
  concat2_kernel<<<8, blk, 0, stream>>>(bq, bk, qkbias);
  // 3) QK via f16 hi/lo split (fp32-accurate, feeds exact top-k)
  gemm_8ph_kernel<false,false,true,1><<<dim3(LD2/128, M/256), dim3(512), 0, stream>>>(
      A2, B2, qkbias, QKb, M, LD2, LD3);
  // 4) bf16 weight transposes (A2 region dead)
  transpose_bf16_kernel<<<dim3(D/32,  D/32),   blk, 0, stream>>>(Wv, Wvt, D, D);
  transpose_bf16_kernel<<<dim3(D/32,  D/32),   blk, 0, stream>>>(Wo, Wot, D, D);
  transpose_bf16_kernel<<<dim3(FFD/32, D/32),  blk, 0, stream>>>(W1, W1t, D, FFD);
  transpose_bf16_kernel<<<dim3(D/32,  FFD/32), blk, 0, stream>>>(W2, W2t, FFD, D);
  // 5) V projection: bf16, split-K=2 partials (consumers sum them)
  gemm_8ph_kernel<false,false,false,2><<<dim3(D/128, M/256, 2), dim3(512), 0, stream>>>(
      xb, Wvt, nullptr, Vp, M, D, D);
  // 6-9) ProbSparse attention
  prob_m_kernel<<<B*L, blk, 0, stream>>>(QKb, idx, Mbuf);
  topk_kernel<<<B*H, blk, 0, stream>>>(Mbuf, Mtop);
  attn_p1_kernel<<<dim3(NJC, H, B), dim3(320), 0, stream>>>(QKb, Vp, Mtop, pmax, psum, pv);
  attn_p2_kernel<<<B*H*U, dim3(64), 0, stream>>>(pmax, psum, pv, updb);
  // 10) context = cumsum(V) with top-k rows replaced
  cumsum_pass1<<<dim3(D/256, NCHUNK, B), blk, 0, stream>>>(Vp, ctxb, csum);
  cumsum_pass2<<<dim3(D/256, NCHUNK-1, B), blk, 0, stream>>>(ctxb, csum);
  // 11) scatter attn rows
  scatter_kernel<<<(B*H*U*DH + 255)/256, blk, 0, stream>>>(ctxb, updb, Mtop);
  // 12) ctx -> bf16
  cvt_bf16_kernel<<<(int)(SZ/4 + 255)/256, blk, 0, stream>>>(ctxb, ctx16, (int)SZ);
  // 13) Wo projection: split-K=2 partials
  gemm_8ph_kernel<false,false,false,2><<<dim3(D/128, M/256, 2), dim3(512), 0, stream>>>(
      ctx16, Wot, nullptr, WoP, M, D, D);
  // 14) LN1 fused with split-K reduce + bias
  add2_ln_kernel<<<B*L, blk, 0, stream>>>(x, WoP, WoP + SZ, bo, g1, be1, x1, x1b);
  // 15) FF1 (bias+relu in-kernel)
  gemm_8ph_kernel<true,true,false,1><<<dim3(FFD/128, M/256), dim3(512), 0, stream>>>(
      x1b, W1t, b1, ff1b, M, FFD, D);
  // 16) FF2: split-K=2 partials
  gemm_8ph_kernel<false,false,false,2><<<dim3(D/128, M/256, 2), dim3(512), 0, stream>>>(
      ff1b, W2t, nullptr, FFP, M, D, FFD);
  // 17) LN2 fused with split-K reduce + bias
  add2_ln_kernel<<<B*L, blk, 0, stream>>>(x1, FFP, FFP + SZ, b2, g2, be2, out,
                                          (unsigned short*)nullptr);
}

// Round 6
// 407.053 us; speedup vs baseline: 5.2598x; 1.0393x over previous
//
#include <hip/hip_runtime.h>
#include <hip/hip_bf16.h>
#include <hip/hip_fp16.h>
#include <math.h>

constexpr int B = 2, L = 2048, D = 1024, H = 16, DH = 64, FFD = 4096;
constexpr int S = 40;   // sample_k
constexpr int U = 40;   // n_top
constexpr float EPS = 1e-5f;
constexpr int NCHUNK = 32;
constexpr int CHLEN = L / NCHUNK;   // 64
constexpr int LD3 = 3 * D;          // QK split GEMM K' (3072)
constexpr int LD2 = 2 * D;          // QK output row stride
constexpr int JT = 128;             // attn j-chunk
constexpr int NJC = L / JT;         // 16

typedef __attribute__((ext_vector_type(8))) short short8;      // 8 bf16/f16 bits
typedef __attribute__((ext_vector_type(8))) _Float16 half8;
typedef __attribute__((ext_vector_type(4))) float f32x4;

__device__ __forceinline__ unsigned short f2bf(float v) {
  __hip_bfloat16 h = __float2bfloat16(v);
  return __builtin_bit_cast(unsigned short, h);
}
__device__ __forceinline__ float bf2f(unsigned short u) {
  unsigned int x = ((unsigned int)u) << 16;
  return __builtin_bit_cast(float, x);
}
__device__ __forceinline__ unsigned short f2h(float v) {
  __half h = __float2half(v);
  return __builtin_bit_cast(unsigned short, h);
}
__device__ __forceinline__ float h2f(unsigned short u) {
  return __half2float(__builtin_bit_cast(__half, u));
}

__device__ __forceinline__ void gload16(const void* g, void* l) {
  __builtin_amdgcn_global_load_lds(
      (const __attribute__((address_space(1))) void*)g,
      (__attribute__((address_space(3))) void*)l, 16, 0, 0);
}

// ======== pipelined MFMA GEMM: 256x128 tile, BK=64, triple-buffered LDS, ====
// counted vmcnt (never drained in-loop), 2 sub-phases per K-tile (T3 role
// split: {stage-half || 8 ds_reads -> barrier-paired 16-MFMA cluster} x2),
// T5 setprio, T2 source-side XOR swizzle, XCD-aware block swizzle.
// SPLITK>1: blockIdx.z owns a K-slice, writes fp32 partial to C + z*M*N.
template<bool RELU, bool OUT_BF16, bool F16, int SPLITK>
__global__ __launch_bounds__(512, 2) void gemm_8ph_kernel(
    const unsigned short* __restrict__ A,    // [M][K] bits
    const unsigned short* __restrict__ Bt,   // [N][K] bits
    const float* __restrict__ bias,          // [N] (SPLITK==1 only)
    void* __restrict__ C, int M, int N, int K) {
  constexpr int GBM = 256, GBN = 128, GBK = 64;
  constexpr int ABUF = GBM * GBK;    // 16384 shorts
  constexpr int BBUF = GBN * GBK;    // 8192 shorts
  constexpr int BUFS = ABUF + BBUF;  // 24576 shorts
  __shared__ short lds[3 * BUFS];    // 144 KB

  const int tid  = threadIdx.x;
  const int lane = tid & 63;
  const int wid  = tid >> 6;          // 0..7
  const int wr = wid >> 1;            // 0..3  (64-row band of A)
  const int wc = wid & 1;             // 0..1  (64-col band of B)

  // XCD-aware bijective block swizzle (nwg % 8 == 0 for all our shapes)
  const int nwg  = gridDim.x * gridDim.y;
  const int orig = blockIdx.y * gridDim.x + blockIdx.x;
  const int wg   = (orig & 7) * (nwg >> 3) + (orig >> 3);
  const int bm = (wg / gridDim.x) * GBM;
  const int bn = (wg % gridDim.x) * GBN;

  const int kslice = K / SPLITK;
  const int kbase  = (SPLITK > 1) ? blockIdx.z * kslice : 0;

  // staging: lane covers row (wid*8 + lane>>3) (+ r*64 per round),
  // physical 16B slot (lane&7) holds logical slot (lane&7)^(row&7)  [T2/G21]
  const int srow  = lane >> 3;                 // 0..7 == row&7
  const int sslot = (lane & 7) ^ srow;         // pre-swizzled source slot
  const unsigned short* aS = A  + (size_t)(bm + wid * 8 + srow) * K + kbase + sslot * 8;
  const unsigned short* bS = Bt + (size_t)(bn + wid * 8 + srow) * K + kbase + sslot * 8;
  short* ldsAst = lds + wid * 8 * GBK;
  short* ldsBst = lds + ABUF + wid * 8 * GBK;

  auto STAGE_H1 = [&](int buf, int kt) {       // 3 vmem ops (A rows 0,64,128)
    const unsigned short* ap = aS + (size_t)kt * GBK;
    short* la = ldsAst + buf * BUFS;
    gload16(ap,                   la);
    gload16(ap + (size_t)64 * K,  la + 64 * GBK);
    gload16(ap + (size_t)128 * K, la + 128 * GBK);
  };
  auto STAGE_H2 = [&](int buf, int kt) {       // 3 vmem ops (A row 192, B 0,64)
    const unsigned short* ap = aS + (size_t)kt * GBK;
    const unsigned short* bp = bS + (size_t)kt * GBK;
    short* la = ldsAst + buf * BUFS;
    short* lb = ldsBst + buf * BUFS;
    gload16(ap + (size_t)192 * K, la + 192 * GBK);
    gload16(bp,                   lb);
    gload16(bp + (size_t)64 * K,  lb + 64 * GBK);
  };

  const int fr = lane & 15, g = lane >> 4;
  const int nt = kslice / GBK;

  STAGE_H1(0, 0); STAGE_H2(0, 0);
  STAGE_H1(1, 1); STAGE_H2(1, 1);

  f32x4 acc[4][4] = {};
  int bc = 0;
  for (int t = 0; t < nt; ++t) {
    const int bs = (bc + 2 >= 3) ? bc - 1 : bc + 2;   // (bc+2)%3
    const int kt = (t + 2 < nt) ? t + 2 : nt - 1;     // clamp keeps vmcnt uniform
    const short* la = lds + bc * BUFS;
    const short* lb = la + ABUF;

    // ---- phase 0 (kk = 0) ----
    STAGE_H1(bs, kt);                                 // 3 in flight on top
    asm volatile("s_waitcnt vmcnt(9)" ::: "memory");  // tile t landed; t+1 (6) + h1 (3) in flight
    __builtin_amdgcn_sched_barrier(0);
    __builtin_amdgcn_s_barrier();
    {
      short8 av[4], bv[4];
      #pragma unroll
      for (int mi = 0; mi < 4; ++mi) {
        const int row = wr * 64 + mi * 16 + fr;
        av[mi] = *(const short8*)&la[row * GBK + ((g ^ (fr & 7)) << 3)];
      }
      #pragma unroll
      for (int ni = 0; ni < 4; ++ni) {
        const int row = wc * 64 + ni * 16 + fr;
        bv[ni] = *(const short8*)&lb[row * GBK + ((g ^ (fr & 7)) << 3)];
      }
      __builtin_amdgcn_s_setprio(1);
      #pragma unroll
      for (int mi = 0; mi < 4; ++mi)
        #pragma unroll
        for (int ni = 0; ni < 4; ++ni) {
          if constexpr (F16)
            acc[mi][ni] = __builtin_amdgcn_mfma_f32_16x16x32_f16(
                __builtin_bit_cast(half8, av[mi]),
                __builtin_bit_cast(half8, bv[ni]), acc[mi][ni], 0, 0, 0);
          else
            acc[mi][ni] = __builtin_amdgcn_mfma_f32_16x16x32_bf16(
                av[mi], bv[ni], acc[mi][ni], 0, 0, 0);
        }
      __builtin_amdgcn_s_setprio(0);
    }
    __builtin_amdgcn_s_barrier();

    // ---- phase 1 (kk = 1) ----
    STAGE_H2(bs, kt);
    {
      short8 av[4], bv[4];
      #pragma unroll
      for (int mi = 0; mi < 4; ++mi) {
        const int row = wr * 64 + mi * 16 + fr;
        av[mi] = *(const short8*)&la[row * GBK + (((4 | g) ^ (fr & 7)) << 3)];
      }
      #pragma unroll
      for (int ni = 0; ni < 4; ++ni) {
        const int row = wc * 64 + ni * 16 + fr;
        bv[ni] = *(const short8*)&lb[row * GBK + (((4 | g) ^ (fr & 7)) << 3)];
      }
      __builtin_amdgcn_s_setprio(1);
      #pragma unroll
      for (int mi = 0; mi < 4; ++mi)
        #pragma unroll
        for (int ni = 0; ni < 4; ++ni) {
          if constexpr (F16)
            acc[mi][ni] = __builtin_amdgcn_mfma_f32_16x16x32_f16(
                __builtin_bit_cast(half8, av[mi]),
                __builtin_bit_cast(half8, bv[ni]), acc[mi][ni], 0, 0, 0);
          else
            acc[mi][ni] = __builtin_amdgcn_mfma_f32_16x16x32_bf16(
                av[mi], bv[ni], acc[mi][ni], 0, 0, 0);
        }
      __builtin_amdgcn_s_setprio(0);
    }
    asm volatile("s_waitcnt lgkmcnt(0)" ::: "memory"); // this wave's bc reads retired
    __builtin_amdgcn_sched_barrier(0);
    __builtin_amdgcn_s_barrier();                      // all waves done with bc
    bc = (bc + 1 == 3) ? 0 : bc + 1;
  }

  // epilogue: C/D layout col=lane&15, row=(lane>>4)*4+reg  [m89/m91 verified]
  #pragma unroll
  for (int ni = 0; ni < 4; ++ni) {
    const int col = bn + wc * 64 + ni * 16 + fr;
    float bcol = 0.f;
    if constexpr (SPLITK == 1) bcol = bias[col];
    #pragma unroll
    for (int mi = 0; mi < 4; ++mi) {
      #pragma unroll
      for (int j = 0; j < 4; ++j) {
        const int rowg = bm + wr * 64 + mi * 16 + (g << 2) + j;
        if constexpr (SPLITK > 1) {
          float* Cp = (float*)C + (size_t)blockIdx.z * M * N;
          Cp[(size_t)rowg * N + col] = acc[mi][ni][j];
        } else {
          float v = acc[mi][ni][j] + bcol;
          if (RELU) v = fmaxf(v, 0.f);
          if (OUT_BF16) ((unsigned short*)C)[(size_t)rowg * N + col] = f2bf(v);
          else          ((float*)C)[(size_t)rowg * N + col] = v;
        }
      }
    }
  }
}

// ---- x[M][D] f32 -> A2[M][3D] f16 [hi|hi|lo]  AND  xb[M][D] bf16 -----------
__global__ __launch_bounds__(256) void split_x_f16_kernel(
    const float* __restrict__ x, unsigned short* __restrict__ A2,
    unsigned short* __restrict__ xb) {
  const int i = (blockIdx.x * 256 + threadIdx.x) * 4;
  if (i >= B * L * D) return;
  const int m = i / D, k = i % D;
  const float4 v = *(const float4*)(x + i);
  ushort4 hi, lo, bb;
  hi.x = f2h(v.x); lo.x = f2h(v.x - h2f(hi.x)); bb.x = f2bf(v.x);
  hi.y = f2h(v.y); lo.y = f2h(v.y - h2f(hi.y)); bb.y = f2bf(v.y);
  hi.z = f2h(v.z); lo.z = f2h(v.z - h2f(hi.z)); bb.z = f2bf(v.z);
  hi.w = f2h(v.w); lo.w = f2h(v.w - h2f(hi.w)); bb.w = f2bf(v.w);
  unsigned short* row = A2 + (size_t)m * LD3;
  *(ushort4*)(row + k)         = hi;
  *(ushort4*)(row + D + k)     = hi;
  *(ushort4*)(row + 2 * D + k) = lo;
  *(ushort4*)(xb + i) = bb;
}

// ------ W[D][D] f32 -> B2rows[n][3D] f16 bits: [hi(k) | lo(k) | hi(k)] ------
__global__ __launch_bounds__(256) void wsplit_f16_kernel(
    const float* __restrict__ W, unsigned short* __restrict__ B2r) {
  __shared__ float tile[32][33];
  const int bx = blockIdx.x * 32;   // n
  const int by = blockIdx.y * 32;   // k
  const int tx = threadIdx.x & 31, ty = threadIdx.x >> 5;
  #pragma unroll
  for (int i = ty; i < 32; i += 8)
    tile[i][tx] = W[(size_t)(by + i) * D + bx + tx];
  __syncthreads();
  #pragma unroll
  for (int i = ty; i < 32; i += 8) {
    const float v = tile[tx][i];    // W[by+tx][bx+i]
    const unsigned short hi = f2h(v);
    const unsigned short lo = f2h(v - h2f(hi));
    unsigned short* r = B2r + (size_t)(bx + i) * LD3 + (by + tx);
    r[0]     = hi;
    r[D]     = lo;
    r[2 * D] = hi;
  }
}

// ----------- W[K][N] fp32 -> Wt[N][K] bf16 (transpose + convert) ------------
__global__ __launch_bounds__(256) void transpose_bf16_kernel(
    const float* __restrict__ W, unsigned short* __restrict__ Wt, int K, int N) {
  __shared__ float tile[32][33];
  const int bx = blockIdx.x * 32;
  const int by = blockIdx.y * 32;
  const int tx = threadIdx.x & 31, ty = threadIdx.x >> 5;
  #pragma unroll
  for (int i = ty; i < 32; i += 8)
    tile[i][tx] = W[(size_t)(by + i) * N + bx + tx];
  __syncthreads();
  #pragma unroll
  for (int i = ty; i < 32; i += 8)
    Wt[(size_t)(bx + i) * K + by + tx] = f2bf(tile[tx][i]);
}

// ------------------ concat 2 bias vectors of length D -----------------------
__global__ __launch_bounds__(256) void concat2_kernel(
    const float* __restrict__ a, const float* __restrict__ b, float* __restrict__ o) {
  const int i = blockIdx.x * 256 + threadIdx.x;
  if (i < D) o[i] = a[i];
  else if (i < 2 * D) o[i] = b[i - D];
}

// ------------- M[b,h,l] = max_s(Q[l]·K[idx[l,s]]) - sum_s(...)/L ------------
__global__ __launch_bounds__(256) void prob_m_kernel(
    const float* __restrict__ QK, const int* __restrict__ idx,
    float* __restrict__ M_) {
  const int bl = blockIdx.x;
  const int b = bl / L, l = bl % L;
  const int tid = threadIdx.x;
  __shared__ float dots[H][S];
  __shared__ int sidx[S];
  if (tid < S) sidx[tid] = idx[l * S + tid];
  __syncthreads();
  const int h = tid >> 4;
  const int dsub = (tid & 15) * 4;
  float4 q = *(const float4*)(QK + (size_t)bl * LD2 + h * DH + dsub);
  for (int s = 0; s < S; ++s) {
    const float4 kv = *(const float4*)(QK + ((size_t)b * L + sidx[s]) * LD2 + D + h * DH + dsub);
    float p = q.x*kv.x + q.y*kv.y + q.z*kv.z + q.w*kv.w;
    p += __shfl_xor(p, 1);
    p += __shfl_xor(p, 2);
    p += __shfl_xor(p, 4);
    p += __shfl_xor(p, 8);
    if ((tid & 15) == 0) dots[h][s] = p;
  }
  __syncthreads();
  if (tid < H) {
    float mx = -INFINITY, sm = 0.f;
    for (int s = 0; s < S; ++s) { float v = dots[tid][s]; mx = fmaxf(mx, v); sm += v; }
    M_[((size_t)b * H + tid) * L + l] = mx - sm / (float)L;
  }
}

// ---------- exact top-k (k=40, n=2048), register-resident argmax ------------
__global__ __launch_bounds__(256) void topk_kernel(
    const float* __restrict__ M_, int* __restrict__ Mtop) {
  const int bh = blockIdx.x;
  const float* row = M_ + (size_t)bh * L;
  const int tid = threadIdx.x;
  const int lane = tid & 63, w = tid >> 6;
  float v[8];
  #pragma unroll
  for (int k = 0; k < 8; ++k) v[k] = row[tid + k * 256];
  __shared__ float wv[4];
  __shared__ int   wi[4];
  __shared__ int   winner;
  for (int u = 0; u < U; ++u) {
    float best = v[0]; int bk = 0;
    #pragma unroll
    for (int k = 1; k < 8; ++k)
      if (v[k] > best) { best = v[k]; bk = k; }          // strict >: lower index wins
    int bidx = bk * 256 + tid;
    #pragma unroll
    for (int off = 1; off < 64; off <<= 1) {
      const float ov = __shfl_xor(best, off);
      const int   oi = __shfl_xor(bidx, off);
      if (ov > best || (ov == best && oi < bidx)) { best = ov; bidx = oi; }
    }
    if (lane == 0) { wv[w] = best; wi[w] = bidx; }
    __syncthreads();
    if (tid == 0) {
      float bb = wv[0]; int bi = wi[0];
      #pragma unroll
      for (int q2 = 1; q2 < 4; ++q2)
        if (wv[q2] > bb || (wv[q2] == bb && wi[q2] < bi)) { bb = wv[q2]; bi = wi[q2]; }
      Mtop[bh * U + u] = bi;
      winner = bi;
    }
    __syncthreads();
    const int wn = winner;
    if ((wn & 255) == tid) {
      const int kk = wn >> 8;
      #pragma unroll
      for (int k = 0; k < 8; ++k) if (k == kk) v[k] = -INFINITY;   // static idx
    }
  }
}

// ------- attn phase 1: per (b,h,jc) partial softmax + PV over 128 keys ------
// V comes as two split-K partials (Vp0 + Vp1), summed at stage time.
__global__ __launch_bounds__(320) void attn_p1_kernel(
    const float* __restrict__ QK, const float* __restrict__ Vp,
    const int* __restrict__ Mtop,
    float* __restrict__ pmax, float* __restrict__ psum, float* __restrict__ pv) {
  const int jc = blockIdx.x, h = blockIdx.y, b = blockIdx.z;
  const int bh = b * H + h;
  const int tid = threadIdx.x;
  const int j0 = jc * JT;
  const float* Vp1 = Vp + (size_t)B * L * D;
  __shared__ float Qs[U][68];
  __shared__ float KVs[JT][68];
  __shared__ unsigned short ws[U][JT];

  for (int i = tid; i < U * 16; i += 320) {
    const int u = i >> 4, dq = (i & 15) << 2;
    const int row = Mtop[bh * U + u];
    *(float4*)&Qs[u][dq] =
        *(const float4*)(QK + ((size_t)b * L + row) * LD2 + h * DH + dq);
  }
  for (int i = tid; i < JT * 16; i += 320) {
    const int j = i >> 4, dq = (i & 15) << 2;
    *(float4*)&KVs[j][dq] =
        *(const float4*)(QK + ((size_t)b * L + j0 + j) * LD2 + D + h * DH + dq);
  }
  __syncthreads();

  const int u = tid >> 3, jg = tid & 7;
  const int mt = Mtop[bh * U + u];
  float sc[16];
  #pragma unroll
  for (int jt = 0; jt < 16; ++jt) sc[jt] = 0.f;
  for (int dq = 0; dq < 64; dq += 4) {
    const float4 q = *(const float4*)&Qs[u][dq];
    #pragma unroll
    for (int jt = 0; jt < 16; ++jt) {
      const float4 k = *(const float4*)&KVs[jt * 8 + jg][dq];
      sc[jt] += q.x*k.x + q.y*k.y + q.z*k.z + q.w*k.w;
    }
  }
  float m = -INFINITY;
  #pragma unroll
  for (int jt = 0; jt < 16; ++jt) {
    const int j = j0 + jt * 8 + jg;
    sc[jt] = (j <= mt) ? sc[jt] * 0.125f : -INFINITY;
    m = fmaxf(m, sc[jt]);
  }
  m = fmaxf(m, __shfl_xor(m, 1));
  m = fmaxf(m, __shfl_xor(m, 2));
  m = fmaxf(m, __shfl_xor(m, 4));
  float sum = 0.f;
  #pragma unroll
  for (int jt = 0; jt < 16; ++jt) {
    const float e = (sc[jt] == -INFINITY) ? 0.f : expf(sc[jt] - m);
    sum += e;
    ws[u][jt * 8 + jg] = f2bf(e);
  }
  sum += __shfl_xor(sum, 1);
  sum += __shfl_xor(sum, 2);
  sum += __shfl_xor(sum, 4);
  if (jg == 0) {
    pmax[(size_t)(bh * NJC + jc) * U + u] = m;
    psum[(size_t)(bh * NJC + jc) * U + u] = sum;
  }
  __syncthreads();
  // reload LDS with V chunk (sum of split-K partials)
  for (int i = tid; i < JT * 16; i += 320) {
    const int j = i >> 4, dq = (i & 15) << 2;
    const size_t off = ((size_t)b * L + j0 + j) * D + h * DH + dq;
    const float4 a = *(const float4*)(Vp + off);
    const float4 c = *(const float4*)(Vp1 + off);
    float4 r; r.x = a.x + c.x; r.y = a.y + c.y; r.z = a.z + c.z; r.w = a.w + c.w;
    *(float4*)&KVs[j][dq] = r;
  }
  __syncthreads();
  const int d = tid & 63, ug = tid >> 6;
  float acc[8] = {};
  for (int j = 0; j < JT; j += 2) {
    const float v0 = KVs[j][d], v1 = KVs[j + 1][d];
    #pragma unroll
    for (int k = 0; k < 8; ++k) {
      const int uu = ug + k * 5;
      const unsigned int wp = *(const unsigned int*)&ws[uu][j];
      acc[k] = fmaf(bf2f((unsigned short)(wp & 0xffff)), v0, acc[k]);
      acc[k] = fmaf(bf2f((unsigned short)(wp >> 16)), v1, acc[k]);
    }
  }
  #pragma unroll
  for (int k = 0; k < 8; ++k) {
    const int uu = ug + k * 5;
    pv[((size_t)(bh * NJC + jc) * U + uu) * DH + d] = acc[k];
  }
}

// -- attn phase 2: combine 16 chunks per (b,h,u), scatter into ctx16 (bf16) --
__global__ __launch_bounds__(64) void attn_p2_kernel(
    const float* __restrict__ pmax, const float* __restrict__ psum,
    const float* __restrict__ pv, const int* __restrict__ Mtop,
    unsigned short* __restrict__ ctx16) {
  const int bid = blockIdx.x;          // bh*U + u
  const int u = bid % U, bh = bid / U;
  const int d = threadIdx.x;
  float gmax = -INFINITY;
  for (int c = 0; c < NJC; ++c)
    gmax = fmaxf(gmax, pmax[(size_t)(bh * NJC + c) * U + u]);
  float den = 0.f, num = 0.f;
  for (int c = 0; c < NJC; ++c) {
    const float m = pmax[(size_t)(bh * NJC + c) * U + u];
    if (m == -INFINITY) continue;
    const float s = expf(m - gmax);
    den += psum[(size_t)(bh * NJC + c) * U + u] * s;
    num += pv[((size_t)(bh * NJC + c) * U + u) * DH + d] * s;
  }
  const int h = bh % H, b = bh / H;
  const int l = Mtop[bh * U + u];
  ctx16[((size_t)b * L + l) * D + h * DH + d] = f2bf(num / den);
}

// -------------- cumsum(V) over l, two-pass (V = Vp0 + Vp1) ------------------
__global__ __launch_bounds__(256) void cumsum_pass1(
    const float* __restrict__ Vp, float* __restrict__ ctx, float* __restrict__ csums) {
  const int c = blockIdx.x * 256 + threadIdx.x;
  const int ch = blockIdx.y, b = blockIdx.z;
  const float* Vp1 = Vp + (size_t)B * L * D;
  size_t base = ((size_t)b * L + (size_t)ch * CHLEN) * D + c;
  float acc = 0.f;
  for (int i = 0; i < CHLEN; ++i) {
    const size_t o = base + (size_t)i * D;
    acc += Vp[o] + Vp1[o];
    ctx[o] = acc;
  }
  csums[((size_t)b * NCHUNK + ch) * D + c] = acc;
}

// pass2 covers ALL chunks (ch=0 has zero offset) and emits bf16 ctx directly.
__global__ __launch_bounds__(256) void cumsum_pass2(
    const float* __restrict__ ctx, const float* __restrict__ csums,
    unsigned short* __restrict__ ctx16) {
  const int c = blockIdx.x * 256 + threadIdx.x;
  const int ch = blockIdx.y, b = blockIdx.z;
  float off = 0.f;
  for (int j = 0; j < ch; ++j) off += csums[((size_t)b * NCHUNK + j) * D + c];
  size_t base = ((size_t)b * L + (size_t)ch * CHLEN) * D + c;
  for (int i = 0; i < CHLEN; ++i) {
    const size_t o = base + (size_t)i * D;
    ctx16[o] = f2bf(ctx[o] + off);
  }
}

// -- out = LayerNorm(a + p0 + p1 + bias) * g + be  (+ optional bf16 copy) ----
__global__ __launch_bounds__(256) void add2_ln_kernel(
    const float* __restrict__ a, const float* __restrict__ p0,
    const float* __restrict__ p1, const float* __restrict__ bias,
    const float* __restrict__ g, const float* __restrict__ be,
    float* __restrict__ out, unsigned short* __restrict__ out16) {
  const int row = blockIdx.x;
  const int tid = threadIdx.x;
  __shared__ float buf[D];
  __shared__ float red[256];
  const float* pa = a  + (size_t)row * D;
  const float* q0 = p0 + (size_t)row * D;
  const float* q1 = p1 + (size_t)row * D;
  float s = 0.f;
  for (int i = tid; i < D; i += 256) {
    float v = pa[i] + q0[i] + q1[i] + bias[i];
    buf[i] = v; s += v;
  }
  red[tid] = s; __syncthreads();
  for (int off = 128; off > 0; off >>= 1) {
    if (tid < off) red[tid] += red[tid+off];
    __syncthreads();
  }
  const float mu = red[0] / (float)D;
  __syncthreads();
  float s2 = 0.f;
  for (int i = tid; i < D; i += 256) { float dv = buf[i] - mu; s2 += dv * dv; }
  red[tid] = s2; __syncthreads();
  for (int off = 128; off > 0; off >>= 1) {
    if (tid < off) red[tid] += red[tid+off];
    __syncthreads();
  }
  const float rstd = rsqrtf(red[0] / (float)D + EPS);
  __syncthreads();
  float* po = out + (size_t)row * D;
  for (int i = tid; i < D; i += 256) {
    float v = (buf[i] - mu) * rstd * g[i] + be[i];
    po[i] = v;
    if (out16) out16[(size_t)row * D + i] = f2bf(v);
  }
}

// ----------------------------------------------------------------------------
extern "C" void kernel_launch(void* const* d_in, const int* in_sizes, int n_in,
                              void* d_out, int out_size, void* d_ws, size_t ws_size,
                              hipStream_t stream) {
  const float* x   = (const float*)d_in[0];
  const float* Wq  = (const float*)d_in[1];
  const float* bq  = (const float*)d_in[2];
  const float* Wk  = (const float*)d_in[3];
  const float* bk  = (const float*)d_in[4];
  const float* Wv  = (const float*)d_in[5];
  const float* bv  = (const float*)d_in[6];
  const float* Wo  = (const float*)d_in[7];
  const float* bo  = (const float*)d_in[8];
  const float* g1  = (const float*)d_in[9];
  const float* be1 = (const float*)d_in[10];
  const float* W1  = (const float*)d_in[11];
  const float* b1  = (const float*)d_in[12];
  const float* W2  = (const float*)d_in[13];
  const float* b2  = (const float*)d_in[14];
  const float* g2  = (const float*)d_in[15];
  const float* be2 = (const float*)d_in[16];
  const int*   idx = (const int*)d_in[17];
  float* out = (float*)d_out;

  const size_t SZ = (size_t)B * L * D;            // 4,194,304
  char* p = (char*)d_ws;
  // ---- workspace (stream-ordered lifetimes; see region comments) ----
  // R1 [0, 25165824): A2 (steps 1-3) -> Wvt/Wot/W1t/W2t (4+)
  unsigned short* A2  = (unsigned short*)p;
  unsigned short* Wvt = (unsigned short*)p;
  unsigned short* Wot = (unsigned short*)(p + 2097152);
  unsigned short* W1t = (unsigned short*)(p + 4194304);
  unsigned short* W2t = (unsigned short*)(p + 12582912);
  // R2 [25165824, 33554432): xb (1-5) -> ctx16 (10-12) -> x1b (13-14)
  unsigned short* xb    = (unsigned short*)(p + 25165824);
  unsigned short* ctx16 = (unsigned short*)(p + 25165824);
  unsigned short* x1b   = (unsigned short*)(p + 25165824);
  // R3 [33554432, 46137344): B2 (2-3) -> scratch (6-11)
  unsigned short* B2 = (unsigned short*)(p + 33554432);
  char* scr = p + 33554432;
  float* Mbuf = (float*)(scr);             // 262,144
  float* csum = (float*)(scr + 262144);    // 262,144
  int*   Mtop = (int*)  (scr + 524288);    // 5,120 (pad 8192)
  float* pmax = (float*)(scr + 532480);    // 81,920
  float* psum = (float*)(scr + 614400);    // 81,920
  float* pv   = (float*)(scr + 696320);    // 5,242,880 -> ends 5,939,200 OK
  // R4 [46137344, 79691776): QKb (3-8) -> WoP (12-13) -> ff1b (14-15)
  float* QKb = (float*)(p + 46137344);
  float* WoP = (float*)(p + 46137344);
  unsigned short* ff1b = (unsigned short*)(p + 46137344);
  // R5 [79691776, 113246208): Vp 2x16MB (5-9) -> FFP 2x16MB (15-16)
  float* Vp  = (float*)(p + 79691776);
  float* FFP = (float*)(p + 79691776);
  // R6 [113246208, 130023424): ctxb f32 partial-cumsum (9-10) -> x1 (13-16)
  float* ctxb = (float*)(p + 113246208);
  float* x1   = (float*)(p + 113246208);
  // tail: qk bias
  float* qkbias = (float*)(p + 130023424);

  dim3 blk(256);
  const int M = B * L;   // 4096

  // 1) inputs prep
  split_x_f16_kernel<<<(int)(SZ/4 + 255)/256, blk, 0, stream>>>(x, A2, xb);
  // 2) QK weight split
  wsplit_f16_kernel<<<dim3(D/32, D/32), blk, 0, stream>>>(Wq, B2);
  wsplit_f16_kernel<<<dim3(D/32, D/32), blk, 0, stream>>>(Wk, B2 + (size_t)D * LD3);
  concat2_kernel<<<8, blk, 0, stream>>>(bq, bk, qkbias);
  // 3) QK via f16 hi/lo split (fp32-accurate, feeds exact top-k)
  gemm_8ph_kernel<false,false,true,1><<<dim3(LD2/128, M/256), dim3(512), 0, stream>>>(
      A2, B2, qkbias, QKb, M, LD2, LD3);
  // 4) bf16 weight transposes (A2 region dead)
  transpose_bf16_kernel<<<dim3(D/32,  D/32),   blk, 0, stream>>>(Wv, Wvt, D, D);
  transpose_bf16_kernel<<<dim3(D/32,  D/32),   blk, 0, stream>>>(Wo, Wot, D, D);
  transpose_bf16_kernel<<<dim3(FFD/32, D/32),  blk, 0, stream>>>(W1, W1t, D, FFD);
  transpose_bf16_kernel<<<dim3(D/32,  FFD/32), blk, 0, stream>>>(W2, W2t, FFD, D);
  // 5) V projection: bf16, split-K=2 partials (consumers sum them)
  gemm_8ph_kernel<false,false,false,2><<<dim3(D/128, M/256, 2), dim3(512), 0, stream>>>(
      xb, Wvt, nullptr, Vp, M, D, D);
  // 6-8) ProbSparse attention scoring
  prob_m_kernel<<<B*L, blk, 0, stream>>>(QKb, idx, Mbuf);
  topk_kernel<<<B*H, blk, 0, stream>>>(Mbuf, Mtop);
  attn_p1_kernel<<<dim3(NJC, H, B), dim3(320), 0, stream>>>(QKb, Vp, Mtop, pmax, psum, pv);
  // 9-10) context = cumsum(V), emitted directly as bf16
  cumsum_pass1<<<dim3(D/256, NCHUNK, B), blk, 0, stream>>>(Vp, ctxb, csum);
  cumsum_pass2<<<dim3(D/256, NCHUNK, B), blk, 0, stream>>>(ctxb, csum, ctx16);
  // 11) attn combine + scatter into ctx16
  attn_p2_kernel<<<B*H*U, dim3(64), 0, stream>>>(pmax, psum, pv, Mtop, ctx16);
  // 12) Wo projection: split-K=2 partials
  gemm_8ph_kernel<false,false,false,2><<<dim3(D/128, M/256, 2), dim3(512), 0, stream>>>(
      ctx16, Wot, nullptr, WoP, M, D, D);
  // 13) LN1 fused with split-K reduce + bias
  add2_ln_kernel<<<B*L, blk, 0, stream>>>(x, WoP, WoP + SZ, bo, g1, be1, x1, x1b);
  // 14) FF1 (bias+relu in-kernel)
  gemm_8ph_kernel<true,true,false,1><<<dim3(FFD/128, M/256), dim3(512), 0, stream>>>(
      x1b, W1t, b1, ff1b, M, FFD, D);
  // 15) FF2: split-K=2 partials
  gemm_8ph_kernel<false,false,false,2><<<dim3(D/128, M/256, 2), dim3(512), 0, stream>>>(
      ff1b, W2t, nullptr, FFP, M, D, FFD);
  // 16) LN2 fused with split-K reduce + bias
  add2_ln_kernel<<<B*L, blk, 0, stream>>>(x1, FFP, FFP + SZ, b2, g2, be2, out,
                                          (unsigned short*)nullptr);
}

// Round 8
// 397.436 us; speedup vs baseline: 5.3871x; 1.0242x over previous
//
#include <hip/hip_runtime.h>
#include <hip/hip_bf16.h>
#include <hip/hip_fp16.h>
#include <math.h>

constexpr int B = 2, L = 2048, D = 1024, H = 16, DH = 64, FFD = 4096;
constexpr int S = 40;   // sample_k
constexpr int U = 40;   // n_top
constexpr float EPS = 1e-5f;
constexpr int NCHUNK = 32;
constexpr int CHLEN = L / NCHUNK;   // 64
constexpr int LD3 = 3 * D;          // QK split GEMM K' (3072)
constexpr int LD2 = 2 * D;          // QK output row stride
constexpr int LDA2 = 2 * D;         // A2 row stride [hi|lo]
constexpr int JT = 128;             // attn j-chunk
constexpr int NJC = L / JT;         // 16

typedef __attribute__((ext_vector_type(8))) short short8;      // 8 bf16/f16 bits
typedef __attribute__((ext_vector_type(8))) _Float16 half8;
typedef __attribute__((ext_vector_type(4))) float f32x4;

__device__ __forceinline__ unsigned short f2bf(float v) {
  __hip_bfloat16 h = __float2bfloat16(v);
  return __builtin_bit_cast(unsigned short, h);
}
__device__ __forceinline__ float bf2f(unsigned short u) {
  unsigned int x = ((unsigned int)u) << 16;
  return __builtin_bit_cast(float, x);
}
__device__ __forceinline__ unsigned short f2h(float v) {
  __half h = __float2half(v);
  return __builtin_bit_cast(unsigned short, h);
}
__device__ __forceinline__ float h2f(unsigned short u) {
  return __half2float(__builtin_bit_cast(__half, u));
}

__device__ __forceinline__ void gload16(const void* g, void* l) {
  __builtin_amdgcn_global_load_lds(
      (const __attribute__((address_space(1))) void*)g,
      (__attribute__((address_space(3))) void*)l, 16, 0, 0);
}

// ======== pipelined MFMA GEMM: 128x128 tile, BK=64, DOUBLE-buffered LDS =====
// (64 KB -> 2 blocks/CU; cross-block overlap hides LDS-read vs MFMA), counted
// vmcnt(8), raw s_barrier, T2 source-side XOR swizzle, T5 setprio, XCD swizzle.
// DUPA: A has K/3 duplicated layout [hi|lo] (KA=2K/3); K-tiles [16,32) re-read
// the hi columns (QK 3-term f16 split: hi*Whi + hi*Wlo + lo*Whi).
template<bool RELU, bool OUT_BF16, bool F16, bool DUPA>
__global__ __launch_bounds__(256, 2) void gemm128_kernel(
    const unsigned short* __restrict__ A,    // [M][KA] bits
    const unsigned short* __restrict__ Bt,   // [N][K] bits
    const float* __restrict__ bias,          // [N]
    void* __restrict__ C, int M, int N, int K, int KA) {
  constexpr int GBM = 128, GBN = 128, GBK = 64;
  constexpr int ABUF = GBM * GBK;    // 8192 shorts
  constexpr int BUFS = 2 * ABUF;     // A+B = 16384 shorts (32 KB)
  __shared__ short lds[2 * BUFS];    // 64 KB -> 2 blocks/CU

  const int tid  = threadIdx.x;
  const int lane = tid & 63;
  const int wid  = tid >> 6;          // 0..3
  const int wr = wid >> 1;            // 0..1 (64-row band)
  const int wc = wid & 1;             // 0..1 (64-col band)

  // XCD-aware bijective block swizzle (nwg % 8 == 0 for all our shapes)
  const int nwg  = gridDim.x * gridDim.y;
  const int orig = blockIdx.y * gridDim.x + blockIdx.x;
  const int wg   = (orig & 7) * (nwg >> 3) + (orig >> 3);
  const int bm = (wg / gridDim.x) * GBM;
  const int bn = (wg % gridDim.x) * GBN;

  // staging: wave w covers rows w*8 + (lane>>3) (+32 per issue),
  // physical 16B slot (lane&7) holds logical slot (lane&7)^(row&7)  [T2/G21]
  const int srow  = lane >> 3;                 // 0..7 == row&7
  const int sslot = (lane & 7) ^ srow;         // pre-swizzled source slot
  const unsigned short* aS = A  + (size_t)(bm + wid * 8 + srow) * KA + sslot * 8;
  const unsigned short* bS = Bt + (size_t)(bn + wid * 8 + srow) * K  + sslot * 8;
  short* la0 = lds + wid * 8 * GBK;
  short* lb0 = lds + ABUF + wid * 8 * GBK;

  auto STAGE = [&](int buf, int kt) {          // 8 vmem ops / thread / tile
    const int akt = (DUPA && kt >= 16) ? kt - 16 : kt;
    const unsigned short* ap = aS + (size_t)akt * GBK;
    const unsigned short* bp = bS + (size_t)kt  * GBK;
    short* la = la0 + buf * BUFS;
    short* lb = lb0 + buf * BUFS;
    gload16(ap,                   la);
    gload16(ap + (size_t)32 * KA, la + 32 * GBK);
    gload16(ap + (size_t)64 * KA, la + 64 * GBK);
    gload16(ap + (size_t)96 * KA, la + 96 * GBK);
    gload16(bp,                   lb);
    gload16(bp + (size_t)32 * K,  lb + 32 * GBK);
    gload16(bp + (size_t)64 * K,  lb + 64 * GBK);
    gload16(bp + (size_t)96 * K,  lb + 96 * GBK);
  };

  const int fr = lane & 15, g = lane >> 4;
  const int nt = K / GBK;

  STAGE(0, 0);

  f32x4 acc[4][4] = {};
  int cur = 0;
  for (int t = 0; t < nt; ++t) {
    const int kt = (t + 1 < nt) ? t + 1 : t;          // clamp keeps vmcnt uniform
    STAGE(cur ^ 1, kt);                               // prefetch next tile
    asm volatile("s_waitcnt vmcnt(8)" ::: "memory");  // tile t landed; t+1 in flight
    __builtin_amdgcn_sched_barrier(0);
    __builtin_amdgcn_s_barrier();

    const short* la = lds + cur * BUFS;
    const short* lb = la + ABUF;
    short8 av[2][4], bv[2][4];
    #pragma unroll
    for (int kk = 0; kk < 2; ++kk) {
      #pragma unroll
      for (int mi = 0; mi < 4; ++mi) {
        const int row = wr * 64 + mi * 16 + fr;
        av[kk][mi] = *(const short8*)&la[row * GBK + ((((kk << 2) | g) ^ (fr & 7)) << 3)];
      }
      #pragma unroll
      for (int ni = 0; ni < 4; ++ni) {
        const int row = wc * 64 + ni * 16 + fr;
        bv[kk][ni] = *(const short8*)&lb[row * GBK + ((((kk << 2) | g) ^ (fr & 7)) << 3)];
      }
    }
    __builtin_amdgcn_s_setprio(1);
    #pragma unroll
    for (int kk = 0; kk < 2; ++kk)
      #pragma unroll
      for (int mi = 0; mi < 4; ++mi)
        #pragma unroll
        for (int ni = 0; ni < 4; ++ni) {
          if constexpr (F16)
            acc[mi][ni] = __builtin_amdgcn_mfma_f32_16x16x32_f16(
                __builtin_bit_cast(half8, av[kk][mi]),
                __builtin_bit_cast(half8, bv[kk][ni]), acc[mi][ni], 0, 0, 0);
          else
            acc[mi][ni] = __builtin_amdgcn_mfma_f32_16x16x32_bf16(
                av[kk][mi], bv[kk][ni], acc[mi][ni], 0, 0, 0);
        }
    __builtin_amdgcn_s_setprio(0);
    asm volatile("s_waitcnt lgkmcnt(0)" ::: "memory"); // all reads of cur retired
    __builtin_amdgcn_sched_barrier(0);
    __builtin_amdgcn_s_barrier();                      // safe to restage cur
    cur ^= 1;
  }

  // epilogue: C/D layout col=lane&15, row=(lane>>4)*4+reg  [m89/m91 verified]
  #pragma unroll
  for (int ni = 0; ni < 4; ++ni) {
    const int col = bn + wc * 64 + ni * 16 + fr;
    const float bcol = bias[col];
    #pragma unroll
    for (int mi = 0; mi < 4; ++mi) {
      #pragma unroll
      for (int j = 0; j < 4; ++j) {
        const int rowg = bm + wr * 64 + mi * 16 + (g << 2) + j;
        float v = acc[mi][ni][j] + bcol;
        if (RELU) v = fmaxf(v, 0.f);
        if (OUT_BF16) ((unsigned short*)C)[(size_t)rowg * N + col] = f2bf(v);
        else          ((float*)C)[(size_t)rowg * N + col] = v;
      }
    }
  }
}

// ---- x[M][D] f32 -> A2[M][2D] f16 [hi|lo]  AND  xb[M][D] bf16 --------------
__global__ __launch_bounds__(256) void split_x_f16_kernel(
    const float* __restrict__ x, unsigned short* __restrict__ A2,
    unsigned short* __restrict__ xb) {
  const int i = (blockIdx.x * 256 + threadIdx.x) * 4;
  if (i >= B * L * D) return;
  const int m = i / D, k = i % D;
  const float4 v = *(const float4*)(x + i);
  ushort4 hi, lo, bb;
  hi.x = f2h(v.x); lo.x = f2h(v.x - h2f(hi.x)); bb.x = f2bf(v.x);
  hi.y = f2h(v.y); lo.y = f2h(v.y - h2f(hi.y)); bb.y = f2bf(v.y);
  hi.z = f2h(v.z); lo.z = f2h(v.z - h2f(hi.z)); bb.z = f2bf(v.z);
  hi.w = f2h(v.w); lo.w = f2h(v.w - h2f(hi.w)); bb.w = f2bf(v.w);
  unsigned short* row = A2 + (size_t)m * LDA2;
  *(ushort4*)(row + k)     = hi;
  *(ushort4*)(row + D + k) = lo;
  *(ushort4*)(xb + i) = bb;
}

// ------ W[D][D] f32 -> B2rows[n][3D] f16 bits: [hi(k) | lo(k) | hi(k)] ------
__global__ __launch_bounds__(256) void wsplit_f16_kernel(
    const float* __restrict__ W, unsigned short* __restrict__ B2r) {
  __shared__ float tile[32][33];
  const int bx = blockIdx.x * 32;   // n
  const int by = blockIdx.y * 32;   // k
  const int tx = threadIdx.x & 31, ty = threadIdx.x >> 5;
  #pragma unroll
  for (int i = ty; i < 32; i += 8)
    tile[i][tx] = W[(size_t)(by + i) * D + bx + tx];
  __syncthreads();
  #pragma unroll
  for (int i = ty; i < 32; i += 8) {
    const float v = tile[tx][i];    // W[by+tx][bx+i]
    const unsigned short hi = f2h(v);
    const unsigned short lo = f2h(v - h2f(hi));
    unsigned short* r = B2r + (size_t)(bx + i) * LD3 + (by + tx);
    r[0]     = hi;
    r[D]     = lo;
    r[2 * D] = hi;
  }
}

// ----------- W[K][N] fp32 -> Wt[N][K] bf16 (transpose + convert) ------------
__global__ __launch_bounds__(256) void transpose_bf16_kernel(
    const float* __restrict__ W, unsigned short* __restrict__ Wt, int K, int N) {
  __shared__ float tile[32][33];
  const int bx = blockIdx.x * 32;
  const int by = blockIdx.y * 32;
  const int tx = threadIdx.x & 31, ty = threadIdx.x >> 5;
  #pragma unroll
  for (int i = ty; i < 32; i += 8)
    tile[i][tx] = W[(size_t)(by + i) * N + bx + tx];
  __syncthreads();
  #pragma unroll
  for (int i = ty; i < 32; i += 8)
    Wt[(size_t)(bx + i) * K + by + tx] = f2bf(tile[tx][i]);
}

// ------------------ concat 2 bias vectors of length D -----------------------
__global__ __launch_bounds__(256) void concat2_kernel(
    const float* __restrict__ a, const float* __restrict__ b, float* __restrict__ o) {
  const int i = blockIdx.x * 256 + threadIdx.x;
  if (i < D) o[i] = a[i];
  else if (i < 2 * D) o[i] = b[i - D];
}

// ------------- M[b,h,l] = max_s(Q[l]·K[idx[l,s]]) - sum_s(...)/L ------------
__global__ __launch_bounds__(256) void prob_m_kernel(
    const float* __restrict__ QK, const int* __restrict__ idx,
    float* __restrict__ M_) {
  const int bl = blockIdx.x;
  const int b = bl / L, l = bl % L;
  const int tid = threadIdx.x;
  __shared__ float dots[H][S];
  __shared__ int sidx[S];
  if (tid < S) sidx[tid] = idx[l * S + tid];
  __syncthreads();
  const int h = tid >> 4;
  const int dsub = (tid & 15) * 4;
  float4 q = *(const float4*)(QK + (size_t)bl * LD2 + h * DH + dsub);
  for (int s = 0; s < S; ++s) {
    const float4 kv = *(const float4*)(QK + ((size_t)b * L + sidx[s]) * LD2 + D + h * DH + dsub);
    float p = q.x*kv.x + q.y*kv.y + q.z*kv.z + q.w*kv.w;
    p += __shfl_xor(p, 1);
    p += __shfl_xor(p, 2);
    p += __shfl_xor(p, 4);
    p += __shfl_xor(p, 8);
    if ((tid & 15) == 0) dots[h][s] = p;
  }
  __syncthreads();
  if (tid < H) {
    float mx = -INFINITY, sm = 0.f;
    for (int s = 0; s < S; ++s) { float v = dots[tid][s]; mx = fmaxf(mx, v); sm += v; }
    M_[((size_t)b * H + tid) * L + l] = mx - sm / (float)L;
  }
}

// ---- exact top-k (k=40, n=2048): single wave, register-resident, no LDS ----
__global__ __launch_bounds__(64) void topk_kernel(
    const float* __restrict__ M_, int* __restrict__ Mtop) {
  const int bh = blockIdx.x;
  const float* row = M_ + (size_t)bh * L;
  const int lane = threadIdx.x;   // 0..63
  float v[32];
  #pragma unroll
  for (int k = 0; k < 32; ++k) v[k] = row[k * 64 + lane];
  for (int u = 0; u < U; ++u) {
    float best = v[0]; int bk = 0;
    #pragma unroll
    for (int k = 1; k < 32; ++k)
      if (v[k] > best) { best = v[k]; bk = k; }        // strict >: lower k wins
    int bidx = bk * 64 + lane;
    #pragma unroll
    for (int off = 1; off < 64; off <<= 1) {
      const float ov = __shfl_xor(best, off);
      const int   oi = __shfl_xor(bidx, off);
      if (ov > best || (ov == best && oi < bidx)) { best = ov; bidx = oi; }
    }
    if (lane == 0) Mtop[bh * U + u] = bidx;            // all lanes agree
    if ((bidx & 63) == lane) {                          // kill winner (static idx)
      const int kk = bidx >> 6;
      #pragma unroll
      for (int k = 0; k < 32; ++k) if (k == kk) v[k] = -INFINITY;
    }
  }
}

// ------- attn phase 1: per (b,h,jc) partial softmax + PV over 128 keys ------
__global__ __launch_bounds__(320) void attn_p1_kernel(
    const float* __restrict__ QK, const float* __restrict__ V,
    const int* __restrict__ Mtop,
    float* __restrict__ pmax, float* __restrict__ psum, float* __restrict__ pv) {
  const int jc = blockIdx.x, h = blockIdx.y, b = blockIdx.z;
  const int bh = b * H + h;
  const int tid = threadIdx.x;
  const int j0 = jc * JT;
  __shared__ float Qs[U][68];
  __shared__ float KVs[JT][68];
  __shared__ unsigned short ws[U][JT];

  for (int i = tid; i < U * 16; i += 320) {
    const int u = i >> 4, dq = (i & 15) << 2;
    const int row = Mtop[bh * U + u];
    *(float4*)&Qs[u][dq] =
        *(const float4*)(QK + ((size_t)b * L + row) * LD2 + h * DH + dq);
  }
  for (int i = tid; i < JT * 16; i += 320) {
    const int j = i >> 4, dq = (i & 15) << 2;
    *(float4*)&KVs[j][dq] =
        *(const float4*)(QK + ((size_t)b * L + j0 + j) * LD2 + D + h * DH + dq);
  }
  __syncthreads();

  const int u = tid >> 3, jg = tid & 7;
  const int mt = Mtop[bh * U + u];
  float sc[16];
  #pragma unroll
  for (int jt = 0; jt < 16; ++jt) sc[jt] = 0.f;
  for (int dq = 0; dq < 64; dq += 4) {
    const float4 q = *(const float4*)&Qs[u][dq];
    #pragma unroll
    for (int jt = 0; jt < 16; ++jt) {
      const float4 k = *(const float4*)&KVs[jt * 8 + jg][dq];
      sc[jt] += q.x*k.x + q.y*k.y + q.z*k.z + q.w*k.w;
    }
  }
  float m = -INFINITY;
  #pragma unroll
  for (int jt = 0; jt < 16; ++jt) {
    const int j = j0 + jt * 8 + jg;
    sc[jt] = (j <= mt) ? sc[jt] * 0.125f : -INFINITY;
    m = fmaxf(m, sc[jt]);
  }
  m = fmaxf(m, __shfl_xor(m, 1));
  m = fmaxf(m, __shfl_xor(m, 2));
  m = fmaxf(m, __shfl_xor(m, 4));
  float sum = 0.f;
  #pragma unroll
  for (int jt = 0; jt < 16; ++jt) {
    const float e = (sc[jt] == -INFINITY) ? 0.f : expf(sc[jt] - m);
    sum += e;
    ws[u][jt * 8 + jg] = f2bf(e);
  }
  sum += __shfl_xor(sum, 1);
  sum += __shfl_xor(sum, 2);
  sum += __shfl_xor(sum, 4);
  if (jg == 0) {
    pmax[(size_t)(bh * NJC + jc) * U + u] = m;
    psum[(size_t)(bh * NJC + jc) * U + u] = sum;
  }
  __syncthreads();
  // reload LDS with V chunk
  for (int i = tid; i < JT * 16; i += 320) {
    const int j = i >> 4, dq = (i & 15) << 2;
    *(float4*)&KVs[j][dq] =
        *(const float4*)(V + ((size_t)b * L + j0 + j) * D + h * DH + dq);
  }
  __syncthreads();
  const int d = tid & 63, ug = tid >> 6;
  float acc[8] = {};
  for (int j = 0; j < JT; j += 2) {
    const float v0 = KVs[j][d], v1 = KVs[j + 1][d];
    #pragma unroll
    for (int k = 0; k < 8; ++k) {
      const int uu = ug + k * 5;
      const unsigned int wp = *(const unsigned int*)&ws[uu][j];
      acc[k] = fmaf(bf2f((unsigned short)(wp & 0xffff)), v0, acc[k]);
      acc[k] = fmaf(bf2f((unsigned short)(wp >> 16)), v1, acc[k]);
    }
  }
  #pragma unroll
  for (int k = 0; k < 8; ++k) {
    const int uu = ug + k * 5;
    pv[((size_t)(bh * NJC + jc) * U + uu) * DH + d] = acc[k];
  }
}

// -- attn phase 2: combine 16 chunks per (b,h,u), scatter into ctx16 (bf16) --
__global__ __launch_bounds__(64) void attn_p2_kernel(
    const float* __restrict__ pmax, const float* __restrict__ psum,
    const float* __restrict__ pv, const int* __restrict__ Mtop,
    unsigned short* __restrict__ ctx16) {
  const int bid = blockIdx.x;          // bh*U + u
  const int u = bid % U, bh = bid / U;
  const int d = threadIdx.x;
  float gmax = -INFINITY;
  for (int c = 0; c < NJC; ++c)
    gmax = fmaxf(gmax, pmax[(size_t)(bh * NJC + c) * U + u]);
  float den = 0.f, num = 0.f;
  for (int c = 0; c < NJC; ++c) {
    const float m = pmax[(size_t)(bh * NJC + c) * U + u];
    if (m == -INFINITY) continue;
    const float s = expf(m - gmax);
    den += psum[(size_t)(bh * NJC + c) * U + u] * s;
    num += pv[((size_t)(bh * NJC + c) * U + u) * DH + d] * s;
  }
  const int h = bh % H, b = bh / H;
  const int l = Mtop[bh * U + u];
  ctx16[((size_t)b * L + l) * D + h * DH + d] = f2bf(num / den);
}

// ------------------------ cumsum(V) over l, two-pass ------------------------
__global__ __launch_bounds__(256) void cumsum_pass1(
    const float* __restrict__ V, float* __restrict__ ctx, float* __restrict__ csums) {
  const int c = blockIdx.x * 256 + threadIdx.x;
  const int ch = blockIdx.y, b = blockIdx.z;
  size_t base = ((size_t)b * L + (size_t)ch * CHLEN) * D + c;
  float acc = 0.f;
  for (int i = 0; i < CHLEN; ++i) {
    const size_t o = base + (size_t)i * D;
    acc += V[o];
    ctx[o] = acc;
  }
  csums[((size_t)b * NCHUNK + ch) * D + c] = acc;
}

// pass2 covers ALL chunks (ch=0 zero offset) and emits bf16 ctx directly.
__global__ __launch_bounds__(256) void cumsum_pass2(
    const float* __restrict__ ctx, const float* __restrict__ csums,
    unsigned short* __restrict__ ctx16) {
  const int c = blockIdx.x * 256 + threadIdx.x;
  const int ch = blockIdx.y, b = blockIdx.z;
  float off = 0.f;
  for (int j = 0; j < ch; ++j) off += csums[((size_t)b * NCHUNK + j) * D + c];
  size_t base = ((size_t)b * L + (size_t)ch * CHLEN) * D + c;
  for (int i = 0; i < CHLEN; ++i) {
    const size_t o = base + (size_t)i * D;
    ctx16[o] = f2bf(ctx[o] + off);
  }
}

// ------- out = LayerNorm(a + r) * g + be  (+ optional bf16 copy) ------------
__global__ __launch_bounds__(256) void add_ln_kernel(
    const float* __restrict__ a, const float* __restrict__ r,
    const float* __restrict__ g, const float* __restrict__ be,
    float* __restrict__ out, unsigned short* __restrict__ out16) {
  const int row = blockIdx.x;
  const int tid = threadIdx.x;
  __shared__ float buf[D];
  __shared__ float red[256];
  const float* pa = a + (size_t)row * D;
  const float* pr = r + (size_t)row * D;
  float s = 0.f;
  for (int i = tid; i < D; i += 256) { float v = pa[i] + pr[i]; buf[i] = v; s += v; }
  red[tid] = s; __syncthreads();
  for (int off = 128; off > 0; off >>= 1) {
    if (tid < off) red[tid] += red[tid+off];
    __syncthreads();
  }
  const float mu = red[0] / (float)D;
  __syncthreads();
  float s2 = 0.f;
  for (int i = tid; i < D; i += 256) { float dv = buf[i] - mu; s2 += dv * dv; }
  red[tid] = s2; __syncthreads();
  for (int off = 128; off > 0; off >>= 1) {
    if (tid < off) red[tid] += red[tid+off];
    __syncthreads();
  }
  const float rstd = rsqrtf(red[0] / (float)D + EPS);
  __syncthreads();
  float* po = out + (size_t)row * D;
  for (int i = tid; i < D; i += 256) {
    float v = (buf[i] - mu) * rstd * g[i] + be[i];
    po[i] = v;
    if (out16) out16[(size_t)row * D + i] = f2bf(v);
  }
}

// ----------------------------------------------------------------------------
extern "C" void kernel_launch(void* const* d_in, const int* in_sizes, int n_in,
                              void* d_out, int out_size, void* d_ws, size_t ws_size,
                              hipStream_t stream) {
  const float* x   = (const float*)d_in[0];
  const float* Wq  = (const float*)d_in[1];
  const float* bq  = (const float*)d_in[2];
  const float* Wk  = (const float*)d_in[3];
  const float* bk  = (const float*)d_in[4];
  const float* Wv  = (const float*)d_in[5];
  const float* bv  = (const float*)d_in[6];
  const float* Wo  = (const float*)d_in[7];
  const float* bo  = (const float*)d_in[8];
  const float* g1  = (const float*)d_in[9];
  const float* be1 = (const float*)d_in[10];
  const float* W1  = (const float*)d_in[11];
  const float* b1  = (const float*)d_in[12];
  const float* W2  = (const float*)d_in[13];
  const float* b2  = (const float*)d_in[14];
  const float* g2  = (const float*)d_in[15];
  const float* be2 = (const float*)d_in[16];
  const int*   idx = (const int*)d_in[17];
  float* out = (float*)d_out;

  char* p = (char*)d_ws;
  // ---- workspace (stream-ordered lifetimes) ----
  // R1 [0,16M): A2 (1-3) -> ctxb (9a-9b) -> AO (11-12) -> ff2 (14-15)
  unsigned short* A2   = (unsigned short*)p;
  float*          ctxb = (float*)p;
  float*          AO   = (float*)p;
  float*          ff2  = (float*)p;
  // R2 [16M,24M): xb (1-5) -> ctx16 (9b-11)
  unsigned short* xb    = (unsigned short*)(p + 16777216);
  unsigned short* ctx16 = (unsigned short*)(p + 16777216);
  // R3 [24M,36M): B2 (2-3, 12.58MB) -> scratch (6-10; first write at step 6)
  unsigned short* B2 = (unsigned short*)(p + 25165824);
  char* scr = p + 25165824;
  float* Mbuf   = (float*)(scr);             // 262,144
  float* csum   = (float*)(scr + 262144);    // 262,144
  int*   Mtop   = (int*)  (scr + 524288);    // 5,120 (pad 8192)
  float* pmax   = (float*)(scr + 532480);    // 81,920
  float* psum   = (float*)(scr + 614400);    // 81,920
  float* pv     = (float*)(scr + 696320);    // 5,242,880 -> ends 5,939,200
  // R4 [36M,68M): QKb (3-8) -> x1 [36M,52M) (12-15) + x1b [52M,60M) (12-13)
  float*          QKb = (float*)(p + 37748736);
  float*          x1  = (float*)(p + 37748736);
  unsigned short* x1b = (unsigned short*)(p + 54525952);
  // [60M,92M): ff1b (13-14); overlaps QKb tail (dead after 8) only
  unsigned short* ff1b = (unsigned short*)(p + 62914560);
  // [92M,108M): Vb (5-9)
  float* Vb = (float*)(p + 96468992);
  // [108M,128M): bf16 weights (4-14)
  unsigned short* Wvt = (unsigned short*)(p + 113246208);
  unsigned short* Wot = (unsigned short*)(p + 115343360);
  unsigned short* W1t = (unsigned short*)(p + 117440512);
  unsigned short* W2t = (unsigned short*)(p + 125829120);
  // [128M, 128M+8K): qkbias — MUST NOT overlap B2 (round-7 bug: it was inside
  // B2's Wk half and concat2 corrupted K columns 0..1 -> top-k flips)
  float* qkbias = (float*)(p + 134217728);

  dim3 blk(256);
  const int M = B * L;   // 4096
  const int SZ = B * L * D;

  // 1) inputs prep: A2 [hi|lo] + bf16 copy
  split_x_f16_kernel<<<(SZ/4 + 255)/256, blk, 0, stream>>>(x, A2, xb);
  // 2) QK weight split + bias concat
  wsplit_f16_kernel<<<dim3(D/32, D/32), blk, 0, stream>>>(Wq, B2);
  wsplit_f16_kernel<<<dim3(D/32, D/32), blk, 0, stream>>>(Wk, B2 + (size_t)D * LD3);
  concat2_kernel<<<8, blk, 0, stream>>>(bq, bk, qkbias);
  // 3) QK via f16 hi/lo 3-term split (fp32-accurate), A-dedup layout
  gemm128_kernel<false,false,true,true><<<dim3(LD2/128, M/128), blk, 0, stream>>>(
      A2, B2, qkbias, QKb, M, LD2, LD3, LDA2);
  // 4) bf16 weight transposes
  transpose_bf16_kernel<<<dim3(D/32,  D/32),   blk, 0, stream>>>(Wv, Wvt, D, D);
  transpose_bf16_kernel<<<dim3(D/32,  D/32),   blk, 0, stream>>>(Wo, Wot, D, D);
  transpose_bf16_kernel<<<dim3(FFD/32, D/32),  blk, 0, stream>>>(W1, W1t, D, FFD);
  transpose_bf16_kernel<<<dim3(D/32,  FFD/32), blk, 0, stream>>>(W2, W2t, FFD, D);
  // 5) V projection (bf16: LN renorm makes cumsum error relative — safe)
  gemm128_kernel<false,false,false,false><<<dim3(D/128, M/128), blk, 0, stream>>>(
      xb, Wvt, bv, Vb, M, D, D, D);
  // 6-8) ProbSparse attention scoring
  prob_m_kernel<<<B*L, blk, 0, stream>>>(QKb, idx, Mbuf);
  topk_kernel<<<B*H, dim3(64), 0, stream>>>(Mbuf, Mtop);
  attn_p1_kernel<<<dim3(NJC, H, B), dim3(320), 0, stream>>>(QKb, Vb, Mtop, pmax, psum, pv);
  // 9) context = cumsum(V), emitted directly as bf16
  cumsum_pass1<<<dim3(D/256, NCHUNK, B), blk, 0, stream>>>(Vb, ctxb, csum);
  cumsum_pass2<<<dim3(D/256, NCHUNK, B), blk, 0, stream>>>(ctxb, csum, ctx16);
  // 10) attn combine + scatter into ctx16
  attn_p2_kernel<<<B*H*U, dim3(64), 0, stream>>>(pmax, psum, pv, Mtop, ctx16);
  // 11) output projection (bias fused)
  gemm128_kernel<false,false,false,false><<<dim3(D/128, M/128), blk, 0, stream>>>(
      ctx16, Wot, bo, AO, M, D, D, D);
  // 12) LN1
  add_ln_kernel<<<B*L, blk, 0, stream>>>(x, AO, g1, be1, x1, x1b);
  // 13) FF1 (bias+relu fused, bf16 out)
  gemm128_kernel<true,true,false,false><<<dim3(FFD/128, M/128), blk, 0, stream>>>(
      x1b, W1t, b1, ff1b, M, FFD, D, D);
  // 14) FF2 (bias fused)
  gemm128_kernel<false,false,false,false><<<dim3(D/128, M/128), blk, 0, stream>>>(
      ff1b, W2t, b2, ff2, M, D, FFD, FFD);
  // 15) LN2
  add_ln_kernel<<<B*L, blk, 0, stream>>>(x1, ff2, g2, be2, out,
                                         (unsigned short*)nullptr);
}

// Round 9
// 384.677 us; speedup vs baseline: 5.5658x; 1.0332x over previous
//
#include <hip/hip_runtime.h>
#include <hip/hip_bf16.h>
#include <hip/hip_fp16.h>
#include <math.h>

constexpr int B = 2, L = 2048, D = 1024, H = 16, DH = 64, FFD = 4096;
constexpr int S = 40;   // sample_k
constexpr int U = 40;   // n_top
constexpr float EPS = 1e-5f;
constexpr int NCHUNK = 32;
constexpr int CHLEN = L / NCHUNK;   // 64
constexpr int LD3 = 3 * D;          // QK split GEMM K' (3072)
constexpr int LD2 = 2 * D;          // QK output row stride
constexpr int LDA2 = 2 * D;         // A2 row stride [hi|lo]
constexpr int JT = 128;             // attn j-chunk
constexpr int NJC = L / JT;         // 16

typedef __attribute__((ext_vector_type(8))) short short8;      // 8 bf16/f16 bits
typedef __attribute__((ext_vector_type(8))) _Float16 half8;
typedef __attribute__((ext_vector_type(4))) float f32x4;

__device__ __forceinline__ unsigned short f2bf(float v) {
  __hip_bfloat16 h = __float2bfloat16(v);
  return __builtin_bit_cast(unsigned short, h);
}
__device__ __forceinline__ float bf2f(unsigned short u) {
  unsigned int x = ((unsigned int)u) << 16;
  return __builtin_bit_cast(float, x);
}
__device__ __forceinline__ unsigned short f2h(float v) {
  __half h = __float2half(v);
  return __builtin_bit_cast(unsigned short, h);
}
__device__ __forceinline__ float h2f(unsigned short u) {
  return __half2float(__builtin_bit_cast(__half, u));
}

__device__ __forceinline__ void gload16(const void* g, void* l) {
  __builtin_amdgcn_global_load_lds(
      (const __attribute__((address_space(1))) void*)g,
      (__attribute__((address_space(3))) void*)l, 16, 0, 0);
}

// ======== pipelined MFMA GEMM: 128x128 tile, BK=64, DOUBLE-buffered LDS =====
// (64 KB -> 2 blocks/CU; cross-block overlap hides LDS-read vs MFMA), counted
// vmcnt(8), raw s_barrier, T2 source-side XOR swizzle, T5 setprio, XCD swizzle.
// DUPA: A has K/3 duplicated layout [hi|lo] (KA=2K/3); K-tiles [16,32) re-read
// the hi columns (QK 3-term f16 split: hi*Whi + hi*Wlo + lo*Whi).
template<bool RELU, bool OUT_BF16, bool F16, bool DUPA>
__global__ __launch_bounds__(256, 2) void gemm128_kernel(
    const unsigned short* __restrict__ A,    // [M][KA] bits
    const unsigned short* __restrict__ Bt,   // [N][K] bits
    const float* __restrict__ bias,          // [N]
    void* __restrict__ C, int M, int N, int K, int KA) {
  constexpr int GBM = 128, GBN = 128, GBK = 64;
  constexpr int ABUF = GBM * GBK;    // 8192 shorts
  constexpr int BUFS = 2 * ABUF;     // A+B = 16384 shorts (32 KB)
  __shared__ short lds[2 * BUFS];    // 64 KB -> 2 blocks/CU

  const int tid  = threadIdx.x;
  const int lane = tid & 63;
  const int wid  = tid >> 6;          // 0..3
  const int wr = wid >> 1;            // 0..1 (64-row band)
  const int wc = wid & 1;             // 0..1 (64-col band)

  // XCD-aware bijective block swizzle (nwg % 8 == 0 for all our shapes)
  const int nwg  = gridDim.x * gridDim.y;
  const int orig = blockIdx.y * gridDim.x + blockIdx.x;
  const int wg   = (orig & 7) * (nwg >> 3) + (orig >> 3);
  const int bm = (wg / gridDim.x) * GBM;
  const int bn = (wg % gridDim.x) * GBN;

  // staging: wave w covers rows w*8 + (lane>>3) (+32 per issue),
  // physical 16B slot (lane&7) holds logical slot (lane&7)^(row&7)  [T2/G21]
  const int srow  = lane >> 3;                 // 0..7 == row&7
  const int sslot = (lane & 7) ^ srow;         // pre-swizzled source slot
  const unsigned short* aS = A  + (size_t)(bm + wid * 8 + srow) * KA + sslot * 8;
  const unsigned short* bS = Bt + (size_t)(bn + wid * 8 + srow) * K  + sslot * 8;
  short* la0 = lds + wid * 8 * GBK;
  short* lb0 = lds + ABUF + wid * 8 * GBK;

  auto STAGE = [&](int buf, int kt) {          // 8 vmem ops / thread / tile
    const int akt = (DUPA && kt >= 16) ? kt - 16 : kt;
    const unsigned short* ap = aS + (size_t)akt * GBK;
    const unsigned short* bp = bS + (size_t)kt  * GBK;
    short* la = la0 + buf * BUFS;
    short* lb = lb0 + buf * BUFS;
    gload16(ap,                   la);
    gload16(ap + (size_t)32 * KA, la + 32 * GBK);
    gload16(ap + (size_t)64 * KA, la + 64 * GBK);
    gload16(ap + (size_t)96 * KA, la + 96 * GBK);
    gload16(bp,                   lb);
    gload16(bp + (size_t)32 * K,  lb + 32 * GBK);
    gload16(bp + (size_t)64 * K,  lb + 64 * GBK);
    gload16(bp + (size_t)96 * K,  lb + 96 * GBK);
  };

  const int fr = lane & 15, g = lane >> 4;
  const int nt = K / GBK;

  STAGE(0, 0);

  f32x4 acc[4][4] = {};
  int cur = 0;
  for (int t = 0; t < nt; ++t) {
    const int kt = (t + 1 < nt) ? t + 1 : t;          // clamp keeps vmcnt uniform
    STAGE(cur ^ 1, kt);                               // prefetch next tile
    asm volatile("s_waitcnt vmcnt(8)" ::: "memory");  // tile t landed; t+1 in flight
    __builtin_amdgcn_sched_barrier(0);
    __builtin_amdgcn_s_barrier();

    const short* la = lds + cur * BUFS;
    const short* lb = la + ABUF;
    short8 av[2][4], bv[2][4];
    #pragma unroll
    for (int kk = 0; kk < 2; ++kk) {
      #pragma unroll
      for (int mi = 0; mi < 4; ++mi) {
        const int row = wr * 64 + mi * 16 + fr;
        av[kk][mi] = *(const short8*)&la[row * GBK + ((((kk << 2) | g) ^ (fr & 7)) << 3)];
      }
      #pragma unroll
      for (int ni = 0; ni < 4; ++ni) {
        const int row = wc * 64 + ni * 16 + fr;
        bv[kk][ni] = *(const short8*)&lb[row * GBK + ((((kk << 2) | g) ^ (fr & 7)) << 3)];
      }
    }
    __builtin_amdgcn_s_setprio(1);
    #pragma unroll
    for (int kk = 0; kk < 2; ++kk)
      #pragma unroll
      for (int mi = 0; mi < 4; ++mi)
        #pragma unroll
        for (int ni = 0; ni < 4; ++ni) {
          if constexpr (F16)
            acc[mi][ni] = __builtin_amdgcn_mfma_f32_16x16x32_f16(
                __builtin_bit_cast(half8, av[kk][mi]),
                __builtin_bit_cast(half8, bv[kk][ni]), acc[mi][ni], 0, 0, 0);
          else
            acc[mi][ni] = __builtin_amdgcn_mfma_f32_16x16x32_bf16(
                av[kk][mi], bv[kk][ni], acc[mi][ni], 0, 0, 0);
        }
    __builtin_amdgcn_s_setprio(0);
    asm volatile("s_waitcnt lgkmcnt(0)" ::: "memory"); // all reads of cur retired
    __builtin_amdgcn_sched_barrier(0);
    __builtin_amdgcn_s_barrier();                      // safe to restage cur
    cur ^= 1;
  }

  // epilogue: C/D layout col=lane&15, row=(lane>>4)*4+reg  [m89/m91 verified]
  #pragma unroll
  for (int ni = 0; ni < 4; ++ni) {
    const int col = bn + wc * 64 + ni * 16 + fr;
    const float bcol = bias[col];
    #pragma unroll
    for (int mi = 0; mi < 4; ++mi) {
      #pragma unroll
      for (int j = 0; j < 4; ++j) {
        const int rowg = bm + wr * 64 + mi * 16 + (g << 2) + j;
        float v = acc[mi][ni][j] + bcol;
        if (RELU) v = fmaxf(v, 0.f);
        if (OUT_BF16) ((unsigned short*)C)[(size_t)rowg * N + col] = f2bf(v);
        else          ((float*)C)[(size_t)rowg * N + col] = v;
      }
    }
  }
}

// ---- x[M][D] f32 -> A2[M][2D] f16 [hi|lo]  AND  xb[M][D] bf16 --------------
__global__ __launch_bounds__(256) void split_x_f16_kernel(
    const float* __restrict__ x, unsigned short* __restrict__ A2,
    unsigned short* __restrict__ xb) {
  const int i = (blockIdx.x * 256 + threadIdx.x) * 4;
  if (i >= B * L * D) return;
  const int m = i / D, k = i % D;
  const float4 v = *(const float4*)(x + i);
  ushort4 hi, lo, bb;
  hi.x = f2h(v.x); lo.x = f2h(v.x - h2f(hi.x)); bb.x = f2bf(v.x);
  hi.y = f2h(v.y); lo.y = f2h(v.y - h2f(hi.y)); bb.y = f2bf(v.y);
  hi.z = f2h(v.z); lo.z = f2h(v.z - h2f(hi.z)); bb.z = f2bf(v.z);
  hi.w = f2h(v.w); lo.w = f2h(v.w - h2f(hi.w)); bb.w = f2bf(v.w);
  unsigned short* row = A2 + (size_t)m * LDA2;
  *(ushort4*)(row + k)     = hi;
  *(ushort4*)(row + D + k) = lo;
  *(ushort4*)(xb + i) = bb;
}

// ------ W[D][D] f32 -> B2rows[n][3D] f16 bits: [hi(k) | lo(k) | hi(k)] ------
__global__ __launch_bounds__(256) void wsplit_f16_kernel(
    const float* __restrict__ W, unsigned short* __restrict__ B2r) {
  __shared__ float tile[32][33];
  const int bx = blockIdx.x * 32;   // n
  const int by = blockIdx.y * 32;   // k
  const int tx = threadIdx.x & 31, ty = threadIdx.x >> 5;
  #pragma unroll
  for (int i = ty; i < 32; i += 8)
    tile[i][tx] = W[(size_t)(by + i) * D + bx + tx];
  __syncthreads();
  #pragma unroll
  for (int i = ty; i < 32; i += 8) {
    const float v = tile[tx][i];    // W[by+tx][bx+i]
    const unsigned short hi = f2h(v);
    const unsigned short lo = f2h(v - h2f(hi));
    unsigned short* r = B2r + (size_t)(bx + i) * LD3 + (by + tx);
    r[0]     = hi;
    r[D]     = lo;
    r[2 * D] = hi;
  }
}

// ----------- W[K][N] fp32 -> Wt[N][K] bf16 (transpose + convert) ------------
__global__ __launch_bounds__(256) void transpose_bf16_kernel(
    const float* __restrict__ W, unsigned short* __restrict__ Wt, int K, int N) {
  __shared__ float tile[32][33];
  const int bx = blockIdx.x * 32;
  const int by = blockIdx.y * 32;
  const int tx = threadIdx.x & 31, ty = threadIdx.x >> 5;
  #pragma unroll
  for (int i = ty; i < 32; i += 8)
    tile[i][tx] = W[(size_t)(by + i) * N + bx + tx];
  __syncthreads();
  #pragma unroll
  for (int i = ty; i < 32; i += 8)
    Wt[(size_t)(bx + i) * K + by + tx] = f2bf(tile[tx][i]);
}

// ------------------ concat 2 bias vectors of length D -----------------------
__global__ __launch_bounds__(256) void concat2_kernel(
    const float* __restrict__ a, const float* __restrict__ b, float* __restrict__ o) {
  const int i = blockIdx.x * 256 + threadIdx.x;
  if (i < D) o[i] = a[i];
  else if (i < 2 * D) o[i] = b[i - D];
}

// ------------- M[b,h,l] = max_s(Q[l]·K[idx[l,s]]) - sum_s(...)/L ------------
// Head-sliced + XCD-pinned: grid (8, L); x = combo (b*4 + head-group-of-4) is
// the fastest-varying block index so round-robin dispatch pins each combo to
// one XCD. Per-combo K gather working set = 2048 rows x 4 heads x 256 B = 2 MB
// -> L2-resident on that XCD (4 MB). One wave per head, no LDS dots.
__global__ __launch_bounds__(256) void prob_m_kernel(
    const float* __restrict__ QK, const int* __restrict__ idx,
    float* __restrict__ M_) {
  const int combo = blockIdx.x;        // 0..7
  const int b = combo >> 2, hg = combo & 3;
  const int l = blockIdx.y;
  const int tid = threadIdx.x;
  const int wave = tid >> 6;           // 0..3
  const int lane = tid & 63;
  const int h = hg * 4 + wave;
  __shared__ int sidx[S];
  if (tid < S) sidx[tid] = idx[l * S + tid];
  __syncthreads();
  const int dsub = (lane & 15) * 4;
  const int sgrp = lane >> 4;          // 0..3
  const float4 q = *(const float4*)(QK + ((size_t)b * L + l) * LD2 + h * DH + dsub);
  float mx = -INFINITY, sm = 0.f;
  for (int s = sgrp; s < S; s += 4) {
    const float4 kv = *(const float4*)(QK + ((size_t)b * L + sidx[s]) * LD2 + D + h * DH + dsub);
    float p = q.x*kv.x + q.y*kv.y + q.z*kv.z + q.w*kv.w;
    p += __shfl_xor(p, 1);
    p += __shfl_xor(p, 2);
    p += __shfl_xor(p, 4);
    p += __shfl_xor(p, 8);             // all 16 lanes of the group hold the dot
    mx = fmaxf(mx, p);
    sm += p;
  }
  // reduce across the 4 s-groups (lane bits 4,5)
  mx = fmaxf(mx, __shfl_xor(mx, 16));
  mx = fmaxf(mx, __shfl_xor(mx, 32));
  sm += __shfl_xor(sm, 16);
  sm += __shfl_xor(sm, 32);
  if (lane == 0)
    M_[((size_t)b * H + h) * L + l] = mx - sm / (float)L;
}

// ---- exact top-k (k=40, n=2048): single wave, register-resident, no LDS ----
__global__ __launch_bounds__(64) void topk_kernel(
    const float* __restrict__ M_, int* __restrict__ Mtop) {
  const int bh = blockIdx.x;
  const float* row = M_ + (size_t)bh * L;
  const int lane = threadIdx.x;   // 0..63
  float v[32];
  #pragma unroll
  for (int k = 0; k < 32; ++k) v[k] = row[k * 64 + lane];
  for (int u = 0; u < U; ++u) {
    float best = v[0]; int bk = 0;
    #pragma unroll
    for (int k = 1; k < 32; ++k)
      if (v[k] > best) { best = v[k]; bk = k; }        // strict >: lower k wins
    int bidx = bk * 64 + lane;
    #pragma unroll
    for (int off = 1; off < 64; off <<= 1) {
      const float ov = __shfl_xor(best, off);
      const int   oi = __shfl_xor(bidx, off);
      if (ov > best || (ov == best && oi < bidx)) { best = ov; bidx = oi; }
    }
    if (lane == 0) Mtop[bh * U + u] = bidx;            // all lanes agree
    if ((bidx & 63) == lane) {                          // kill winner (static idx)
      const int kk = bidx >> 6;
      #pragma unroll
      for (int k = 0; k < 32; ++k) if (k == kk) v[k] = -INFINITY;
    }
  }
}

// ------- attn phase 1: per (b,h,jc) partial softmax + PV over 128 keys ------
__global__ __launch_bounds__(320) void attn_p1_kernel(
    const float* __restrict__ QK, const float* __restrict__ V,
    const int* __restrict__ Mtop,
    float* __restrict__ pmax, float* __restrict__ psum, float* __restrict__ pv) {
  const int jc = blockIdx.x, h = blockIdx.y, b = blockIdx.z;
  const int bh = b * H + h;
  const int tid = threadIdx.x;
  const int j0 = jc * JT;
  __shared__ float Qs[U][68];
  __shared__ float KVs[JT][68];
  __shared__ unsigned short ws[U][JT];

  for (int i = tid; i < U * 16; i += 320) {
    const int u = i >> 4, dq = (i & 15) << 2;
    const int row = Mtop[bh * U + u];
    *(float4*)&Qs[u][dq] =
        *(const float4*)(QK + ((size_t)b * L + row) * LD2 + h * DH + dq);
  }
  for (int i = tid; i < JT * 16; i += 320) {
    const int j = i >> 4, dq = (i & 15) << 2;
    *(float4*)&KVs[j][dq] =
        *(const float4*)(QK + ((size_t)b * L + j0 + j) * LD2 + D + h * DH + dq);
  }
  __syncthreads();

  const int u = tid >> 3, jg = tid & 7;
  const int mt = Mtop[bh * U + u];
  float sc[16];
  #pragma unroll
  for (int jt = 0; jt < 16; ++jt) sc[jt] = 0.f;
  for (int dq = 0; dq < 64; dq += 4) {
    const float4 q = *(const float4*)&Qs[u][dq];
    #pragma unroll
    for (int jt = 0; jt < 16; ++jt) {
      const float4 k = *(const float4*)&KVs[jt * 8 + jg][dq];
      sc[jt] += q.x*k.x + q.y*k.y + q.z*k.z + q.w*k.w;
    }
  }
  float m = -INFINITY;
  #pragma unroll
  for (int jt = 0; jt < 16; ++jt) {
    const int j = j0 + jt * 8 + jg;
    sc[jt] = (j <= mt) ? sc[jt] * 0.125f : -INFINITY;
    m = fmaxf(m, sc[jt]);
  }
  m = fmaxf(m, __shfl_xor(m, 1));
  m = fmaxf(m, __shfl_xor(m, 2));
  m = fmaxf(m, __shfl_xor(m, 4));
  float sum = 0.f;
  #pragma unroll
  for (int jt = 0; jt < 16; ++jt) {
    const float e = (sc[jt] == -INFINITY) ? 0.f : expf(sc[jt] - m);
    sum += e;
    ws[u][jt * 8 + jg] = f2bf(e);
  }
  sum += __shfl_xor(sum, 1);
  sum += __shfl_xor(sum, 2);
  sum += __shfl_xor(sum, 4);
  if (jg == 0) {
    pmax[(size_t)(bh * NJC + jc) * U + u] = m;
    psum[(size_t)(bh * NJC + jc) * U + u] = sum;
  }
  __syncthreads();
  // reload LDS with V chunk
  for (int i = tid; i < JT * 16; i += 320) {
    const int j = i >> 4, dq = (i & 15) << 2;
    *(float4*)&KVs[j][dq] =
        *(const float4*)(V + ((size_t)b * L + j0 + j) * D + h * DH + dq);
  }
  __syncthreads();
  const int d = tid & 63, ug = tid >> 6;
  float acc[8] = {};
  for (int j = 0; j < JT; j += 2) {
    const float v0 = KVs[j][d], v1 = KVs[j + 1][d];
    #pragma unroll
    for (int k = 0; k < 8; ++k) {
      const int uu = ug + k * 5;
      const unsigned int wp = *(const unsigned int*)&ws[uu][j];
      acc[k] = fmaf(bf2f((unsigned short)(wp & 0xffff)), v0, acc[k]);
      acc[k] = fmaf(bf2f((unsigned short)(wp >> 16)), v1, acc[k]);
    }
  }
  #pragma unroll
  for (int k = 0; k < 8; ++k) {
    const int uu = ug + k * 5;
    pv[((size_t)(bh * NJC + jc) * U + uu) * DH + d] = acc[k];
  }
}

// -- attn phase 2: combine 16 chunks per (b,h,u), scatter into ctx16 (bf16) --
__global__ __launch_bounds__(64) void attn_p2_kernel(
    const float* __restrict__ pmax, const float* __restrict__ psum,
    const float* __restrict__ pv, const int* __restrict__ Mtop,
    unsigned short* __restrict__ ctx16) {
  const int bid = blockIdx.x;          // bh*U + u
  const int u = bid % U, bh = bid / U;
  const int d = threadIdx.x;
  float gmax = -INFINITY;
  for (int c = 0; c < NJC; ++c)
    gmax = fmaxf(gmax, pmax[(size_t)(bh * NJC + c) * U + u]);
  float den = 0.f, num = 0.f;
  for (int c = 0; c < NJC; ++c) {
    const float m = pmax[(size_t)(bh * NJC + c) * U + u];
    if (m == -INFINITY) continue;
    const float s = expf(m - gmax);
    den += psum[(size_t)(bh * NJC + c) * U + u] * s;
    num += pv[((size_t)(bh * NJC + c) * U + u) * DH + d] * s;
  }
  const int h = bh % H, b = bh / H;
  const int l = Mtop[bh * U + u];
  ctx16[((size_t)b * L + l) * D + h * DH + d] = f2bf(num / den);
}

// ------------------------ cumsum(V) over l, two-pass ------------------------
__global__ __launch_bounds__(256) void cumsum_pass1(
    const float* __restrict__ V, float* __restrict__ ctx, float* __restrict__ csums) {
  const int c = blockIdx.x * 256 + threadIdx.x;
  const int ch = blockIdx.y, b = blockIdx.z;
  size_t base = ((size_t)b * L + (size_t)ch * CHLEN) * D + c;
  float acc = 0.f;
  for (int i = 0; i < CHLEN; ++i) {
    const size_t o = base + (size_t)i * D;
    acc += V[o];
    ctx[o] = acc;
  }
  csums[((size_t)b * NCHUNK + ch) * D + c] = acc;
}

// pass2 covers ALL chunks (ch=0 zero offset) and emits bf16 ctx directly.
__global__ __launch_bounds__(256) void cumsum_pass2(
    const float* __restrict__ ctx, const float* __restrict__ csums,
    unsigned short* __restrict__ ctx16) {
  const int c = blockIdx.x * 256 + threadIdx.x;
  const int ch = blockIdx.y, b = blockIdx.z;
  float off = 0.f;
  for (int j = 0; j < ch; ++j) off += csums[((size_t)b * NCHUNK + j) * D + c];
  size_t base = ((size_t)b * L + (size_t)ch * CHLEN) * D + c;
  for (int i = 0; i < CHLEN; ++i) {
    const size_t o = base + (size_t)i * D;
    ctx16[o] = f2bf(ctx[o] + off);
  }
}

// ------- out = LayerNorm(a + r) * g + be  (+ optional bf16 copy) ------------
__global__ __launch_bounds__(256) void add_ln_kernel(
    const float* __restrict__ a, const float* __restrict__ r,
    const float* __restrict__ g, const float* __restrict__ be,
    float* __restrict__ out, unsigned short* __restrict__ out16) {
  const int row = blockIdx.x;
  const int tid = threadIdx.x;
  __shared__ float buf[D];
  __shared__ float red[256];
  const float* pa = a + (size_t)row * D;
  const float* pr = r + (size_t)row * D;
  float s = 0.f;
  for (int i = tid; i < D; i += 256) { float v = pa[i] + pr[i]; buf[i] = v; s += v; }
  red[tid] = s; __syncthreads();
  for (int off = 128; off > 0; off >>= 1) {
    if (tid < off) red[tid] += red[tid+off];
    __syncthreads();
  }
  const float mu = red[0] / (float)D;
  __syncthreads();
  float s2 = 0.f;
  for (int i = tid; i < D; i += 256) { float dv = buf[i] - mu; s2 += dv * dv; }
  red[tid] = s2; __syncthreads();
  for (int off = 128; off > 0; off >>= 1) {
    if (tid < off) red[tid] += red[tid+off];
    __syncthreads();
  }
  const float rstd = rsqrtf(red[0] / (float)D + EPS);
  __syncthreads();
  float* po = out + (size_t)row * D;
  for (int i = tid; i < D; i += 256) {
    float v = (buf[i] - mu) * rstd * g[i] + be[i];
    po[i] = v;
    if (out16) out16[(size_t)row * D + i] = f2bf(v);
  }
}

// ----------------------------------------------------------------------------
extern "C" void kernel_launch(void* const* d_in, const int* in_sizes, int n_in,
                              void* d_out, int out_size, void* d_ws, size_t ws_size,
                              hipStream_t stream) {
  const float* x   = (const float*)d_in[0];
  const float* Wq  = (const float*)d_in[1];
  const float* bq  = (const float*)d_in[2];
  const float* Wk  = (const float*)d_in[3];
  const float* bk  = (const float*)d_in[4];
  const float* Wv  = (const float*)d_in[5];
  const float* bv  = (const float*)d_in[6];
  const float* Wo  = (const float*)d_in[7];
  const float* bo  = (const float*)d_in[8];
  const float* g1  = (const float*)d_in[9];
  const float* be1 = (const float*)d_in[10];
  const float* W1  = (const float*)d_in[11];
  const float* b1  = (const float*)d_in[12];
  const float* W2  = (const float*)d_in[13];
  const float* b2  = (const float*)d_in[14];
  const float* g2  = (const float*)d_in[15];
  const float* be2 = (const float*)d_in[16];
  const int*   idx = (const int*)d_in[17];
  float* out = (float*)d_out;

  char* p = (char*)d_ws;
  // ---- workspace (stream-ordered lifetimes) ----
  // R1 [0,16M): A2 (1-3) -> ctxb (9a-9b) -> AO (11-12) -> ff2 (14-15)
  unsigned short* A2   = (unsigned short*)p;
  float*          ctxb = (float*)p;
  float*          AO   = (float*)p;
  float*          ff2  = (float*)p;
  // R2 [16M,24M): xb (1-5) -> ctx16 (9b-11)
  unsigned short* xb    = (unsigned short*)(p + 16777216);
  unsigned short* ctx16 = (unsigned short*)(p + 16777216);
  // R3 [24M,36M): B2 (2-3, 12.58MB) -> scratch (6-10; first write at step 6)
  unsigned short* B2 = (unsigned short*)(p + 25165824);
  char* scr = p + 25165824;
  float* Mbuf   = (float*)(scr);             // 262,144
  float* csum   = (float*)(scr + 262144);    // 262,144
  int*   Mtop   = (int*)  (scr + 524288);    // 5,120 (pad 8192)
  float* pmax   = (float*)(scr + 532480);    // 81,920
  float* psum   = (float*)(scr + 614400);    // 81,920
  float* pv     = (float*)(scr + 696320);    // 5,242,880 -> ends 5,939,200
  // R4 [36M,68M): QKb (3-8) -> x1 [36M,52M) (12-15) + x1b [52M,60M) (12-13)
  float*          QKb = (float*)(p + 37748736);
  float*          x1  = (float*)(p + 37748736);
  unsigned short* x1b = (unsigned short*)(p + 54525952);
  // [60M,92M): ff1b (13-14); overlaps QKb tail (dead after 8) only
  unsigned short* ff1b = (unsigned short*)(p + 62914560);
  // [92M,108M): Vb (5-9)
  float* Vb = (float*)(p + 96468992);
  // [108M,128M): bf16 weights (4-14)
  unsigned short* Wvt = (unsigned short*)(p + 113246208);
  unsigned short* Wot = (unsigned short*)(p + 115343360);
  unsigned short* W1t = (unsigned short*)(p + 117440512);
  unsigned short* W2t = (unsigned short*)(p + 125829120);
  // [128M, 128M+8K): qkbias — dedicated slot, must not overlap B2 (round-7 bug)
  float* qkbias = (float*)(p + 134217728);

  dim3 blk(256);
  const int M = B * L;   // 4096
  const int SZ = B * L * D;

  // 1) inputs prep: A2 [hi|lo] + bf16 copy
  split_x_f16_kernel<<<(SZ/4 + 255)/256, blk, 0, stream>>>(x, A2, xb);
  // 2) QK weight split + bias concat
  wsplit_f16_kernel<<<dim3(D/32, D/32), blk, 0, stream>>>(Wq, B2);
  wsplit_f16_kernel<<<dim3(D/32, D/32), blk, 0, stream>>>(Wk, B2 + (size_t)D * LD3);
  concat2_kernel<<<8, blk, 0, stream>>>(bq, bk, qkbias);
  // 3) QK via f16 hi/lo 3-term split (fp32-accurate), A-dedup layout
  gemm128_kernel<false,false,true,true><<<dim3(LD2/128, M/128), blk, 0, stream>>>(
      A2, B2, qkbias, QKb, M, LD2, LD3, LDA2);
  // 4) bf16 weight transposes
  transpose_bf16_kernel<<<dim3(D/32,  D/32),   blk, 0, stream>>>(Wv, Wvt, D, D);
  transpose_bf16_kernel<<<dim3(D/32,  D/32),   blk, 0, stream>>>(Wo, Wot, D, D);
  transpose_bf16_kernel<<<dim3(FFD/32, D/32),  blk, 0, stream>>>(W1, W1t, D, FFD);
  transpose_bf16_kernel<<<dim3(D/32,  FFD/32), blk, 0, stream>>>(W2, W2t, FFD, D);
  // 5) V projection (bf16: LN renorm makes cumsum error relative — safe)
  gemm128_kernel<false,false,false,false><<<dim3(D/128, M/128), blk, 0, stream>>>(
      xb, Wvt, bv, Vb, M, D, D, D);
  // 6-8) ProbSparse attention scoring
  prob_m_kernel<<<dim3(8, L), blk, 0, stream>>>(QKb, idx, Mbuf);
  topk_kernel<<<B*H, dim3(64), 0, stream>>>(Mbuf, Mtop);
  attn_p1_kernel<<<dim3(NJC, H, B), dim3(320), 0, stream>>>(QKb, Vb, Mtop, pmax, psum, pv);
  // 9) context = cumsum(V), emitted directly as bf16
  cumsum_pass1<<<dim3(D/256, NCHUNK, B), blk, 0, stream>>>(Vb, ctxb, csum);
  cumsum_pass2<<<dim3(D/256, NCHUNK, B), blk, 0, stream>>>(ctxb, csum, ctx16);
  // 10) attn combine + scatter into ctx16
  attn_p2_kernel<<<B*H*U, dim3(64), 0, stream>>>(pmax, psum, pv, Mtop, ctx16);
  // 11) output projection (bias fused)
  gemm128_kernel<false,false,false,false><<<dim3(D/128, M/128), blk, 0, stream>>>(
      ctx16, Wot, bo, AO, M, D, D, D);
  // 12) LN1
  add_ln_kernel<<<B*L, blk, 0, stream>>>(x, AO, g1, be1, x1, x1b);
  // 13) FF1 (bias+relu fused, bf16 out)
  gemm128_kernel<true,true,false,false><<<dim3(FFD/128, M/128), blk, 0, stream>>>(
      x1b, W1t, b1, ff1b, M, FFD, D, D);
  // 14) FF2 (bias fused)
  gemm128_kernel<false,false,false,false><<<dim3(D/128, M/128), blk, 0, stream>>>(
      ff1b, W2t, b2, ff2, M, D, FFD, FFD);
  // 15) LN2
  add_ln_kernel<<<B*L, blk, 0, stream>>>(x1, ff2, g2, be2, out,
                                         (unsigned short*)nullptr);
}

// Round 10
// 366.818 us; speedup vs baseline: 5.8367x; 1.0487x over previous
//
#include <hip/hip_runtime.h>
#include <hip/hip_bf16.h>
#include <hip/hip_fp16.h>
#include <math.h>

constexpr int B = 2, L = 2048, D = 1024, H = 16, DH = 64, FFD = 4096;
constexpr int S = 40;   // sample_k
constexpr int U = 40;   // n_top
constexpr float EPS = 1e-5f;
constexpr int NCHUNK = 32;
constexpr int CHLEN = L / NCHUNK;   // 64
constexpr int LD3 = 3 * D;          // QK split GEMM K' (3072)
constexpr int LD2 = 2 * D;          // QK output row stride
constexpr int LDA2 = 2 * D;         // A2 row stride [hi|lo]
constexpr int JT = 128;             // attn j-chunk
constexpr int NJC = L / JT;         // 16

typedef __attribute__((ext_vector_type(8))) short short8;      // 8 bf16/f16 bits
typedef __attribute__((ext_vector_type(8))) _Float16 half8;
typedef __attribute__((ext_vector_type(4))) float f32x4;

__device__ __forceinline__ unsigned short f2bf(float v) {
  __hip_bfloat16 h = __float2bfloat16(v);
  return __builtin_bit_cast(unsigned short, h);
}
__device__ __forceinline__ float bf2f(unsigned short u) {
  unsigned int x = ((unsigned int)u) << 16;
  return __builtin_bit_cast(float, x);
}
__device__ __forceinline__ unsigned short f2h(float v) {
  __half h = __float2half(v);
  return __builtin_bit_cast(unsigned short, h);
}
__device__ __forceinline__ float h2f(unsigned short u) {
  return __half2float(__builtin_bit_cast(__half, u));
}

__device__ __forceinline__ void gload16(const void* g, void* l) {
  __builtin_amdgcn_global_load_lds(
      (const __attribute__((address_space(1))) void*)g,
      (__attribute__((address_space(3))) void*)l, 16, 0, 0);
}

// ======== pipelined MFMA GEMM: 128xGBN tile, BK=64, DOUBLE-buffered LDS =====
// GBN=128: 64 KB LDS -> 2 blocks/CU.  GBN=64: 48 KB LDS -> 3 blocks/CU (used
// for N=1024 shapes so the grid is >=2 blocks/CU; cross-block overlap hides
// LDS-read vs MFMA). Counted vmcnt (8 or 6), raw s_barrier, T2 source-side
// XOR swizzle, T5 setprio, XCD-aware bijective block swizzle.
// DUPA: A has K/3 duplicated layout [hi|lo] (KA=2K/3); K-tiles [16,32) re-read
// the hi columns (QK 3-term f16 split). DUPA also selects split bias:
// col < D -> bias[], else biasB[] (kills the concat kernel).
template<int GBN, int MINB, bool RELU, bool OUT_BF16, bool F16, bool DUPA>
__global__ __launch_bounds__(256, MINB) void gemm_kernel(
    const unsigned short* __restrict__ A,    // [M][KA] bits
    const unsigned short* __restrict__ Bt,   // [N][K] bits
    const float* __restrict__ bias,          // [N] (or [D] when DUPA)
    const float* __restrict__ biasB,         // [D] second half when DUPA
    void* __restrict__ C, int M, int N, int K, int KA) {
  constexpr int GBM = 128, GBK = 64;
  constexpr int ABUF = GBM * GBK;        // 8192 shorts
  constexpr int BBUF = GBN * GBK;        // 8192 or 4096 shorts
  constexpr int BUFS = ABUF + BBUF;
  constexpr int NI = GBN / 32;           // B frags per wave (4 or 2)
  constexpr int NLOADS = 4 + GBN / 32;   // vmem ops per thread per tile
  __shared__ short lds[2 * BUFS];

  const int tid  = threadIdx.x;
  const int lane = tid & 63;
  const int wid  = tid >> 6;          // 0..3
  const int wr = wid >> 1;            // 0..1 (64-row band)
  const int wc = wid & 1;             // 0..1 (GBN/2-col band)

  // XCD-aware bijective block swizzle (nwg % 8 == 0 for all our shapes)
  const int nwg  = gridDim.x * gridDim.y;
  const int orig = blockIdx.y * gridDim.x + blockIdx.x;
  const int wg   = (orig & 7) * (nwg >> 3) + (orig >> 3);
  const int bm = (wg / gridDim.x) * GBM;
  const int bn = (wg % gridDim.x) * GBN;

  // staging: wave w covers rows w*8 + (lane>>3) (+32 per issue),
  // physical 16B slot (lane&7) holds logical slot (lane&7)^(row&7)  [T2/G21]
  const int srow  = lane >> 3;                 // 0..7 == row&7
  const int sslot = (lane & 7) ^ srow;         // pre-swizzled source slot
  const unsigned short* aS = A  + (size_t)(bm + wid * 8 + srow) * KA + sslot * 8;
  const unsigned short* bS = Bt + (size_t)(bn + wid * 8 + srow) * K  + sslot * 8;
  short* la0 = lds + wid * 8 * GBK;
  short* lb0 = lds + ABUF + wid * 8 * GBK;

  auto STAGE = [&](int buf, int kt) {          // NLOADS vmem ops / thread
    const int akt = (DUPA && kt >= 16) ? kt - 16 : kt;
    const unsigned short* ap = aS + (size_t)akt * GBK;
    const unsigned short* bp = bS + (size_t)kt  * GBK;
    short* la = la0 + buf * BUFS;
    short* lb = lb0 + buf * BUFS;
    gload16(ap,                   la);
    gload16(ap + (size_t)32 * KA, la + 32 * GBK);
    gload16(ap + (size_t)64 * KA, la + 64 * GBK);
    gload16(ap + (size_t)96 * KA, la + 96 * GBK);
    #pragma unroll
    for (int r = 0; r < GBN / 32; ++r)
      gload16(bp + (size_t)(r * 32) * K, lb + r * 32 * GBK);
  };

  const int fr = lane & 15, g = lane >> 4;
  const int nt = K / GBK;

  STAGE(0, 0);

  f32x4 acc[4][NI] = {};
  int cur = 0;
  for (int t = 0; t < nt; ++t) {
    const int kt = (t + 1 < nt) ? t + 1 : t;          // clamp keeps vmcnt uniform
    STAGE(cur ^ 1, kt);                               // prefetch next tile
    if constexpr (NLOADS == 8)
      asm volatile("s_waitcnt vmcnt(8)" ::: "memory"); // tile t landed; t+1 in flight
    else
      asm volatile("s_waitcnt vmcnt(6)" ::: "memory");
    __builtin_amdgcn_sched_barrier(0);
    __builtin_amdgcn_s_barrier();

    const short* la = lds + cur * BUFS;
    const short* lb = la + ABUF;
    short8 av[2][4], bv[2][NI];
    #pragma unroll
    for (int kk = 0; kk < 2; ++kk) {
      #pragma unroll
      for (int mi = 0; mi < 4; ++mi) {
        const int row = wr * 64 + mi * 16 + fr;
        av[kk][mi] = *(const short8*)&la[row * GBK + ((((kk << 2) | g) ^ (fr & 7)) << 3)];
      }
      #pragma unroll
      for (int ni = 0; ni < NI; ++ni) {
        const int row = wc * (GBN / 2) + ni * 16 + fr;
        bv[kk][ni] = *(const short8*)&lb[row * GBK + ((((kk << 2) | g) ^ (fr & 7)) << 3)];
      }
    }
    __builtin_amdgcn_s_setprio(1);
    #pragma unroll
    for (int kk = 0; kk < 2; ++kk)
      #pragma unroll
      for (int mi = 0; mi < 4; ++mi)
        #pragma unroll
        for (int ni = 0; ni < NI; ++ni) {
          if constexpr (F16)
            acc[mi][ni] = __builtin_amdgcn_mfma_f32_16x16x32_f16(
                __builtin_bit_cast(half8, av[kk][mi]),
                __builtin_bit_cast(half8, bv[kk][ni]), acc[mi][ni], 0, 0, 0);
          else
            acc[mi][ni] = __builtin_amdgcn_mfma_f32_16x16x32_bf16(
                av[kk][mi], bv[kk][ni], acc[mi][ni], 0, 0, 0);
        }
    __builtin_amdgcn_s_setprio(0);
    asm volatile("s_waitcnt lgkmcnt(0)" ::: "memory"); // all reads of cur retired
    __builtin_amdgcn_sched_barrier(0);
    __builtin_amdgcn_s_barrier();                      // safe to restage cur
    cur ^= 1;
  }

  // epilogue: C/D layout col=lane&15, row=(lane>>4)*4+reg  [m89/m91 verified]
  #pragma unroll
  for (int ni = 0; ni < NI; ++ni) {
    const int col = bn + wc * (GBN / 2) + ni * 16 + fr;
    const float bcol = DUPA ? (col < D ? bias[col] : biasB[col - D]) : bias[col];
    #pragma unroll
    for (int mi = 0; mi < 4; ++mi) {
      #pragma unroll
      for (int j = 0; j < 4; ++j) {
        const int rowg = bm + wr * 64 + mi * 16 + (g << 2) + j;
        float v = acc[mi][ni][j] + bcol;
        if (RELU) v = fmaxf(v, 0.f);
        if (OUT_BF16) ((unsigned short*)C)[(size_t)rowg * N + col] = f2bf(v);
        else          ((float*)C)[(size_t)rowg * N + col] = v;
      }
    }
  }
}

// ---- x[M][D] f32 -> A2[M][2D] f16 [hi|lo]  AND  xb[M][D] bf16 --------------
__global__ __launch_bounds__(256) void split_x_f16_kernel(
    const float* __restrict__ x, unsigned short* __restrict__ A2,
    unsigned short* __restrict__ xb) {
  const int i = (blockIdx.x * 256 + threadIdx.x) * 4;
  if (i >= B * L * D) return;
  const int m = i / D, k = i % D;
  const float4 v = *(const float4*)(x + i);
  ushort4 hi, lo, bb;
  hi.x = f2h(v.x); lo.x = f2h(v.x - h2f(hi.x)); bb.x = f2bf(v.x);
  hi.y = f2h(v.y); lo.y = f2h(v.y - h2f(hi.y)); bb.y = f2bf(v.y);
  hi.z = f2h(v.z); lo.z = f2h(v.z - h2f(hi.z)); bb.z = f2bf(v.z);
  hi.w = f2h(v.w); lo.w = f2h(v.w - h2f(hi.w)); bb.w = f2bf(v.w);
  unsigned short* row = A2 + (size_t)m * LDA2;
  *(ushort4*)(row + k)     = hi;
  *(ushort4*)(row + D + k) = lo;
  *(ushort4*)(xb + i) = bb;
}

// ------ W[D][D] f32 -> B2rows[n][3D] f16 bits: [hi(k) | lo(k) | hi(k)] ------
__global__ __launch_bounds__(256) void wsplit_f16_kernel(
    const float* __restrict__ W, unsigned short* __restrict__ B2r) {
  __shared__ float tile[32][33];
  const int bx = blockIdx.x * 32;   // n
  const int by = blockIdx.y * 32;   // k
  const int tx = threadIdx.x & 31, ty = threadIdx.x >> 5;
  #pragma unroll
  for (int i = ty; i < 32; i += 8)
    tile[i][tx] = W[(size_t)(by + i) * D + bx + tx];
  __syncthreads();
  #pragma unroll
  for (int i = ty; i < 32; i += 8) {
    const float v = tile[tx][i];    // W[by+tx][bx+i]
    const unsigned short hi = f2h(v);
    const unsigned short lo = f2h(v - h2f(hi));
    unsigned short* r = B2r + (size_t)(bx + i) * LD3 + (by + tx);
    r[0]     = hi;
    r[D]     = lo;
    r[2 * D] = hi;
  }
}

// ---- fused transpose+bf16 for Wv, Wo, W1, W2 (one launch, block ranges) ----
__global__ __launch_bounds__(256) void transpose4_bf16_kernel(
    const float* __restrict__ Wv, const float* __restrict__ Wo,
    const float* __restrict__ W1, const float* __restrict__ W2,
    unsigned short* __restrict__ Wvt, unsigned short* __restrict__ Wot,
    unsigned short* __restrict__ W1t, unsigned short* __restrict__ W2t) {
  const int bid = blockIdx.x;
  const float* W; unsigned short* Wt; int K, N, t;
  if (bid < 1024)      { W = Wv; Wt = Wvt; K = D;   N = D;   t = bid; }
  else if (bid < 2048) { W = Wo; Wt = Wot; K = D;   N = D;   t = bid - 1024; }
  else if (bid < 6144) { W = W1; Wt = W1t; K = D;   N = FFD; t = bid - 2048; }
  else                 { W = W2; Wt = W2t; K = FFD; N = D;   t = bid - 6144; }
  const int nx = N / 32;
  const int bx = (t % nx) * 32;   // N offset
  const int by = (t / nx) * 32;   // K offset
  __shared__ float tile[32][33];
  const int tx = threadIdx.x & 31, ty = threadIdx.x >> 5;
  #pragma unroll
  for (int i = ty; i < 32; i += 8)
    tile[i][tx] = W[(size_t)(by + i) * N + bx + tx];
  __syncthreads();
  #pragma unroll
  for (int i = ty; i < 32; i += 8)
    Wt[(size_t)(bx + i) * K + by + tx] = f2bf(tile[tx][i]);
}

// ------------- M[b,h,l] = max_s(Q[l]·K[idx[l,s]]) - sum_s(...)/L ------------
// Head-sliced + XCD-pinned: grid (8, L); per-combo K working set 2 MB -> L2.
__global__ __launch_bounds__(256) void prob_m_kernel(
    const float* __restrict__ QK, const int* __restrict__ idx,
    float* __restrict__ M_) {
  const int combo = blockIdx.x;        // 0..7
  const int b = combo >> 2, hg = combo & 3;
  const int l = blockIdx.y;
  const int tid = threadIdx.x;
  const int wave = tid >> 6;           // 0..3
  const int lane = tid & 63;
  const int h = hg * 4 + wave;
  __shared__ int sidx[S];
  if (tid < S) sidx[tid] = idx[l * S + tid];
  __syncthreads();
  const int dsub = (lane & 15) * 4;
  const int sgrp = lane >> 4;          // 0..3
  const float4 q = *(const float4*)(QK + ((size_t)b * L + l) * LD2 + h * DH + dsub);
  float mx = -INFINITY, sm = 0.f;
  for (int s = sgrp; s < S; s += 4) {
    const float4 kv = *(const float4*)(QK + ((size_t)b * L + sidx[s]) * LD2 + D + h * DH + dsub);
    float p = q.x*kv.x + q.y*kv.y + q.z*kv.z + q.w*kv.w;
    p += __shfl_xor(p, 1);
    p += __shfl_xor(p, 2);
    p += __shfl_xor(p, 4);
    p += __shfl_xor(p, 8);
    mx = fmaxf(mx, p);
    sm += p;
  }
  mx = fmaxf(mx, __shfl_xor(mx, 16));
  mx = fmaxf(mx, __shfl_xor(mx, 32));
  sm += __shfl_xor(sm, 16);
  sm += __shfl_xor(sm, 32);
  if (lane == 0)
    M_[((size_t)b * H + h) * L + l] = mx - sm / (float)L;
}

// ---- exact top-k (k=40, n=2048): single wave, register-resident, no LDS ----
__global__ __launch_bounds__(64) void topk_kernel(
    const float* __restrict__ M_, int* __restrict__ Mtop) {
  const int bh = blockIdx.x;
  const float* row = M_ + (size_t)bh * L;
  const int lane = threadIdx.x;   // 0..63
  float v[32];
  #pragma unroll
  for (int k = 0; k < 32; ++k) v[k] = row[k * 64 + lane];
  for (int u = 0; u < U; ++u) {
    float best = v[0]; int bk = 0;
    #pragma unroll
    for (int k = 1; k < 32; ++k)
      if (v[k] > best) { best = v[k]; bk = k; }        // strict >: lower k wins
    int bidx = bk * 64 + lane;
    #pragma unroll
    for (int off = 1; off < 64; off <<= 1) {
      const float ov = __shfl_xor(best, off);
      const int   oi = __shfl_xor(bidx, off);
      if (ov > best || (ov == best && oi < bidx)) { best = ov; bidx = oi; }
    }
    if (lane == 0) Mtop[bh * U + u] = bidx;            // all lanes agree
    if ((bidx & 63) == lane) {                          // kill winner (static idx)
      const int kk = bidx >> 6;
      #pragma unroll
      for (int k = 0; k < 32; ++k) if (k == kk) v[k] = -INFINITY;
    }
  }
}

// ------- attn phase 1: per (b,h,jc) partial softmax + PV over 128 keys ------
__global__ __launch_bounds__(320) void attn_p1_kernel(
    const float* __restrict__ QK, const float* __restrict__ V,
    const int* __restrict__ Mtop,
    float* __restrict__ pmax, float* __restrict__ psum, float* __restrict__ pv) {
  const int jc = blockIdx.x, h = blockIdx.y, b = blockIdx.z;
  const int bh = b * H + h;
  const int tid = threadIdx.x;
  const int j0 = jc * JT;
  __shared__ float Qs[U][68];
  __shared__ float KVs[JT][68];
  __shared__ unsigned short ws[U][JT];

  for (int i = tid; i < U * 16; i += 320) {
    const int u = i >> 4, dq = (i & 15) << 2;
    const int row = Mtop[bh * U + u];
    *(float4*)&Qs[u][dq] =
        *(const float4*)(QK + ((size_t)b * L + row) * LD2 + h * DH + dq);
  }
  for (int i = tid; i < JT * 16; i += 320) {
    const int j = i >> 4, dq = (i & 15) << 2;
    *(float4*)&KVs[j][dq] =
        *(const float4*)(QK + ((size_t)b * L + j0 + j) * LD2 + D + h * DH + dq);
  }
  __syncthreads();

  const int u = tid >> 3, jg = tid & 7;
  const int mt = Mtop[bh * U + u];
  float sc[16];
  #pragma unroll
  for (int jt = 0; jt < 16; ++jt) sc[jt] = 0.f;
  for (int dq = 0; dq < 64; dq += 4) {
    const float4 q = *(const float4*)&Qs[u][dq];
    #pragma unroll
    for (int jt = 0; jt < 16; ++jt) {
      const float4 k = *(const float4*)&KVs[jt * 8 + jg][dq];
      sc[jt] += q.x*k.x + q.y*k.y + q.z*k.z + q.w*k.w;
    }
  }
  float m = -INFINITY;
  #pragma unroll
  for (int jt = 0; jt < 16; ++jt) {
    const int j = j0 + jt * 8 + jg;
    sc[jt] = (j <= mt) ? sc[jt] * 0.125f : -INFINITY;
    m = fmaxf(m, sc[jt]);
  }
  m = fmaxf(m, __shfl_xor(m, 1));
  m = fmaxf(m, __shfl_xor(m, 2));
  m = fmaxf(m, __shfl_xor(m, 4));
  float sum = 0.f;
  #pragma unroll
  for (int jt = 0; jt < 16; ++jt) {
    const float e = (sc[jt] == -INFINITY) ? 0.f : expf(sc[jt] - m);
    sum += e;
    ws[u][jt * 8 + jg] = f2bf(e);
  }
  sum += __shfl_xor(sum, 1);
  sum += __shfl_xor(sum, 2);
  sum += __shfl_xor(sum, 4);
  if (jg == 0) {
    pmax[(size_t)(bh * NJC + jc) * U + u] = m;
    psum[(size_t)(bh * NJC + jc) * U + u] = sum;
  }
  __syncthreads();
  // reload LDS with V chunk
  for (int i = tid; i < JT * 16; i += 320) {
    const int j = i >> 4, dq = (i & 15) << 2;
    *(float4*)&KVs[j][dq] =
        *(const float4*)(V + ((size_t)b * L + j0 + j) * D + h * DH + dq);
  }
  __syncthreads();
  const int d = tid & 63, ug = tid >> 6;
  float acc[8] = {};
  for (int j = 0; j < JT; j += 2) {
    const float v0 = KVs[j][d], v1 = KVs[j + 1][d];
    #pragma unroll
    for (int k = 0; k < 8; ++k) {
      const int uu = ug + k * 5;
      const unsigned int wp = *(const unsigned int*)&ws[uu][j];
      acc[k] = fmaf(bf2f((unsigned short)(wp & 0xffff)), v0, acc[k]);
      acc[k] = fmaf(bf2f((unsigned short)(wp >> 16)), v1, acc[k]);
    }
  }
  #pragma unroll
  for (int k = 0; k < 8; ++k) {
    const int uu = ug + k * 5;
    pv[((size_t)(bh * NJC + jc) * U + uu) * DH + d] = acc[k];
  }
}

// -- attn phase 2: combine 16 chunks per (b,h,u), scatter into ctx16 (bf16) --
__global__ __launch_bounds__(64) void attn_p2_kernel(
    const float* __restrict__ pmax, const float* __restrict__ psum,
    const float* __restrict__ pv, const int* __restrict__ Mtop,
    unsigned short* __restrict__ ctx16) {
  const int bid = blockIdx.x;          // bh*U + u
  const int u = bid % U, bh = bid / U;
  const int d = threadIdx.x;
  float gmax = -INFINITY;
  for (int c = 0; c < NJC; ++c)
    gmax = fmaxf(gmax, pmax[(size_t)(bh * NJC + c) * U + u]);
  float den = 0.f, num = 0.f;
  for (int c = 0; c < NJC; ++c) {
    const float m = pmax[(size_t)(bh * NJC + c) * U + u];
    if (m == -INFINITY) continue;
    const float s = expf(m - gmax);
    den += psum[(size_t)(bh * NJC + c) * U + u] * s;
    num += pv[((size_t)(bh * NJC + c) * U + u) * DH + d] * s;
  }
  const int h = bh % H, b = bh / H;
  const int l = Mtop[bh * U + u];
  ctx16[((size_t)b * L + l) * D + h * DH + d] = f2bf(num / den);
}

// ------------------------ cumsum(V) over l, two-pass ------------------------
__global__ __launch_bounds__(256) void cumsum_pass1(
    const float* __restrict__ V, float* __restrict__ ctx, float* __restrict__ csums) {
  const int c = blockIdx.x * 256 + threadIdx.x;
  const int ch = blockIdx.y, b = blockIdx.z;
  size_t base = ((size_t)b * L + (size_t)ch * CHLEN) * D + c;
  float acc = 0.f;
  for (int i = 0; i < CHLEN; ++i) {
    const size_t o = base + (size_t)i * D;
    acc += V[o];
    ctx[o] = acc;
  }
  csums[((size_t)b * NCHUNK + ch) * D + c] = acc;
}

// pass2 covers ALL chunks (ch=0 zero offset) and emits bf16 ctx directly.
__global__ __launch_bounds__(256) void cumsum_pass2(
    const float* __restrict__ ctx, const float* __restrict__ csums,
    unsigned short* __restrict__ ctx16) {
  const int c = blockIdx.x * 256 + threadIdx.x;
  const int ch = blockIdx.y, b = blockIdx.z;
  float off = 0.f;
  for (int j = 0; j < ch; ++j) off += csums[((size_t)b * NCHUNK + j) * D + c];
  size_t base = ((size_t)b * L + (size_t)ch * CHLEN) * D + c;
  for (int i = 0; i < CHLEN; ++i) {
    const size_t o = base + (size_t)i * D;
    ctx16[o] = f2bf(ctx[o] + off);
  }
}

// -- out = LayerNorm(a + r) * g + be; a is f32 or bf16; f32/bf16 outs opt. ---
template<bool ABF16>
__global__ __launch_bounds__(256) void add_ln_kernel(
    const void* __restrict__ a_, const float* __restrict__ r,
    const float* __restrict__ g, const float* __restrict__ be,
    float* __restrict__ out, unsigned short* __restrict__ out16) {
  const int row = blockIdx.x;
  const int tid = threadIdx.x;
  __shared__ float buf[D];
  __shared__ float red[256];
  const float* pr = r + (size_t)row * D;
  float s = 0.f;
  for (int i = tid; i < D; i += 256) {
    float av;
    if (ABF16) av = bf2f(((const unsigned short*)a_)[(size_t)row * D + i]);
    else       av = ((const float*)a_)[(size_t)row * D + i];
    float v = av + pr[i];
    buf[i] = v; s += v;
  }
  red[tid] = s; __syncthreads();
  for (int off = 128; off > 0; off >>= 1) {
    if (tid < off) red[tid] += red[tid+off];
    __syncthreads();
  }
  const float mu = red[0] / (float)D;
  __syncthreads();
  float s2 = 0.f;
  for (int i = tid; i < D; i += 256) { float dv = buf[i] - mu; s2 += dv * dv; }
  red[tid] = s2; __syncthreads();
  for (int off = 128; off > 0; off >>= 1) {
    if (tid < off) red[tid] += red[tid+off];
    __syncthreads();
  }
  const float rstd = rsqrtf(red[0] / (float)D + EPS);
  __syncthreads();
  for (int i = tid; i < D; i += 256) {
    float v = (buf[i] - mu) * rstd * g[i] + be[i];
    if (out)   out[(size_t)row * D + i] = v;
    if (out16) out16[(size_t)row * D + i] = f2bf(v);
  }
}

// ----------------------------------------------------------------------------
extern "C" void kernel_launch(void* const* d_in, const int* in_sizes, int n_in,
                              void* d_out, int out_size, void* d_ws, size_t ws_size,
                              hipStream_t stream) {
  const float* x   = (const float*)d_in[0];
  const float* Wq  = (const float*)d_in[1];
  const float* bq  = (const float*)d_in[2];
  const float* Wk  = (const float*)d_in[3];
  const float* bk  = (const float*)d_in[4];
  const float* Wv  = (const float*)d_in[5];
  const float* bv  = (const float*)d_in[6];
  const float* Wo  = (const float*)d_in[7];
  const float* bo  = (const float*)d_in[8];
  const float* g1  = (const float*)d_in[9];
  const float* be1 = (const float*)d_in[10];
  const float* W1  = (const float*)d_in[11];
  const float* b1  = (const float*)d_in[12];
  const float* W2  = (const float*)d_in[13];
  const float* b2  = (const float*)d_in[14];
  const float* g2  = (const float*)d_in[15];
  const float* be2 = (const float*)d_in[16];
  const int*   idx = (const int*)d_in[17];
  float* out = (float*)d_out;

  char* p = (char*)d_ws;
  // ---- workspace (stream-ordered lifetimes) ----
  // R1 [0,16M): A2 (1-3) -> ctxb (9a-9b) -> AO (11-12) -> ff2 (14-15)
  unsigned short* A2   = (unsigned short*)p;
  float*          ctxb = (float*)p;
  float*          AO   = (float*)p;
  float*          ff2  = (float*)p;
  // R2 [16M,24M): xb (1-5) -> ctx16 (9b-11)
  unsigned short* xb    = (unsigned short*)(p + 16777216);
  unsigned short* ctx16 = (unsigned short*)(p + 16777216);
  // R3 [24M,36M): B2 (2-3, 12.58MB) -> scratch (6-10; first write at step 6)
  unsigned short* B2 = (unsigned short*)(p + 25165824);
  char* scr = p + 25165824;
  float* Mbuf   = (float*)(scr);             // 262,144
  float* csum   = (float*)(scr + 262144);    // 262,144
  int*   Mtop   = (int*)  (scr + 524288);    // 5,120 (pad 8192)
  float* pmax   = (float*)(scr + 532480);    // 81,920
  float* psum   = (float*)(scr + 614400);    // 81,920
  float* pv     = (float*)(scr + 696320);    // 5,242,880 -> ends 5,939,200
  // R4 [36M,68M): QKb (3-8) -> x1b [52M,60M) (12-15)
  float*          QKb = (float*)(p + 37748736);
  unsigned short* x1b = (unsigned short*)(p + 54525952);
  // [60M,92M): ff1b (13-14); overlaps QKb tail (dead after 8) only
  unsigned short* ff1b = (unsigned short*)(p + 62914560);
  // [92M,108M): Vb (5-9)
  float* Vb = (float*)(p + 96468992);
  // [108M,128M): bf16 weights (4-14)
  unsigned short* Wvt = (unsigned short*)(p + 113246208);
  unsigned short* Wot = (unsigned short*)(p + 115343360);
  unsigned short* W1t = (unsigned short*)(p + 117440512);
  unsigned short* W2t = (unsigned short*)(p + 125829120);

  dim3 blk(256);
  const int M = B * L;   // 4096
  const int SZ = B * L * D;

  // 1) inputs prep: A2 [hi|lo] + bf16 copy
  split_x_f16_kernel<<<(SZ/4 + 255)/256, blk, 0, stream>>>(x, A2, xb);
  // 2) QK weight split
  wsplit_f16_kernel<<<dim3(D/32, D/32), blk, 0, stream>>>(Wq, B2);
  wsplit_f16_kernel<<<dim3(D/32, D/32), blk, 0, stream>>>(Wk, B2 + (size_t)D * LD3);
  // 3) QK via f16 hi/lo 3-term split (fp32-accurate), A-dedup, split bias
  gemm_kernel<128,2,false,false,true,true><<<dim3(LD2/128, M/128), blk, 0, stream>>>(
      A2, B2, bq, bk, QKb, M, LD2, LD3, LDA2);
  // 4) bf16 weight transposes (fused, one launch)
  transpose4_bf16_kernel<<<10240, blk, 0, stream>>>(Wv, Wo, W1, W2, Wvt, Wot, W1t, W2t);
  // 5) V projection (bf16; GBN=64 -> 512 blocks, 3 blocks/CU)
  gemm_kernel<64,3,false,false,false,false><<<dim3(D/64, M/128), blk, 0, stream>>>(
      xb, Wvt, bv, bv, Vb, M, D, D, D);
  // 6-8) ProbSparse attention scoring
  prob_m_kernel<<<dim3(8, L), blk, 0, stream>>>(QKb, idx, Mbuf);
  topk_kernel<<<B*H, dim3(64), 0, stream>>>(Mbuf, Mtop);
  attn_p1_kernel<<<dim3(NJC, H, B), dim3(320), 0, stream>>>(QKb, Vb, Mtop, pmax, psum, pv);
  // 9) context = cumsum(V), emitted directly as bf16
  cumsum_pass1<<<dim3(D/256, NCHUNK, B), blk, 0, stream>>>(Vb, ctxb, csum);
  cumsum_pass2<<<dim3(D/256, NCHUNK, B), blk, 0, stream>>>(ctxb, csum, ctx16);
  // 10) attn combine + scatter into ctx16
  attn_p2_kernel<<<B*H*U, dim3(64), 0, stream>>>(pmax, psum, pv, Mtop, ctx16);
  // 11) output projection (bias fused; GBN=64)
  gemm_kernel<64,3,false,false,false,false><<<dim3(D/64, M/128), blk, 0, stream>>>(
      ctx16, Wot, bo, bo, AO, M, D, D, D);
  // 12) LN1 -> bf16 residual only
  add_ln_kernel<false><<<B*L, blk, 0, stream>>>(x, AO, g1, be1, nullptr, x1b);
  // 13) FF1 (bias+relu fused, bf16 out)
  gemm_kernel<128,2,true,true,false,false><<<dim3(FFD/128, M/128), blk, 0, stream>>>(
      x1b, W1t, b1, b1, ff1b, M, FFD, D, D);
  // 14) FF2 (bias fused; GBN=64)
  gemm_kernel<64,3,false,false,false,false><<<dim3(D/64, M/128), blk, 0, stream>>>(
      ff1b, W2t, b2, b2, ff2, M, D, FFD, FFD);
  // 15) LN2 (bf16 residual in, f32 out)
  add_ln_kernel<true><<<B*L, blk, 0, stream>>>(x1b, ff2, g2, be2, out,
                                               (unsigned short*)nullptr);
}

// Round 11
// 350.781 us; speedup vs baseline: 6.1036x; 1.0457x over previous
//
#include <hip/hip_runtime.h>
#include <hip/hip_bf16.h>
#include <hip/hip_fp16.h>
#include <math.h>

constexpr int B = 2, L = 2048, D = 1024, H = 16, DH = 64, FFD = 4096;
constexpr int S = 40;   // sample_k
constexpr int U = 40;   // n_top
constexpr float EPS = 1e-5f;
constexpr int NCHUNK = 32;
constexpr int CHLEN = L / NCHUNK;   // 64
constexpr int LD3 = 3 * D;          // QK split GEMM K' (3072)
constexpr int LD2 = 2 * D;          // QK output row stride
constexpr int LDA2 = 2 * D;         // A2 row stride [hi|lo]
constexpr int JT = 128;             // attn j-chunk
constexpr int NJC = L / JT;         // 16

typedef __attribute__((ext_vector_type(8))) short short8;      // 8 bf16/f16 bits
typedef __attribute__((ext_vector_type(8))) _Float16 half8;
typedef __attribute__((ext_vector_type(4))) float f32x4;

__device__ __forceinline__ unsigned short f2bf(float v) {
  __hip_bfloat16 h = __float2bfloat16(v);
  return __builtin_bit_cast(unsigned short, h);
}
__device__ __forceinline__ float bf2f(unsigned short u) {
  unsigned int x = ((unsigned int)u) << 16;
  return __builtin_bit_cast(float, x);
}
__device__ __forceinline__ unsigned short f2h(float v) {
  __half h = __float2half(v);
  return __builtin_bit_cast(unsigned short, h);
}
__device__ __forceinline__ float h2f(unsigned short u) {
  return __half2float(__builtin_bit_cast(__half, u));
}

__device__ __forceinline__ void gload16(const void* g, void* l) {
  __builtin_amdgcn_global_load_lds(
      (const __attribute__((address_space(1))) void*)g,
      (__attribute__((address_space(3))) void*)l, 16, 0, 0);
}

// ======== pipelined MFMA GEMM: 128xGBN tile, BK=64, DOUBLE-buffered LDS =====
// GBN=128: 64 KB LDS -> 2 blocks/CU.  GBN=64: 48 KB LDS -> 3 blocks/CU.
// Counted vmcnt (8 or 6), raw s_barrier, T2 source-side XOR swizzle, T5
// setprio, XCD-aware bijective block swizzle.
// DUPA: A has K/3 duplicated layout [hi|lo] (KA=2K/3); K-tiles [16,32) re-read
// the hi columns (QK 3-term f16 split). DUPA also selects split bias:
// col < D -> bias[], else biasB[].
template<int GBN, int MINB, bool RELU, bool OUT_BF16, bool F16, bool DUPA>
__global__ __launch_bounds__(256, MINB) void gemm_kernel(
    const unsigned short* __restrict__ A,    // [M][KA] bits
    const unsigned short* __restrict__ Bt,   // [N][K] bits
    const float* __restrict__ bias,          // [N] (or [D] when DUPA)
    const float* __restrict__ biasB,         // [D] second half when DUPA
    void* __restrict__ C, int M, int N, int K, int KA) {
  constexpr int GBM = 128, GBK = 64;
  constexpr int ABUF = GBM * GBK;        // 8192 shorts
  constexpr int BBUF = GBN * GBK;        // 8192 or 4096 shorts
  constexpr int BUFS = ABUF + BBUF;
  constexpr int NI = GBN / 32;           // B frags per wave (4 or 2)
  constexpr int NLOADS = 4 + GBN / 32;   // vmem ops per thread per tile
  __shared__ short lds[2 * BUFS];

  const int tid  = threadIdx.x;
  const int lane = tid & 63;
  const int wid  = tid >> 6;          // 0..3
  const int wr = wid >> 1;            // 0..1 (64-row band)
  const int wc = wid & 1;             // 0..1 (GBN/2-col band)

  // XCD-aware bijective block swizzle (nwg % 8 == 0 for all our shapes)
  const int nwg  = gridDim.x * gridDim.y;
  const int orig = blockIdx.y * gridDim.x + blockIdx.x;
  const int wg   = (orig & 7) * (nwg >> 3) + (orig >> 3);
  const int bm = (wg / gridDim.x) * GBM;
  const int bn = (wg % gridDim.x) * GBN;

  // staging: wave w covers rows w*8 + (lane>>3) (+32 per issue),
  // physical 16B slot (lane&7) holds logical slot (lane&7)^(row&7)  [T2/G21]
  const int srow  = lane >> 3;                 // 0..7 == row&7
  const int sslot = (lane & 7) ^ srow;         // pre-swizzled source slot
  const unsigned short* aS = A  + (size_t)(bm + wid * 8 + srow) * KA + sslot * 8;
  const unsigned short* bS = Bt + (size_t)(bn + wid * 8 + srow) * K  + sslot * 8;
  short* la0 = lds + wid * 8 * GBK;
  short* lb0 = lds + ABUF + wid * 8 * GBK;

  auto STAGE = [&](int buf, int kt) {          // NLOADS vmem ops / thread
    const int akt = (DUPA && kt >= 16) ? kt - 16 : kt;
    const unsigned short* ap = aS + (size_t)akt * GBK;
    const unsigned short* bp = bS + (size_t)kt  * GBK;
    short* la = la0 + buf * BUFS;
    short* lb = lb0 + buf * BUFS;
    gload16(ap,                   la);
    gload16(ap + (size_t)32 * KA, la + 32 * GBK);
    gload16(ap + (size_t)64 * KA, la + 64 * GBK);
    gload16(ap + (size_t)96 * KA, la + 96 * GBK);
    #pragma unroll
    for (int r = 0; r < GBN / 32; ++r)
      gload16(bp + (size_t)(r * 32) * K, lb + r * 32 * GBK);
  };

  const int fr = lane & 15, g = lane >> 4;
  const int nt = K / GBK;

  STAGE(0, 0);

  f32x4 acc[4][NI] = {};
  int cur = 0;
  for (int t = 0; t < nt; ++t) {
    const int kt = (t + 1 < nt) ? t + 1 : t;          // clamp keeps vmcnt uniform
    STAGE(cur ^ 1, kt);                               // prefetch next tile
    if constexpr (NLOADS == 8)
      asm volatile("s_waitcnt vmcnt(8)" ::: "memory"); // tile t landed; t+1 in flight
    else
      asm volatile("s_waitcnt vmcnt(6)" ::: "memory");
    __builtin_amdgcn_sched_barrier(0);
    __builtin_amdgcn_s_barrier();

    const short* la = lds + cur * BUFS;
    const short* lb = la + ABUF;
    short8 av[2][4], bv[2][NI];
    #pragma unroll
    for (int kk = 0; kk < 2; ++kk) {
      #pragma unroll
      for (int mi = 0; mi < 4; ++mi) {
        const int row = wr * 64 + mi * 16 + fr;
        av[kk][mi] = *(const short8*)&la[row * GBK + ((((kk << 2) | g) ^ (fr & 7)) << 3)];
      }
      #pragma unroll
      for (int ni = 0; ni < NI; ++ni) {
        const int row = wc * (GBN / 2) + ni * 16 + fr;
        bv[kk][ni] = *(const short8*)&lb[row * GBK + ((((kk << 2) | g) ^ (fr & 7)) << 3)];
      }
    }
    __builtin_amdgcn_s_setprio(1);
    #pragma unroll
    for (int kk = 0; kk < 2; ++kk)
      #pragma unroll
      for (int mi = 0; mi < 4; ++mi)
        #pragma unroll
        for (int ni = 0; ni < NI; ++ni) {
          if constexpr (F16)
            acc[mi][ni] = __builtin_amdgcn_mfma_f32_16x16x32_f16(
                __builtin_bit_cast(half8, av[kk][mi]),
                __builtin_bit_cast(half8, bv[kk][ni]), acc[mi][ni], 0, 0, 0);
          else
            acc[mi][ni] = __builtin_amdgcn_mfma_f32_16x16x32_bf16(
                av[kk][mi], bv[kk][ni], acc[mi][ni], 0, 0, 0);
        }
    __builtin_amdgcn_s_setprio(0);
    asm volatile("s_waitcnt lgkmcnt(0)" ::: "memory"); // all reads of cur retired
    __builtin_amdgcn_sched_barrier(0);
    __builtin_amdgcn_s_barrier();                      // safe to restage cur
    cur ^= 1;
  }

  // epilogue: C/D layout col=lane&15, row=(lane>>4)*4+reg  [m89/m91 verified]
  #pragma unroll
  for (int ni = 0; ni < NI; ++ni) {
    const int col = bn + wc * (GBN / 2) + ni * 16 + fr;
    const float bcol = DUPA ? (col < D ? bias[col] : biasB[col - D]) : bias[col];
    #pragma unroll
    for (int mi = 0; mi < 4; ++mi) {
      #pragma unroll
      for (int j = 0; j < 4; ++j) {
        const int rowg = bm + wr * 64 + mi * 16 + (g << 2) + j;
        float v = acc[mi][ni][j] + bcol;
        if (RELU) v = fmaxf(v, 0.f);
        if (OUT_BF16) ((unsigned short*)C)[(size_t)rowg * N + col] = f2bf(v);
        else          ((float*)C)[(size_t)rowg * N + col] = v;
      }
    }
  }
}

// ---- x[M][D] f32 -> A2[M][2D] f16 [hi|lo]  AND  xb[M][D] bf16 --------------
__global__ __launch_bounds__(256) void split_x_f16_kernel(
    const float* __restrict__ x, unsigned short* __restrict__ A2,
    unsigned short* __restrict__ xb) {
  const int i = (blockIdx.x * 256 + threadIdx.x) * 4;
  if (i >= B * L * D) return;
  const int m = i / D, k = i % D;
  const float4 v = *(const float4*)(x + i);
  ushort4 hi, lo, bb;
  hi.x = f2h(v.x); lo.x = f2h(v.x - h2f(hi.x)); bb.x = f2bf(v.x);
  hi.y = f2h(v.y); lo.y = f2h(v.y - h2f(hi.y)); bb.y = f2bf(v.y);
  hi.z = f2h(v.z); lo.z = f2h(v.z - h2f(hi.z)); bb.z = f2bf(v.z);
  hi.w = f2h(v.w); lo.w = f2h(v.w - h2f(hi.w)); bb.w = f2bf(v.w);
  unsigned short* row = A2 + (size_t)m * LDA2;
  *(ushort4*)(row + k)     = hi;
  *(ushort4*)(row + D + k) = lo;
  *(ushort4*)(xb + i) = bb;
}

// - Wq/Wk[D][D] f32 -> B2rows[n][3D] f16 [hi(k)|lo(k)|hi(k)]; z picks Wq/Wk --
__global__ __launch_bounds__(256) void wsplit_f16_kernel(
    const float* __restrict__ Wq, const float* __restrict__ Wk,
    unsigned short* __restrict__ B2r) {
  const float* W = blockIdx.z ? Wk : Wq;
  unsigned short* outb = B2r + (size_t)blockIdx.z * D * LD3;
  __shared__ float tile[32][33];
  const int bx = blockIdx.x * 32;   // n
  const int by = blockIdx.y * 32;   // k
  const int tx = threadIdx.x & 31, ty = threadIdx.x >> 5;
  #pragma unroll
  for (int i = ty; i < 32; i += 8)
    tile[i][tx] = W[(size_t)(by + i) * D + bx + tx];
  __syncthreads();
  #pragma unroll
  for (int i = ty; i < 32; i += 8) {
    const float v = tile[tx][i];    // W[by+tx][bx+i]
    const unsigned short hi = f2h(v);
    const unsigned short lo = f2h(v - h2f(hi));
    unsigned short* r = outb + (size_t)(bx + i) * LD3 + (by + tx);
    r[0]     = hi;
    r[D]     = lo;
    r[2 * D] = hi;
  }
}

// ---- fused transpose+bf16 for Wv, Wo, W1, W2 (one launch, block ranges) ----
__global__ __launch_bounds__(256) void transpose4_bf16_kernel(
    const float* __restrict__ Wv, const float* __restrict__ Wo,
    const float* __restrict__ W1, const float* __restrict__ W2,
    unsigned short* __restrict__ Wvt, unsigned short* __restrict__ Wot,
    unsigned short* __restrict__ W1t, unsigned short* __restrict__ W2t) {
  const int bid = blockIdx.x;
  const float* W; unsigned short* Wt; int K, N, t;
  if (bid < 1024)      { W = Wv; Wt = Wvt; K = D;   N = D;   t = bid; }
  else if (bid < 2048) { W = Wo; Wt = Wot; K = D;   N = D;   t = bid - 1024; }
  else if (bid < 6144) { W = W1; Wt = W1t; K = D;   N = FFD; t = bid - 2048; }
  else                 { W = W2; Wt = W2t; K = FFD; N = D;   t = bid - 6144; }
  const int nx = N / 32;
  const int bx = (t % nx) * 32;   // N offset
  const int by = (t / nx) * 32;   // K offset
  __shared__ float tile[32][33];
  const int tx = threadIdx.x & 31, ty = threadIdx.x >> 5;
  #pragma unroll
  for (int i = ty; i < 32; i += 8)
    tile[i][tx] = W[(size_t)(by + i) * N + bx + tx];
  __syncthreads();
  #pragma unroll
  for (int i = ty; i < 32; i += 8)
    Wt[(size_t)(bx + i) * K + by + tx] = f2bf(tile[tx][i]);
}

// ------------- M[b,h,l] = max_s(Q[l]·K[idx[l,s]]) - sum_s(...)/L ------------
// Head-sliced + XCD-pinned: grid (8, L); per-combo K working set 2 MB -> L2.
__global__ __launch_bounds__(256) void prob_m_kernel(
    const float* __restrict__ QK, const int* __restrict__ idx,
    float* __restrict__ M_) {
  const int combo = blockIdx.x;        // 0..7
  const int b = combo >> 2, hg = combo & 3;
  const int l = blockIdx.y;
  const int tid = threadIdx.x;
  const int wave = tid >> 6;           // 0..3
  const int lane = tid & 63;
  const int h = hg * 4 + wave;
  __shared__ int sidx[S];
  if (tid < S) sidx[tid] = idx[l * S + tid];
  __syncthreads();
  const int dsub = (lane & 15) * 4;
  const int sgrp = lane >> 4;          // 0..3
  const float4 q = *(const float4*)(QK + ((size_t)b * L + l) * LD2 + h * DH + dsub);
  float mx = -INFINITY, sm = 0.f;
  for (int s = sgrp; s < S; s += 4) {
    const float4 kv = *(const float4*)(QK + ((size_t)b * L + sidx[s]) * LD2 + D + h * DH + dsub);
    float p = q.x*kv.x + q.y*kv.y + q.z*kv.z + q.w*kv.w;
    p += __shfl_xor(p, 1);
    p += __shfl_xor(p, 2);
    p += __shfl_xor(p, 4);
    p += __shfl_xor(p, 8);
    mx = fmaxf(mx, p);
    sm += p;
  }
  mx = fmaxf(mx, __shfl_xor(mx, 16));
  mx = fmaxf(mx, __shfl_xor(mx, 32));
  sm += __shfl_xor(sm, 16);
  sm += __shfl_xor(sm, 32);
  if (lane == 0)
    M_[((size_t)b * H + h) * L + l] = mx - sm / (float)L;
}

// ---- exact top-k (k=40, n=2048): single wave, register-resident, no LDS ----
__global__ __launch_bounds__(64) void topk_kernel(
    const float* __restrict__ M_, int* __restrict__ Mtop) {
  const int bh = blockIdx.x;
  const float* row = M_ + (size_t)bh * L;
  const int lane = threadIdx.x;   // 0..63
  float v[32];
  #pragma unroll
  for (int k = 0; k < 32; ++k) v[k] = row[k * 64 + lane];
  for (int u = 0; u < U; ++u) {
    float best = v[0]; int bk = 0;
    #pragma unroll
    for (int k = 1; k < 32; ++k)
      if (v[k] > best) { best = v[k]; bk = k; }        // strict >: lower k wins
    int bidx = bk * 64 + lane;
    #pragma unroll
    for (int off = 1; off < 64; off <<= 1) {
      const float ov = __shfl_xor(best, off);
      const int   oi = __shfl_xor(bidx, off);
      if (ov > best || (ov == best && oi < bidx)) { best = ov; bidx = oi; }
    }
    if (lane == 0) Mtop[bh * U + u] = bidx;            // all lanes agree
    if ((bidx & 63) == lane) {                          // kill winner (static idx)
      const int kk = bidx >> 6;
      #pragma unroll
      for (int k = 0; k < 32; ++k) if (k == kk) v[k] = -INFINITY;
    }
  }
}

// ------- attn phase 1: per (b,h,jc) partial softmax + PV over 128 keys ------
// V is bf16 (V16).
__global__ __launch_bounds__(320) void attn_p1_kernel(
    const float* __restrict__ QK, const unsigned short* __restrict__ V16,
    const int* __restrict__ Mtop,
    float* __restrict__ pmax, float* __restrict__ psum, float* __restrict__ pv) {
  const int jc = blockIdx.x, h = blockIdx.y, b = blockIdx.z;
  const int bh = b * H + h;
  const int tid = threadIdx.x;
  const int j0 = jc * JT;
  __shared__ float Qs[U][68];
  __shared__ float KVs[JT][68];
  __shared__ unsigned short ws[U][JT];

  for (int i = tid; i < U * 16; i += 320) {
    const int u = i >> 4, dq = (i & 15) << 2;
    const int row = Mtop[bh * U + u];
    *(float4*)&Qs[u][dq] =
        *(const float4*)(QK + ((size_t)b * L + row) * LD2 + h * DH + dq);
  }
  for (int i = tid; i < JT * 16; i += 320) {
    const int j = i >> 4, dq = (i & 15) << 2;
    *(float4*)&KVs[j][dq] =
        *(const float4*)(QK + ((size_t)b * L + j0 + j) * LD2 + D + h * DH + dq);
  }
  __syncthreads();

  const int u = tid >> 3, jg = tid & 7;
  const int mt = Mtop[bh * U + u];
  float sc[16];
  #pragma unroll
  for (int jt = 0; jt < 16; ++jt) sc[jt] = 0.f;
  for (int dq = 0; dq < 64; dq += 4) {
    const float4 q = *(const float4*)&Qs[u][dq];
    #pragma unroll
    for (int jt = 0; jt < 16; ++jt) {
      const float4 k = *(const float4*)&KVs[jt * 8 + jg][dq];
      sc[jt] += q.x*k.x + q.y*k.y + q.z*k.z + q.w*k.w;
    }
  }
  float m = -INFINITY;
  #pragma unroll
  for (int jt = 0; jt < 16; ++jt) {
    const int j = j0 + jt * 8 + jg;
    sc[jt] = (j <= mt) ? sc[jt] * 0.125f : -INFINITY;
    m = fmaxf(m, sc[jt]);
  }
  m = fmaxf(m, __shfl_xor(m, 1));
  m = fmaxf(m, __shfl_xor(m, 2));
  m = fmaxf(m, __shfl_xor(m, 4));
  float sum = 0.f;
  #pragma unroll
  for (int jt = 0; jt < 16; ++jt) {
    const float e = (sc[jt] == -INFINITY) ? 0.f : expf(sc[jt] - m);
    sum += e;
    ws[u][jt * 8 + jg] = f2bf(e);
  }
  sum += __shfl_xor(sum, 1);
  sum += __shfl_xor(sum, 2);
  sum += __shfl_xor(sum, 4);
  if (jg == 0) {
    pmax[(size_t)(bh * NJC + jc) * U + u] = m;
    psum[(size_t)(bh * NJC + jc) * U + u] = sum;
  }
  __syncthreads();
  // reload LDS with V chunk (bf16 -> f32)
  for (int i = tid; i < JT * 8; i += 320) {
    const int j = i >> 3, d8 = (i & 7) << 3;
    short8 vv = *(const short8*)(V16 + ((size_t)b * L + j0 + j) * D + h * DH + d8);
    #pragma unroll
    for (int e = 0; e < 8; ++e)
      KVs[j][d8 + e] = bf2f((unsigned short)vv[e]);
  }
  __syncthreads();
  const int d = tid & 63, ug = tid >> 6;
  float acc[8] = {};
  for (int j = 0; j < JT; j += 2) {
    const float v0 = KVs[j][d], v1 = KVs[j + 1][d];
    #pragma unroll
    for (int k = 0; k < 8; ++k) {
      const int uu = ug + k * 5;
      const unsigned int wp = *(const unsigned int*)&ws[uu][j];
      acc[k] = fmaf(bf2f((unsigned short)(wp & 0xffff)), v0, acc[k]);
      acc[k] = fmaf(bf2f((unsigned short)(wp >> 16)), v1, acc[k]);
    }
  }
  #pragma unroll
  for (int k = 0; k < 8; ++k) {
    const int uu = ug + k * 5;
    pv[((size_t)(bh * NJC + jc) * U + uu) * DH + d] = acc[k];
  }
}

// -- attn phase 2: combine 16 chunks per (b,h,u), scatter into ctx16 (bf16) --
__global__ __launch_bounds__(64) void attn_p2_kernel(
    const float* __restrict__ pmax, const float* __restrict__ psum,
    const float* __restrict__ pv, const int* __restrict__ Mtop,
    unsigned short* __restrict__ ctx16) {
  const int bid = blockIdx.x;          // bh*U + u
  const int u = bid % U, bh = bid / U;
  const int d = threadIdx.x;
  float gmax = -INFINITY;
  for (int c = 0; c < NJC; ++c)
    gmax = fmaxf(gmax, pmax[(size_t)(bh * NJC + c) * U + u]);
  float den = 0.f, num = 0.f;
  for (int c = 0; c < NJC; ++c) {
    const float m = pmax[(size_t)(bh * NJC + c) * U + u];
    if (m == -INFINITY) continue;
    const float s = expf(m - gmax);
    den += psum[(size_t)(bh * NJC + c) * U + u] * s;
    num += pv[((size_t)(bh * NJC + c) * U + u) * DH + d] * s;
  }
  const int h = bh % H, b = bh / H;
  const int l = Mtop[bh * U + u];
  ctx16[((size_t)b * L + l) * D + h * DH + d] = f2bf(num / den);
}

// --------- cumsum(V16) over l: pass1 = per-chunk column sums only -----------
// thread owns a column PAIR (uint = 2 bf16) for full 4B/lane coalescing.
__global__ __launch_bounds__(256) void cumsum_pass1(
    const unsigned short* __restrict__ V16, float* __restrict__ csums) {
  const int cp = blockIdx.x * 256 + threadIdx.x;   // column pair 0..511
  const int ch = blockIdx.y, b = blockIdx.z;
  size_t base = ((size_t)b * L + (size_t)ch * CHLEN) * D + cp * 2;
  float a0 = 0.f, a1 = 0.f;
  for (int i = 0; i < CHLEN; ++i) {
    const unsigned int u = *(const unsigned int*)(V16 + base + (size_t)i * D);
    a0 += bf2f((unsigned short)(u & 0xffff));
    a1 += bf2f((unsigned short)(u >> 16));
  }
  float* cs = csums + ((size_t)b * NCHUNK + ch) * D + cp * 2;
  cs[0] = a0; cs[1] = a1;
}

// pass2: recompute running sums from V16 with chunk offset, emit bf16 ctx.
__global__ __launch_bounds__(256) void cumsum_pass2(
    const unsigned short* __restrict__ V16, const float* __restrict__ csums,
    unsigned short* __restrict__ ctx16) {
  const int cp = blockIdx.x * 256 + threadIdx.x;
  const int ch = blockIdx.y, b = blockIdx.z;
  float a0 = 0.f, a1 = 0.f;
  for (int j = 0; j < ch; ++j) {
    const float* cs = csums + ((size_t)b * NCHUNK + j) * D + cp * 2;
    a0 += cs[0]; a1 += cs[1];
  }
  size_t base = ((size_t)b * L + (size_t)ch * CHLEN) * D + cp * 2;
  for (int i = 0; i < CHLEN; ++i) {
    const size_t o = base + (size_t)i * D;
    const unsigned int u = *(const unsigned int*)(V16 + o);
    a0 += bf2f((unsigned short)(u & 0xffff));
    a1 += bf2f((unsigned short)(u >> 16));
    *(unsigned int*)(ctx16 + o) =
        (unsigned int)f2bf(a0) | ((unsigned int)f2bf(a1) << 16);
  }
}

// -- out = LayerNorm(a + r) * g + be; a f32/bf16 per ABF16; r is bf16. -------
template<bool ABF16>
__global__ __launch_bounds__(256) void add_ln_kernel(
    const void* __restrict__ a_, const unsigned short* __restrict__ r,
    const float* __restrict__ g, const float* __restrict__ be,
    float* __restrict__ out, unsigned short* __restrict__ out16) {
  const int row = blockIdx.x;
  const int tid = threadIdx.x;
  __shared__ float buf[D];
  __shared__ float red[256];
  float s = 0.f;
  for (int i = tid; i < D; i += 256) {
    float av;
    if (ABF16) av = bf2f(((const unsigned short*)a_)[(size_t)row * D + i]);
    else       av = ((const float*)a_)[(size_t)row * D + i];
    float v = av + bf2f(r[(size_t)row * D + i]);
    buf[i] = v; s += v;
  }
  red[tid] = s; __syncthreads();
  for (int off = 128; off > 0; off >>= 1) {
    if (tid < off) red[tid] += red[tid+off];
    __syncthreads();
  }
  const float mu = red[0] / (float)D;
  __syncthreads();
  float s2 = 0.f;
  for (int i = tid; i < D; i += 256) { float dv = buf[i] - mu; s2 += dv * dv; }
  red[tid] = s2; __syncthreads();
  for (int off = 128; off > 0; off >>= 1) {
    if (tid < off) red[tid] += red[tid+off];
    __syncthreads();
  }
  const float rstd = rsqrtf(red[0] / (float)D + EPS);
  __syncthreads();
  for (int i = tid; i < D; i += 256) {
    float v = (buf[i] - mu) * rstd * g[i] + be[i];
    if (out)   out[(size_t)row * D + i] = v;
    if (out16) out16[(size_t)row * D + i] = f2bf(v);
  }
}

// ----------------------------------------------------------------------------
extern "C" void kernel_launch(void* const* d_in, const int* in_sizes, int n_in,
                              void* d_out, int out_size, void* d_ws, size_t ws_size,
                              hipStream_t stream) {
  const float* x   = (const float*)d_in[0];
  const float* Wq  = (const float*)d_in[1];
  const float* bq  = (const float*)d_in[2];
  const float* Wk  = (const float*)d_in[3];
  const float* bk  = (const float*)d_in[4];
  const float* Wv  = (const float*)d_in[5];
  const float* bv  = (const float*)d_in[6];
  const float* Wo  = (const float*)d_in[7];
  const float* bo  = (const float*)d_in[8];
  const float* g1  = (const float*)d_in[9];
  const float* be1 = (const float*)d_in[10];
  const float* W1  = (const float*)d_in[11];
  const float* b1  = (const float*)d_in[12];
  const float* W2  = (const float*)d_in[13];
  const float* b2  = (const float*)d_in[14];
  const float* g2  = (const float*)d_in[15];
  const float* be2 = (const float*)d_in[16];
  const int*   idx = (const int*)d_in[17];
  float* out = (float*)d_out;

  char* p = (char*)d_ws;
  // ---- workspace (stream-ordered lifetimes) ----
  // R1 [0,16M): A2 (1-3) -> AO16 [0,8M) (11-12) + ff2_16 [8M,16M) (14-15)
  unsigned short* A2     = (unsigned short*)p;
  unsigned short* AO16   = (unsigned short*)p;
  unsigned short* ff2_16 = (unsigned short*)(p + 8388608);
  // R2 [16M,24M): xb (1-5) -> ctx16 (9-11)
  unsigned short* xb    = (unsigned short*)(p + 16777216);
  unsigned short* ctx16 = (unsigned short*)(p + 16777216);
  // R3 [24M,36M): B2 (2-3, 12.58MB) -> scratch (6-10; first write at step 6)
  unsigned short* B2 = (unsigned short*)(p + 25165824);
  char* scr = p + 25165824;
  float* Mbuf   = (float*)(scr);             // 262,144
  float* csum   = (float*)(scr + 262144);    // 262,144
  int*   Mtop   = (int*)  (scr + 524288);    // 5,120 (pad 8192)
  float* pmax   = (float*)(scr + 532480);    // 81,920
  float* psum   = (float*)(scr + 614400);    // 81,920
  float* pv     = (float*)(scr + 696320);    // 5,242,880 -> ends 5,939,200
  // R4 [36M,68M): QKb (3-8) -> x1b [52M,60M) (12-15)
  float*          QKb = (float*)(p + 37748736);
  unsigned short* x1b = (unsigned short*)(p + 54525952);
  // [60M,92M): ff1b (13-14); overlaps QKb tail (dead after 8) only
  unsigned short* ff1b = (unsigned short*)(p + 62914560);
  // [92M,100M): Vb16 bf16 (5-9)
  unsigned short* Vb16 = (unsigned short*)(p + 96468992);
  // [108M,128M): bf16 weights (4-14)
  unsigned short* Wvt = (unsigned short*)(p + 113246208);
  unsigned short* Wot = (unsigned short*)(p + 115343360);
  unsigned short* W1t = (unsigned short*)(p + 117440512);
  unsigned short* W2t = (unsigned short*)(p + 125829120);

  dim3 blk(256);
  const int M = B * L;   // 4096
  const int SZ = B * L * D;

  // 1) inputs prep: A2 [hi|lo] + bf16 copy
  split_x_f16_kernel<<<(SZ/4 + 255)/256, blk, 0, stream>>>(x, A2, xb);
  // 2) QK weight split (fused Wq+Wk, grid.z)
  wsplit_f16_kernel<<<dim3(D/32, D/32, 2), blk, 0, stream>>>(Wq, Wk, B2);
  // 3) QK via f16 hi/lo 3-term split (fp32-accurate), A-dedup, split bias
  gemm_kernel<128,2,false,false,true,true><<<dim3(LD2/128, M/128), blk, 0, stream>>>(
      A2, B2, bq, bk, QKb, M, LD2, LD3, LDA2);
  // 4) bf16 weight transposes (fused, one launch)
  transpose4_bf16_kernel<<<10240, blk, 0, stream>>>(Wv, Wo, W1, W2, Wvt, Wot, W1t, W2t);
  // 5) V projection -> bf16 (LN renorm makes downstream error relative)
  gemm_kernel<64,3,false,true,false,false><<<dim3(D/64, M/128), blk, 0, stream>>>(
      xb, Wvt, bv, bv, Vb16, M, D, D, D);
  // 6-8) ProbSparse attention scoring
  prob_m_kernel<<<dim3(8, L), blk, 0, stream>>>(QKb, idx, Mbuf);
  topk_kernel<<<B*H, dim3(64), 0, stream>>>(Mbuf, Mtop);
  attn_p1_kernel<<<dim3(NJC, H, B), dim3(320), 0, stream>>>(QKb, Vb16, Mtop, pmax, psum, pv);
  // 9) context = cumsum(V): chunk sums, then streamed bf16 emit
  cumsum_pass1<<<dim3(D/512, NCHUNK, B), blk, 0, stream>>>(Vb16, csum);
  cumsum_pass2<<<dim3(D/512, NCHUNK, B), blk, 0, stream>>>(Vb16, csum, ctx16);
  // 10) attn combine + scatter into ctx16
  attn_p2_kernel<<<B*H*U, dim3(64), 0, stream>>>(pmax, psum, pv, Mtop, ctx16);
  // 11) output projection -> bf16 AO
  gemm_kernel<64,3,false,true,false,false><<<dim3(D/64, M/128), blk, 0, stream>>>(
      ctx16, Wot, bo, bo, AO16, M, D, D, D);
  // 12) LN1 (x f32 + AO bf16) -> bf16 residual
  add_ln_kernel<false><<<B*L, blk, 0, stream>>>(x, AO16, g1, be1, nullptr, x1b);
  // 13) FF1 (bias+relu fused, bf16 out)
  gemm_kernel<128,2,true,true,false,false><<<dim3(FFD/128, M/128), blk, 0, stream>>>(
      x1b, W1t, b1, b1, ff1b, M, FFD, D, D);
  // 14) FF2 -> bf16
  gemm_kernel<64,3,false,true,false,false><<<dim3(D/64, M/128), blk, 0, stream>>>(
      ff1b, W2t, b2, b2, ff2_16, M, D, FFD, FFD);
  // 15) LN2 (x1 bf16 + ff2 bf16) -> f32 out
  add_ln_kernel<true><<<B*L, blk, 0, stream>>>(x1b, ff2_16, g2, be2, out,
                                               (unsigned short*)nullptr);
}

// Round 13
// 344.670 us; speedup vs baseline: 6.2118x; 1.0177x over previous
//
#include <hip/hip_runtime.h>
#include <hip/hip_bf16.h>
#include <hip/hip_fp16.h>
#include <math.h>

constexpr int B = 2, L = 2048, D = 1024, H = 16, DH = 64, FFD = 4096;
constexpr int S = 40;   // sample_k
constexpr int U = 40;   // n_top
constexpr float EPS = 1e-5f;
constexpr int NCHUNK = 32;
constexpr int CHLEN = L / NCHUNK;   // 64
constexpr int LD3 = 3 * D;          // QK split GEMM K' (3072)
constexpr int LD2 = 2 * D;          // QK output row stride
constexpr int LDA2 = 2 * D;         // A2 row stride [hi|lo]
constexpr int JT = 128;             // attn j-chunk
constexpr int NJC = L / JT;         // 16

typedef __attribute__((ext_vector_type(8))) short short8;      // 8 bf16/f16 bits
typedef __attribute__((ext_vector_type(8))) _Float16 half8;
typedef __attribute__((ext_vector_type(4))) float f32x4;

__device__ __forceinline__ unsigned short f2bf(float v) {
  __hip_bfloat16 h = __float2bfloat16(v);
  return __builtin_bit_cast(unsigned short, h);
}
__device__ __forceinline__ float bf2f(unsigned short u) {
  unsigned int x = ((unsigned int)u) << 16;
  return __builtin_bit_cast(float, x);
}
__device__ __forceinline__ unsigned short f2h(float v) {
  __half h = __float2half(v);
  return __builtin_bit_cast(unsigned short, h);
}
__device__ __forceinline__ float h2f(unsigned short u) {
  return __half2float(__builtin_bit_cast(__half, u));
}

__device__ __forceinline__ void gload16(const void* g, void* l) {
  __builtin_amdgcn_global_load_lds(
      (const __attribute__((address_space(1))) void*)g,
      (__attribute__((address_space(3))) void*)l, 16, 0, 0);
}

// ======== pipelined MFMA GEMM: 128xGBN tile, BK=64, DOUBLE-buffered LDS =====
// GBN=128: 64 KB LDS -> 2 blocks/CU.  GBN=64: 48 KB LDS -> 3 blocks/CU.
// Counted vmcnt (8 or 6), raw s_barrier, T2 source-side XOR swizzle, T5
// setprio, XCD-aware bijective block swizzle.
// DUPA (QK 3-term f16 split, round-11 verified): A = [hi|lo], KA = 2048;
// B = [Whi|Wlo|Whi], K = 3072. Tiles 0-15: hi x Whi; 16-31: hi x Wlo
// (akt = kt-16); 32-47: lo x Whi (akt = kt-16 -> A cols 1024..2047).
// ROUND-12 LESSON: the 2-term variant (dropping lo*Whi, ~2e-3 M-error)
// FLIPS top-k selections (absmax 0.88) — selection boundary needs <=1e-5.
// DUPA also selects split bias: col < D -> bias[], else biasB[].
template<int GBN, int MINB, bool RELU, bool OUT_BF16, bool F16, bool DUPA>
__global__ __launch_bounds__(256, MINB) void gemm_kernel(
    const unsigned short* __restrict__ A,    // [M][KA] bits
    const unsigned short* __restrict__ Bt,   // [N][K] bits
    const float* __restrict__ bias,          // [N] (or [D] when DUPA)
    const float* __restrict__ biasB,         // [D] second half when DUPA
    void* __restrict__ C, int M, int N, int K, int KA) {
  constexpr int GBM = 128, GBK = 64;
  constexpr int ABUF = GBM * GBK;        // 8192 shorts
  constexpr int BBUF = GBN * GBK;        // 8192 or 4096 shorts
  constexpr int BUFS = ABUF + BBUF;
  constexpr int NI = GBN / 32;           // B frags per wave (4 or 2)
  constexpr int NLOADS = 4 + GBN / 32;   // vmem ops per thread per tile
  __shared__ short lds[2 * BUFS];

  const int tid  = threadIdx.x;
  const int lane = tid & 63;
  const int wid  = tid >> 6;          // 0..3
  const int wr = wid >> 1;            // 0..1 (64-row band)
  const int wc = wid & 1;             // 0..1 (GBN/2-col band)

  // XCD-aware bijective block swizzle (nwg % 8 == 0 for all our shapes)
  const int nwg  = gridDim.x * gridDim.y;
  const int orig = blockIdx.y * gridDim.x + blockIdx.x;
  const int wg   = (orig & 7) * (nwg >> 3) + (orig >> 3);
  const int bm = (wg / gridDim.x) * GBM;
  const int bn = (wg % gridDim.x) * GBN;

  // staging: wave w covers rows w*8 + (lane>>3) (+32 per issue),
  // physical 16B slot (lane&7) holds logical slot (lane&7)^(row&7)  [T2/G21]
  const int srow  = lane >> 3;                 // 0..7 == row&7
  const int sslot = (lane & 7) ^ srow;         // pre-swizzled source slot
  const unsigned short* aS = A  + (size_t)(bm + wid * 8 + srow) * KA + sslot * 8;
  const unsigned short* bS = Bt + (size_t)(bn + wid * 8 + srow) * K  + sslot * 8;
  short* la0 = lds + wid * 8 * GBK;
  short* lb0 = lds + ABUF + wid * 8 * GBK;

  auto STAGE = [&](int buf, int kt) {          // NLOADS vmem ops / thread
    const int akt = (DUPA && kt >= 16) ? kt - 16 : kt;
    const unsigned short* ap = aS + (size_t)akt * GBK;
    const unsigned short* bp = bS + (size_t)kt  * GBK;
    short* la = la0 + buf * BUFS;
    short* lb = lb0 + buf * BUFS;
    gload16(ap,                   la);
    gload16(ap + (size_t)32 * KA, la + 32 * GBK);
    gload16(ap + (size_t)64 * KA, la + 64 * GBK);
    gload16(ap + (size_t)96 * KA, la + 96 * GBK);
    #pragma unroll
    for (int r = 0; r < GBN / 32; ++r)
      gload16(bp + (size_t)(r * 32) * K, lb + r * 32 * GBK);
  };

  const int fr = lane & 15, g = lane >> 4;
  const int nt = K / GBK;

  STAGE(0, 0);

  f32x4 acc[4][NI] = {};
  int cur = 0;
  for (int t = 0; t < nt; ++t) {
    const int kt = (t + 1 < nt) ? t + 1 : t;          // clamp keeps vmcnt uniform
    STAGE(cur ^ 1, kt);                               // prefetch next tile
    if constexpr (NLOADS == 8)
      asm volatile("s_waitcnt vmcnt(8)" ::: "memory"); // tile t landed; t+1 in flight
    else
      asm volatile("s_waitcnt vmcnt(6)" ::: "memory");
    __builtin_amdgcn_sched_barrier(0);
    __builtin_amdgcn_s_barrier();

    const short* la = lds + cur * BUFS;
    const short* lb = la + ABUF;
    short8 av[2][4], bv[2][NI];
    #pragma unroll
    for (int kk = 0; kk < 2; ++kk) {
      #pragma unroll
      for (int mi = 0; mi < 4; ++mi) {
        const int row = wr * 64 + mi * 16 + fr;
        av[kk][mi] = *(const short8*)&la[row * GBK + ((((kk << 2) | g) ^ (fr & 7)) << 3)];
      }
      #pragma unroll
      for (int ni = 0; ni < NI; ++ni) {
        const int row = wc * (GBN / 2) + ni * 16 + fr;
        bv[kk][ni] = *(const short8*)&lb[row * GBK + ((((kk << 2) | g) ^ (fr & 7)) << 3)];
      }
    }
    __builtin_amdgcn_s_setprio(1);
    #pragma unroll
    for (int kk = 0; kk < 2; ++kk)
      #pragma unroll
      for (int mi = 0; mi < 4; ++mi)
        #pragma unroll
        for (int ni = 0; ni < NI; ++ni) {
          if constexpr (F16)
            acc[mi][ni] = __builtin_amdgcn_mfma_f32_16x16x32_f16(
                __builtin_bit_cast(half8, av[kk][mi]),
                __builtin_bit_cast(half8, bv[kk][ni]), acc[mi][ni], 0, 0, 0);
          else
            acc[mi][ni] = __builtin_amdgcn_mfma_f32_16x16x32_bf16(
                av[kk][mi], bv[kk][ni], acc[mi][ni], 0, 0, 0);
        }
    __builtin_amdgcn_s_setprio(0);
    asm volatile("s_waitcnt lgkmcnt(0)" ::: "memory"); // all reads of cur retired
    __builtin_amdgcn_sched_barrier(0);
    __builtin_amdgcn_s_barrier();                      // safe to restage cur
    cur ^= 1;
  }

  // epilogue: C/D layout col=lane&15, row=(lane>>4)*4+reg  [m89/m91 verified]
  #pragma unroll
  for (int ni = 0; ni < NI; ++ni) {
    const int col = bn + wc * (GBN / 2) + ni * 16 + fr;
    const float bcol = DUPA ? (col < D ? bias[col] : biasB[col - D]) : bias[col];
    #pragma unroll
    for (int mi = 0; mi < 4; ++mi) {
      #pragma unroll
      for (int j = 0; j < 4; ++j) {
        const int rowg = bm + wr * 64 + mi * 16 + (g << 2) + j;
        float v = acc[mi][ni][j] + bcol;
        if (RELU) v = fmaxf(v, 0.f);
        if (OUT_BF16) ((unsigned short*)C)[(size_t)rowg * N + col] = f2bf(v);
        else          ((float*)C)[(size_t)rowg * N + col] = v;
      }
    }
  }
}

// ===== fused prep (one launch, block ranges): =====
//  [0,4096):     x -> A2 (f16 [hi|lo], stride LDA2) + xb (bf16)
//  [4096,6144):  Wq/Wk -> B2rows[n][3D] f16 [hi(k)|lo(k)|hi(k)]
//  [6144,16384): Wv/Wo/W1/W2 transpose+bf16
__global__ __launch_bounds__(256) void prep_kernel(
    const float* __restrict__ x, unsigned short* __restrict__ A2,
    unsigned short* __restrict__ xb,
    const float* __restrict__ Wq, const float* __restrict__ Wk,
    unsigned short* __restrict__ B2r,
    const float* __restrict__ Wv, const float* __restrict__ Wo,
    const float* __restrict__ W1, const float* __restrict__ W2,
    unsigned short* __restrict__ Wvt, unsigned short* __restrict__ Wot,
    unsigned short* __restrict__ W1t, unsigned short* __restrict__ W2t) {
  const int bid = blockIdx.x;
  __shared__ float tile[32][33];
  if (bid < 4096) {
    const int i = (bid * 256 + threadIdx.x) * 4;
    const int m = i / D, k = i % D;
    const float4 v = *(const float4*)(x + i);
    ushort4 hi, lo, bb;
    hi.x = f2h(v.x); lo.x = f2h(v.x - h2f(hi.x)); bb.x = f2bf(v.x);
    hi.y = f2h(v.y); lo.y = f2h(v.y - h2f(hi.y)); bb.y = f2bf(v.y);
    hi.z = f2h(v.z); lo.z = f2h(v.z - h2f(hi.z)); bb.z = f2bf(v.z);
    hi.w = f2h(v.w); lo.w = f2h(v.w - h2f(hi.w)); bb.w = f2bf(v.w);
    unsigned short* row = A2 + (size_t)m * LDA2;
    *(ushort4*)(row + k)     = hi;
    *(ushort4*)(row + D + k) = lo;
    *(ushort4*)(xb + i) = bb;
    return;
  }
  const int tx = threadIdx.x & 31, ty = threadIdx.x >> 5;
  if (bid < 6144) {
    const int t = bid - 4096;
    const int z = t >> 10;                 // 0: Wq, 1: Wk
    const float* W = z ? Wk : Wq;
    unsigned short* outb = B2r + (size_t)z * D * LD3;
    const int bx = ((t & 1023) & 31) * 32;       // n
    const int by = ((t & 1023) >> 5) * 32;       // k
    #pragma unroll
    for (int i = ty; i < 32; i += 8)
      tile[i][tx] = W[(size_t)(by + i) * D + bx + tx];
    __syncthreads();
    #pragma unroll
    for (int i = ty; i < 32; i += 8) {
      const float v = tile[tx][i];    // W[by+tx][bx+i]
      const unsigned short hi = f2h(v);
      const unsigned short lo = f2h(v - h2f(hi));
      unsigned short* r = outb + (size_t)(bx + i) * LD3 + (by + tx);
      r[0]     = hi;
      r[D]     = lo;
      r[2 * D] = hi;
    }
    return;
  }
  const int tb = bid - 6144;
  const float* W; unsigned short* Wt; int K, N, t;
  if (tb < 1024)      { W = Wv; Wt = Wvt; K = D;   N = D;   t = tb; }
  else if (tb < 2048) { W = Wo; Wt = Wot; K = D;   N = D;   t = tb - 1024; }
  else if (tb < 6144) { W = W1; Wt = W1t; K = D;   N = FFD; t = tb - 2048; }
  else                { W = W2; Wt = W2t; K = FFD; N = D;   t = tb - 6144; }
  const int nx = N / 32;
  const int bx = (t % nx) * 32;   // N offset
  const int by = (t / nx) * 32;   // K offset
  #pragma unroll
  for (int i = ty; i < 32; i += 8)
    tile[i][tx] = W[(size_t)(by + i) * N + bx + tx];
  __syncthreads();
  #pragma unroll
  for (int i = ty; i < 32; i += 8)
    Wt[(size_t)(bx + i) * K + by + tx] = f2bf(tile[tx][i]);
}

// ------------- M[b,h,l] = max_s(Q[l]·K[idx[l,s]]) - sum_s(...)/L ------------
// Head-sliced + XCD-pinned: grid (8, L); per-combo K working set 2 MB -> L2.
__global__ __launch_bounds__(256) void prob_m_kernel(
    const float* __restrict__ QK, const int* __restrict__ idx,
    float* __restrict__ M_) {
  const int combo = blockIdx.x;        // 0..7
  const int b = combo >> 2, hg = combo & 3;
  const int l = blockIdx.y;
  const int tid = threadIdx.x;
  const int wave = tid >> 6;           // 0..3
  const int lane = tid & 63;
  const int h = hg * 4 + wave;
  __shared__ int sidx[S];
  if (tid < S) sidx[tid] = idx[l * S + tid];
  __syncthreads();
  const int dsub = (lane & 15) * 4;
  const int sgrp = lane >> 4;          // 0..3
  const float4 q = *(const float4*)(QK + ((size_t)b * L + l) * LD2 + h * DH + dsub);
  float mx = -INFINITY, sm = 0.f;
  for (int s = sgrp; s < S; s += 4) {
    const float4 kv = *(const float4*)(QK + ((size_t)b * L + sidx[s]) * LD2 + D + h * DH + dsub);
    float p = q.x*kv.x + q.y*kv.y + q.z*kv.z + q.w*kv.w;
    p += __shfl_xor(p, 1);
    p += __shfl_xor(p, 2);
    p += __shfl_xor(p, 4);
    p += __shfl_xor(p, 8);
    mx = fmaxf(mx, p);
    sm += p;
  }
  mx = fmaxf(mx, __shfl_xor(mx, 16));
  mx = fmaxf(mx, __shfl_xor(mx, 32));
  sm += __shfl_xor(sm, 16);
  sm += __shfl_xor(sm, 32);
  if (lane == 0)
    M_[((size_t)b * H + h) * L + l] = mx - sm / (float)L;
}

// ---- exact top-k (k=40, n=2048): single wave, register-resident, no LDS ----
__global__ __launch_bounds__(64) void topk_kernel(
    const float* __restrict__ M_, int* __restrict__ Mtop) {
  const int bh = blockIdx.x;
  const float* row = M_ + (size_t)bh * L;
  const int lane = threadIdx.x;   // 0..63
  float v[32];
  #pragma unroll
  for (int k = 0; k < 32; ++k) v[k] = row[k * 64 + lane];
  for (int u = 0; u < U; ++u) {
    float best = v[0]; int bk = 0;
    #pragma unroll
    for (int k = 1; k < 32; ++k)
      if (v[k] > best) { best = v[k]; bk = k; }        // strict >: lower k wins
    int bidx = bk * 64 + lane;
    #pragma unroll
    for (int off = 1; off < 64; off <<= 1) {
      const float ov = __shfl_xor(best, off);
      const int   oi = __shfl_xor(bidx, off);
      if (ov > best || (ov == best && oi < bidx)) { best = ov; bidx = oi; }
    }
    if (lane == 0) Mtop[bh * U + u] = bidx;            // all lanes agree
    if ((bidx & 63) == lane) {                          // kill winner (static idx)
      const int kk = bidx >> 6;
      #pragma unroll
      for (int k = 0; k < 32; ++k) if (k == kk) v[k] = -INFINITY;
    }
  }
}

// ------- attn phase 1: per (b,h,jc) partial softmax + PV over 128 keys ------
// V is bf16 (V16).
__global__ __launch_bounds__(320) void attn_p1_kernel(
    const float* __restrict__ QK, const unsigned short* __restrict__ V16,
    const int* __restrict__ Mtop,
    float* __restrict__ pmax, float* __restrict__ psum, float* __restrict__ pv) {
  const int jc = blockIdx.x, h = blockIdx.y, b = blockIdx.z;
  const int bh = b * H + h;
  const int tid = threadIdx.x;
  const int j0 = jc * JT;
  __shared__ float Qs[U][68];
  __shared__ float KVs[JT][68];
  __shared__ unsigned short ws[U][JT];

  for (int i = tid; i < U * 16; i += 320) {
    const int u = i >> 4, dq = (i & 15) << 2;
    const int row = Mtop[bh * U + u];
    *(float4*)&Qs[u][dq] =
        *(const float4*)(QK + ((size_t)b * L + row) * LD2 + h * DH + dq);
  }
  for (int i = tid; i < JT * 16; i += 320) {
    const int j = i >> 4, dq = (i & 15) << 2;
    *(float4*)&KVs[j][dq] =
        *(const float4*)(QK + ((size_t)b * L + j0 + j) * LD2 + D + h * DH + dq);
  }
  __syncthreads();

  const int u = tid >> 3, jg = tid & 7;
  const int mt = Mtop[bh * U + u];
  float sc[16];
  #pragma unroll
  for (int jt = 0; jt < 16; ++jt) sc[jt] = 0.f;
  for (int dq = 0; dq < 64; dq += 4) {
    const float4 q = *(const float4*)&Qs[u][dq];
    #pragma unroll
    for (int jt = 0; jt < 16; ++jt) {
      const float4 k = *(const float4*)&KVs[jt * 8 + jg][dq];
      sc[jt] += q.x*k.x + q.y*k.y + q.z*k.z + q.w*k.w;
    }
  }
  float m = -INFINITY;
  #pragma unroll
  for (int jt = 0; jt < 16; ++jt) {
    const int j = j0 + jt * 8 + jg;
    sc[jt] = (j <= mt) ? sc[jt] * 0.125f : -INFINITY;
    m = fmaxf(m, sc[jt]);
  }
  m = fmaxf(m, __shfl_xor(m, 1));
  m = fmaxf(m, __shfl_xor(m, 2));
  m = fmaxf(m, __shfl_xor(m, 4));
  float sum = 0.f;
  #pragma unroll
  for (int jt = 0; jt < 16; ++jt) {
    const float e = (sc[jt] == -INFINITY) ? 0.f : expf(sc[jt] - m);
    sum += e;
    ws[u][jt * 8 + jg] = f2bf(e);
  }
  sum += __shfl_xor(sum, 1);
  sum += __shfl_xor(sum, 2);
  sum += __shfl_xor(sum, 4);
  if (jg == 0) {
    pmax[(size_t)(bh * NJC + jc) * U + u] = m;
    psum[(size_t)(bh * NJC + jc) * U + u] = sum;
  }
  __syncthreads();
  // reload LDS with V chunk (bf16 -> f32)
  for (int i = tid; i < JT * 8; i += 320) {
    const int j = i >> 3, d8 = (i & 7) << 3;
    short8 vv = *(const short8*)(V16 + ((size_t)b * L + j0 + j) * D + h * DH + d8);
    #pragma unroll
    for (int e = 0; e < 8; ++e)
      KVs[j][d8 + e] = bf2f((unsigned short)vv[e]);
  }
  __syncthreads();
  const int d = tid & 63, ug = tid >> 6;
  float acc[8] = {};
  for (int j = 0; j < JT; j += 2) {
    const float v0 = KVs[j][d], v1 = KVs[j + 1][d];
    #pragma unroll
    for (int k = 0; k < 8; ++k) {
      const int uu = ug + k * 5;
      const unsigned int wp = *(const unsigned int*)&ws[uu][j];
      acc[k] = fmaf(bf2f((unsigned short)(wp & 0xffff)), v0, acc[k]);
      acc[k] = fmaf(bf2f((unsigned short)(wp >> 16)), v1, acc[k]);
    }
  }
  #pragma unroll
  for (int k = 0; k < 8; ++k) {
    const int uu = ug + k * 5;
    pv[((size_t)(bh * NJC + jc) * U + uu) * DH + d] = acc[k];
  }
}

// -- attn phase 2: combine 16 chunks per (b,h,u), scatter into ctx16 (bf16) --
__global__ __launch_bounds__(64) void attn_p2_kernel(
    const float* __restrict__ pmax, const float* __restrict__ psum,
    const float* __restrict__ pv, const int* __restrict__ Mtop,
    unsigned short* __restrict__ ctx16) {
  const int bid = blockIdx.x;          // bh*U + u
  const int u = bid % U, bh = bid / U;
  const int d = threadIdx.x;
  float gmax = -INFINITY;
  for (int c = 0; c < NJC; ++c)
    gmax = fmaxf(gmax, pmax[(size_t)(bh * NJC + c) * U + u]);
  float den = 0.f, num = 0.f;
  for (int c = 0; c < NJC; ++c) {
    const float m = pmax[(size_t)(bh * NJC + c) * U + u];
    if (m == -INFINITY) continue;
    const float s = expf(m - gmax);
    den += psum[(size_t)(bh * NJC + c) * U + u] * s;
    num += pv[((size_t)(bh * NJC + c) * U + u) * DH + d] * s;
  }
  const int h = bh % H, b = bh / H;
  const int l = Mtop[bh * U + u];
  ctx16[((size_t)b * L + l) * D + h * DH + d] = f2bf(num / den);
}

// --------- cumsum(V16) over l: pass1 = per-chunk column sums only -----------
__global__ __launch_bounds__(256) void cumsum_pass1(
    const unsigned short* __restrict__ V16, float* __restrict__ csums) {
  const int cp = blockIdx.x * 256 + threadIdx.x;   // column pair 0..511
  const int ch = blockIdx.y, b = blockIdx.z;
  size_t base = ((size_t)b * L + (size_t)ch * CHLEN) * D + cp * 2;
  float a0 = 0.f, a1 = 0.f;
  for (int i = 0; i < CHLEN; ++i) {
    const unsigned int u = *(const unsigned int*)(V16 + base + (size_t)i * D);
    a0 += bf2f((unsigned short)(u & 0xffff));
    a1 += bf2f((unsigned short)(u >> 16));
  }
  float* cs = csums + ((size_t)b * NCHUNK + ch) * D + cp * 2;
  cs[0] = a0; cs[1] = a1;
}

// pass2: recompute running sums from V16 with chunk offset, emit bf16 ctx.
__global__ __launch_bounds__(256) void cumsum_pass2(
    const unsigned short* __restrict__ V16, const float* __restrict__ csums,
    unsigned short* __restrict__ ctx16) {
  const int cp = blockIdx.x * 256 + threadIdx.x;
  const int ch = blockIdx.y, b = blockIdx.z;
  float a0 = 0.f, a1 = 0.f;
  for (int j = 0; j < ch; ++j) {
    const float* cs = csums + ((size_t)b * NCHUNK + j) * D + cp * 2;
    a0 += cs[0]; a1 += cs[1];
  }
  size_t base = ((size_t)b * L + (size_t)ch * CHLEN) * D + cp * 2;
  for (int i = 0; i < CHLEN; ++i) {
    const size_t o = base + (size_t)i * D;
    const unsigned int u = *(const unsigned int*)(V16 + o);
    a0 += bf2f((unsigned short)(u & 0xffff));
    a1 += bf2f((unsigned short)(u >> 16));
    *(unsigned int*)(ctx16 + o) =
        (unsigned int)f2bf(a0) | ((unsigned int)f2bf(a1) << 16);
  }
}

// -- out = LayerNorm(a + r) * g + be; a f32/bf16 per ABF16; r is bf16. -------
template<bool ABF16>
__global__ __launch_bounds__(256) void add_ln_kernel(
    const void* __restrict__ a_, const unsigned short* __restrict__ r,
    const float* __restrict__ g, const float* __restrict__ be,
    float* __restrict__ out, unsigned short* __restrict__ out16) {
  const int row = blockIdx.x;
  const int tid = threadIdx.x;
  __shared__ float buf[D];
  __shared__ float red[256];
  float s = 0.f;
  for (int i = tid; i < D; i += 256) {
    float av;
    if (ABF16) av = bf2f(((const unsigned short*)a_)[(size_t)row * D + i]);
    else       av = ((const float*)a_)[(size_t)row * D + i];
    float v = av + bf2f(r[(size_t)row * D + i]);
    buf[i] = v; s += v;
  }
  red[tid] = s; __syncthreads();
  for (int off = 128; off > 0; off >>= 1) {
    if (tid < off) red[tid] += red[tid+off];
    __syncthreads();
  }
  const float mu = red[0] / (float)D;
  __syncthreads();
  float s2 = 0.f;
  for (int i = tid; i < D; i += 256) { float dv = buf[i] - mu; s2 += dv * dv; }
  red[tid] = s2; __syncthreads();
  for (int off = 128; off > 0; off >>= 1) {
    if (tid < off) red[tid] += red[tid+off];
    __syncthreads();
  }
  const float rstd = rsqrtf(red[0] / (float)D + EPS);
  __syncthreads();
  for (int i = tid; i < D; i += 256) {
    float v = (buf[i] - mu) * rstd * g[i] + be[i];
    if (out)   out[(size_t)row * D + i] = v;
    if (out16) out16[(size_t)row * D + i] = f2bf(v);
  }
}

// ----------------------------------------------------------------------------
extern "C" void kernel_launch(void* const* d_in, const int* in_sizes, int n_in,
                              void* d_out, int out_size, void* d_ws, size_t ws_size,
                              hipStream_t stream) {
  const float* x   = (const float*)d_in[0];
  const float* Wq  = (const float*)d_in[1];
  const float* bq  = (const float*)d_in[2];
  const float* Wk  = (const float*)d_in[3];
  const float* bk  = (const float*)d_in[4];
  const float* Wv  = (const float*)d_in[5];
  const float* bv  = (const float*)d_in[6];
  const float* Wo  = (const float*)d_in[7];
  const float* bo  = (const float*)d_in[8];
  const float* g1  = (const float*)d_in[9];
  const float* be1 = (const float*)d_in[10];
  const float* W1  = (const float*)d_in[11];
  const float* b1  = (const float*)d_in[12];
  const float* W2  = (const float*)d_in[13];
  const float* b2  = (const float*)d_in[14];
  const float* g2  = (const float*)d_in[15];
  const float* be2 = (const float*)d_in[16];
  const int*   idx = (const int*)d_in[17];
  float* out = (float*)d_out;

  char* p = (char*)d_ws;
  // ---- workspace (stream-ordered lifetimes) ----
  // R1 [0,16M): A2 [hi|lo] 16MB (1-3) -> AO16 [0,8M) (11-12) + ff2_16 [8M,16M) (14-15)
  unsigned short* A2     = (unsigned short*)p;
  unsigned short* AO16   = (unsigned short*)p;
  unsigned short* ff2_16 = (unsigned short*)(p + 8388608);
  // R2 [16M,24M): xb (1-5) -> ctx16 (9-11)
  unsigned short* xb    = (unsigned short*)(p + 16777216);
  unsigned short* ctx16 = (unsigned short*)(p + 16777216);
  // R3 [24M,36M): B2 (1-3, 12.58MB) -> scratch (6-10; first write at step 6)
  unsigned short* B2 = (unsigned short*)(p + 25165824);
  char* scr = p + 25165824;
  float* Mbuf   = (float*)(scr);             // 262,144
  float* csum   = (float*)(scr + 262144);    // 262,144
  int*   Mtop   = (int*)  (scr + 524288);    // 5,120 (pad 8192)
  float* pmax   = (float*)(scr + 532480);    // 81,920
  float* psum   = (float*)(scr + 614400);    // 81,920
  float* pv     = (float*)(scr + 696320);    // 5,242,880 -> ends 5,939,200
  // R4 [36M,68M): QKb (3-8) -> x1b [52M,60M) (12-15)
  float*          QKb = (float*)(p + 37748736);
  unsigned short* x1b = (unsigned short*)(p + 54525952);
  // [60M,92M): ff1b (13-14); overlaps QKb tail (dead after 8) only
  unsigned short* ff1b = (unsigned short*)(p + 62914560);
  // [92M,100M): Vb16 bf16 (5-9)
  unsigned short* Vb16 = (unsigned short*)(p + 96468992);
  // [108M,128M): bf16 weights (1-14)
  unsigned short* Wvt = (unsigned short*)(p + 113246208);
  unsigned short* Wot = (unsigned short*)(p + 115343360);
  unsigned short* W1t = (unsigned short*)(p + 117440512);
  unsigned short* W2t = (unsigned short*)(p + 125829120);

  dim3 blk(256);
  const int M = B * L;   // 4096

  // 1) fused prep: A2 ([hi|lo]) + xb (bf16) + B2 ([Whi|Wlo|Whi]) + transposes
  prep_kernel<<<16384, blk, 0, stream>>>(x, A2, xb, Wq, Wk, B2,
                                         Wv, Wo, W1, W2, Wvt, Wot, W1t, W2t);
  // 3) QK via f16 3-term split (fp32-accurate, selection-safe), A-dedup
  gemm_kernel<128,2,false,false,true,true><<<dim3(LD2/128, M/128), blk, 0, stream>>>(
      A2, B2, bq, bk, QKb, M, LD2, LD3, LDA2);
  // 5) V projection -> bf16
  gemm_kernel<64,3,false,true,false,false><<<dim3(D/64, M/128), blk, 0, stream>>>(
      xb, Wvt, bv, bv, Vb16, M, D, D, D);
  // 6-8) ProbSparse attention scoring
  prob_m_kernel<<<dim3(8, L), blk, 0, stream>>>(QKb, idx, Mbuf);
  topk_kernel<<<B*H, dim3(64), 0, stream>>>(Mbuf, Mtop);
  attn_p1_kernel<<<dim3(NJC, H, B), dim3(320), 0, stream>>>(QKb, Vb16, Mtop, pmax, psum, pv);
  // 9) context = cumsum(V): chunk sums, then streamed bf16 emit
  cumsum_pass1<<<dim3(D/512, NCHUNK, B), blk, 0, stream>>>(Vb16, csum);
  cumsum_pass2<<<dim3(D/512, NCHUNK, B), blk, 0, stream>>>(Vb16, csum, ctx16);
  // 10) attn combine + scatter into ctx16
  attn_p2_kernel<<<B*H*U, dim3(64), 0, stream>>>(pmax, psum, pv, Mtop, ctx16);
  // 11) output projection -> bf16 AO
  gemm_kernel<64,3,false,true,false,false><<<dim3(D/64, M/128), blk, 0, stream>>>(
      ctx16, Wot, bo, bo, AO16, M, D, D, D);
  // 12) LN1 (x f32 + AO bf16) -> bf16 residual
  add_ln_kernel<false><<<B*L, blk, 0, stream>>>(x, AO16, g1, be1, nullptr, x1b);
  // 13) FF1 (bias+relu fused, bf16 out)
  gemm_kernel<128,2,true,true,false,false><<<dim3(FFD/128, M/128), blk, 0, stream>>>(
      x1b, W1t, b1, b1, ff1b, M, FFD, D, D);
  // 14) FF2 -> bf16
  gemm_kernel<64,3,false,true,false,false><<<dim3(D/64, M/128), blk, 0, stream>>>(
      ff1b, W2t, b2, b2, ff2_16, M, D, FFD, FFD);
  // 15) LN2 (x1 bf16 + ff2 bf16) -> f32 out
  add_ln_kernel<true><<<B*L, blk, 0, stream>>>(x1b, ff2_16, g2, be2, out,
                                               (unsigned short*)nullptr);
}

// Round 14
// 334.851 us; speedup vs baseline: 6.3940x; 1.0293x over previous
//
#include <hip/hip_runtime.h>
#include <hip/hip_bf16.h>
#include <hip/hip_fp16.h>
#include <math.h>

constexpr int B = 2, L = 2048, D = 1024, H = 16, DH = 64, FFD = 4096;
constexpr int S = 40;   // sample_k
constexpr int U = 40;   // n_top
constexpr float EPS = 1e-5f;
constexpr int NCHUNK = 32;
constexpr int CHLEN = L / NCHUNK;   // 64
constexpr int LD3 = 3 * D;          // QK split GEMM K' (3072)
constexpr int LD2 = 2 * D;          // QK output row stride
constexpr int LDA2 = 2 * D;         // A2 row stride [hi|lo]
constexpr int JT = 128;             // attn j-chunk
constexpr int NJC = L / JT;         // 16

typedef __attribute__((ext_vector_type(8))) short short8;      // 8 bf16/f16 bits
typedef __attribute__((ext_vector_type(8))) _Float16 half8;
typedef __attribute__((ext_vector_type(4))) float f32x4;

__device__ __forceinline__ unsigned short f2bf(float v) {
  __hip_bfloat16 h = __float2bfloat16(v);
  return __builtin_bit_cast(unsigned short, h);
}
__device__ __forceinline__ float bf2f(unsigned short u) {
  unsigned int x = ((unsigned int)u) << 16;
  return __builtin_bit_cast(float, x);
}
__device__ __forceinline__ unsigned short f2h(float v) {
  __half h = __float2half(v);
  return __builtin_bit_cast(unsigned short, h);
}
__device__ __forceinline__ float h2f(unsigned short u) {
  return __half2float(__builtin_bit_cast(__half, u));
}

__device__ __forceinline__ void gload16(const void* g, void* l) {
  __builtin_amdgcn_global_load_lds(
      (const __attribute__((address_space(1))) void*)g,
      (__attribute__((address_space(3))) void*)l, 16, 0, 0);
}

// ======== pipelined MFMA GEMM: 128xGBN tile, BK=64, DOUBLE-buffered LDS =====
// (2-barrier structure; used for QK / V / Wo / FF2.)
// GBN=128: 64 KB LDS -> 2 blocks/CU.  GBN=64: 48 KB LDS -> 3 blocks/CU.
// DUPA (QK 3-term f16 split, verified): A=[hi|lo] KA=2048; B=[Whi|Wlo|Whi]
// K=3072; tiles >=16 re-read A cols via akt=kt-16. ROUND-12 LESSON: 2-term
// (~2e-3 M-error) FLIPS top-k — selection boundary needs <=1e-5.
template<int GBN, int MINB, bool RELU, bool OUT_BF16, bool F16, bool DUPA>
__global__ __launch_bounds__(256, MINB) void gemm_kernel(
    const unsigned short* __restrict__ A,    // [M][KA] bits
    const unsigned short* __restrict__ Bt,   // [N][K] bits
    const float* __restrict__ bias,          // [N] (or [D] when DUPA)
    const float* __restrict__ biasB,         // [D] second half when DUPA
    void* __restrict__ C, int M, int N, int K, int KA) {
  constexpr int GBM = 128, GBK = 64;
  constexpr int ABUF = GBM * GBK;
  constexpr int BBUF = GBN * GBK;
  constexpr int BUFS = ABUF + BBUF;
  constexpr int NI = GBN / 32;
  constexpr int NLOADS = 4 + GBN / 32;
  __shared__ short lds[2 * BUFS];

  const int tid  = threadIdx.x;
  const int lane = tid & 63;
  const int wid  = tid >> 6;
  const int wr = wid >> 1;
  const int wc = wid & 1;

  const int nwg  = gridDim.x * gridDim.y;
  const int orig = blockIdx.y * gridDim.x + blockIdx.x;
  const int wg   = (orig & 7) * (nwg >> 3) + (orig >> 3);
  const int bm = (wg / gridDim.x) * GBM;
  const int bn = (wg % gridDim.x) * GBN;

  const int srow  = lane >> 3;
  const int sslot = (lane & 7) ^ srow;
  const unsigned short* aS = A  + (size_t)(bm + wid * 8 + srow) * KA + sslot * 8;
  const unsigned short* bS = Bt + (size_t)(bn + wid * 8 + srow) * K  + sslot * 8;
  short* la0 = lds + wid * 8 * GBK;
  short* lb0 = lds + ABUF + wid * 8 * GBK;

  auto STAGE = [&](int buf, int kt) {
    const int akt = (DUPA && kt >= 16) ? kt - 16 : kt;
    const unsigned short* ap = aS + (size_t)akt * GBK;
    const unsigned short* bp = bS + (size_t)kt  * GBK;
    short* la = la0 + buf * BUFS;
    short* lb = lb0 + buf * BUFS;
    gload16(ap,                   la);
    gload16(ap + (size_t)32 * KA, la + 32 * GBK);
    gload16(ap + (size_t)64 * KA, la + 64 * GBK);
    gload16(ap + (size_t)96 * KA, la + 96 * GBK);
    #pragma unroll
    for (int r = 0; r < GBN / 32; ++r)
      gload16(bp + (size_t)(r * 32) * K, lb + r * 32 * GBK);
  };

  const int fr = lane & 15, g = lane >> 4;
  const int nt = K / GBK;

  STAGE(0, 0);

  f32x4 acc[4][NI] = {};
  int cur = 0;
  for (int t = 0; t < nt; ++t) {
    const int kt = (t + 1 < nt) ? t + 1 : t;
    STAGE(cur ^ 1, kt);
    if constexpr (NLOADS == 8)
      asm volatile("s_waitcnt vmcnt(8)" ::: "memory");
    else
      asm volatile("s_waitcnt vmcnt(6)" ::: "memory");
    __builtin_amdgcn_sched_barrier(0);
    __builtin_amdgcn_s_barrier();

    const short* la = lds + cur * BUFS;
    const short* lb = la + ABUF;
    short8 av[2][4], bv[2][NI];
    #pragma unroll
    for (int kk = 0; kk < 2; ++kk) {
      #pragma unroll
      for (int mi = 0; mi < 4; ++mi) {
        const int row = wr * 64 + mi * 16 + fr;
        av[kk][mi] = *(const short8*)&la[row * GBK + ((((kk << 2) | g) ^ (fr & 7)) << 3)];
      }
      #pragma unroll
      for (int ni = 0; ni < NI; ++ni) {
        const int row = wc * (GBN / 2) + ni * 16 + fr;
        bv[kk][ni] = *(const short8*)&lb[row * GBK + ((((kk << 2) | g) ^ (fr & 7)) << 3)];
      }
    }
    __builtin_amdgcn_s_setprio(1);
    #pragma unroll
    for (int kk = 0; kk < 2; ++kk)
      #pragma unroll
      for (int mi = 0; mi < 4; ++mi)
        #pragma unroll
        for (int ni = 0; ni < NI; ++ni) {
          if constexpr (F16)
            acc[mi][ni] = __builtin_amdgcn_mfma_f32_16x16x32_f16(
                __builtin_bit_cast(half8, av[kk][mi]),
                __builtin_bit_cast(half8, bv[kk][ni]), acc[mi][ni], 0, 0, 0);
          else
            acc[mi][ni] = __builtin_amdgcn_mfma_f32_16x16x32_bf16(
                av[kk][mi], bv[kk][ni], acc[mi][ni], 0, 0, 0);
        }
    __builtin_amdgcn_s_setprio(0);
    asm volatile("s_waitcnt lgkmcnt(0)" ::: "memory");
    __builtin_amdgcn_sched_barrier(0);
    __builtin_amdgcn_s_barrier();
    cur ^= 1;
  }

  #pragma unroll
  for (int ni = 0; ni < NI; ++ni) {
    const int col = bn + wc * (GBN / 2) + ni * 16 + fr;
    const float bcol = DUPA ? (col < D ? bias[col] : biasB[col - D]) : bias[col];
    #pragma unroll
    for (int mi = 0; mi < 4; ++mi) {
      #pragma unroll
      for (int j = 0; j < 4; ++j) {
        const int rowg = bm + wr * 64 + mi * 16 + (g << 2) + j;
        float v = acc[mi][ni][j] + bcol;
        if (RELU) v = fmaxf(v, 0.f);
        if (OUT_BF16) ((unsigned short*)C)[(size_t)rowg * N + col] = f2bf(v);
        else          ((float*)C)[(size_t)rowg * N + col] = v;
      }
    }
  }
}

// ======== 8-phase 256x256 MFMA GEMM (FF1: M=4096,N=4096,K=1024) =============
// T3+T4 template: 512 thr / 8 waves (2M x 4N), wave C = 128x64 (acc[8][4]),
// BK=64, 2 x 64KB LDS dbuf, counted vmcnt(2) (issue-before-wait, never drain),
// 4 phases/K-tile: {2 gload || quadrant ds_reads -> lgkmcnt(0) -> 16 MFMA},
// register-reuse phase order (av0+bv0 / bv1 / av1 / -), barriers only at tile
// boundaries. bf16 in, bias+ReLU, bf16 out.
__global__ __launch_bounds__(512, 1) void gemm_ff1_8ph_kernel(
    const unsigned short* __restrict__ A,    // [M][K] bf16 bits
    const unsigned short* __restrict__ Bt,   // [N][K] bf16 bits
    const float* __restrict__ bias,          // [N]
    unsigned short* __restrict__ C, int M, int N, int K) {
  constexpr int BK = 64;
  __shared__ short lds8[2 * 32768];   // 2 buf x (A 256x64 + B 256x64) = 128 KB

  const int tid  = threadIdx.x;
  const int lane = tid & 63;
  const int wid  = tid >> 6;          // 0..7
  const int wrm  = wid >> 2;          // 0..1 (128-row band)
  const int wcn  = wid & 3;           // 0..3 (64-col band)

  const int nwg  = gridDim.x * gridDim.y;      // 256
  const int orig = blockIdx.y * gridDim.x + blockIdx.x;
  const int wg   = (orig & 7) * (nwg >> 3) + (orig >> 3);
  const int bm = (wg / gridDim.x) * 256;
  const int bn = (wg % gridDim.x) * 256;

  // staging: wave w covers rows w*8 + (lane>>3) (+r0 per issue), slot
  // pre-swizzle sslot = (lane&7) ^ (row&7)   [proven conflict-free scheme]
  const int srow  = lane >> 3;
  const int sslot = (lane & 7) ^ srow;
  const unsigned short* aS = A  + (size_t)(bm + wid * 8 + srow) * K + sslot * 8;
  const unsigned short* bS = Bt + (size_t)(bn + wid * 8 + srow) * K + sslot * 8;
  short* ldsA0 = lds8 + wid * 8 * BK;            // + buf*32768
  short* ldsB0 = lds8 + 16384 + wid * 8 * BK;

  auto STAGE2 = [&](int buf, int kt, int part) {  // 2 gload16 / thread
    if (part < 2) {
      const unsigned short* ap = aS + (size_t)kt * BK;
      short* la = ldsA0 + buf * 32768;
      const int r0 = part * 128;
      gload16(ap + (size_t)r0 * K,        la + r0 * BK);
      gload16(ap + (size_t)(r0 + 64) * K, la + (r0 + 64) * BK);
    } else {
      const unsigned short* bp = bS + (size_t)kt * BK;
      short* lb = ldsB0 + buf * 32768;
      const int r0 = (part - 2) * 128;
      gload16(bp + (size_t)r0 * K,        lb + r0 * BK);
      gload16(bp + (size_t)(r0 + 64) * K, lb + (r0 + 64) * BK);
    }
  };

  const int fr = lane & 15, g = lane >> 4;
  const int nt = K / BK;   // 16

  // prologue: fully stage tile 0
  #pragma unroll
  for (int p = 0; p < 4; ++p) STAGE2(0, 0, p);

  f32x4 acc[8][4] = {};
  short8 av[2][4], bv0[2][2], bv1[2][2];
  int bc = 0;
  for (int t = 0; t < nt; ++t) {
    const int kt = (t + 1 < nt) ? t + 1 : t;     // clamp keeps vmcnt uniform
    const short* la = lds8 + bc * 32768;
    const short* lb = la + 16384;

    STAGE2(bc ^ 1, kt, 0);
    asm volatile("s_waitcnt vmcnt(2)" ::: "memory");  // tile t resident; 2 of t+1 in flight
    __builtin_amdgcn_sched_barrier(0);
    __builtin_amdgcn_s_barrier();

    // ---- P0: read av(mh=0) + bv0(nh=0); MFMA quadrant (0,0) ----
    #pragma unroll
    for (int kk = 0; kk < 2; ++kk) {
      #pragma unroll
      for (int mi = 0; mi < 4; ++mi) {
        const int row = wrm * 128 + mi * 16 + fr;
        av[kk][mi] = *(const short8*)&la[row * BK + ((((kk << 2) | g) ^ (fr & 7)) << 3)];
      }
      #pragma unroll
      for (int ni = 0; ni < 2; ++ni) {
        const int row = wcn * 64 + ni * 16 + fr;
        bv0[kk][ni] = *(const short8*)&lb[row * BK + ((((kk << 2) | g) ^ (fr & 7)) << 3)];
      }
    }
    asm volatile("s_waitcnt lgkmcnt(0)" ::: "memory");
    __builtin_amdgcn_sched_barrier(0);
    __builtin_amdgcn_s_setprio(1);
    #pragma unroll
    for (int kk = 0; kk < 2; ++kk)
      #pragma unroll
      for (int mi = 0; mi < 4; ++mi)
        #pragma unroll
        for (int ni = 0; ni < 2; ++ni)
          acc[mi][ni] = __builtin_amdgcn_mfma_f32_16x16x32_bf16(
              av[kk][mi], bv0[kk][ni], acc[mi][ni], 0, 0, 0);
    __builtin_amdgcn_s_setprio(0);

    STAGE2(bc ^ 1, kt, 1);
    // ---- P1: read bv1(nh=1); MFMA (0,1) ----
    #pragma unroll
    for (int kk = 0; kk < 2; ++kk)
      #pragma unroll
      for (int ni = 0; ni < 2; ++ni) {
        const int row = wcn * 64 + 32 + ni * 16 + fr;
        bv1[kk][ni] = *(const short8*)&lb[row * BK + ((((kk << 2) | g) ^ (fr & 7)) << 3)];
      }
    asm volatile("s_waitcnt lgkmcnt(0)" ::: "memory");
    __builtin_amdgcn_sched_barrier(0);
    __builtin_amdgcn_s_setprio(1);
    #pragma unroll
    for (int kk = 0; kk < 2; ++kk)
      #pragma unroll
      for (int mi = 0; mi < 4; ++mi)
        #pragma unroll
        for (int ni = 0; ni < 2; ++ni)
          acc[mi][2 + ni] = __builtin_amdgcn_mfma_f32_16x16x32_bf16(
              av[kk][mi], bv1[kk][ni], acc[mi][2 + ni], 0, 0, 0);
    __builtin_amdgcn_s_setprio(0);

    STAGE2(bc ^ 1, kt, 2);
    // ---- P2: read av(mh=1); MFMA (1,0) using bv0 ----
    #pragma unroll
    for (int kk = 0; kk < 2; ++kk)
      #pragma unroll
      for (int mi = 0; mi < 4; ++mi) {
        const int row = wrm * 128 + 64 + mi * 16 + fr;
        av[kk][mi] = *(const short8*)&la[row * BK + ((((kk << 2) | g) ^ (fr & 7)) << 3)];
      }
    asm volatile("s_waitcnt lgkmcnt(0)" ::: "memory");
    __builtin_amdgcn_sched_barrier(0);
    __builtin_amdgcn_s_setprio(1);
    #pragma unroll
    for (int kk = 0; kk < 2; ++kk)
      #pragma unroll
      for (int mi = 0; mi < 4; ++mi)
        #pragma unroll
        for (int ni = 0; ni < 2; ++ni)
          acc[4 + mi][ni] = __builtin_amdgcn_mfma_f32_16x16x32_bf16(
              av[kk][mi], bv0[kk][ni], acc[4 + mi][ni], 0, 0, 0);
    __builtin_amdgcn_s_setprio(0);

    STAGE2(bc ^ 1, kt, 3);
    // ---- P3: MFMA (1,1) using av(mh=1), bv1 ----
    __builtin_amdgcn_s_setprio(1);
    #pragma unroll
    for (int kk = 0; kk < 2; ++kk)
      #pragma unroll
      for (int mi = 0; mi < 4; ++mi)
        #pragma unroll
        for (int ni = 0; ni < 2; ++ni)
          acc[4 + mi][2 + ni] = __builtin_amdgcn_mfma_f32_16x16x32_bf16(
              av[kk][mi], bv1[kk][ni], acc[4 + mi][2 + ni], 0, 0, 0);
    __builtin_amdgcn_s_setprio(0);
    __builtin_amdgcn_s_barrier();   // all waves done reading buf bc
    bc ^= 1;
  }

  // epilogue: C/D layout col=lane&15, row=(lane>>4)*4+reg
  #pragma unroll
  for (int NJ = 0; NJ < 4; ++NJ) {
    const int col = bn + wcn * 64 + NJ * 16 + fr;
    const float bcol = bias[col];
    #pragma unroll
    for (int MI = 0; MI < 8; ++MI) {
      #pragma unroll
      for (int j = 0; j < 4; ++j) {
        const int rowg = bm + wrm * 128 + MI * 16 + (g << 2) + j;
        float v = fmaxf(acc[MI][NJ][j] + bcol, 0.f);   // bias + ReLU
        C[(size_t)rowg * N + col] = f2bf(v);
      }
    }
  }
}

// ===== fused prep (one launch, block ranges): =====
__global__ __launch_bounds__(256) void prep_kernel(
    const float* __restrict__ x, unsigned short* __restrict__ A2,
    unsigned short* __restrict__ xb,
    const float* __restrict__ Wq, const float* __restrict__ Wk,
    unsigned short* __restrict__ B2r,
    const float* __restrict__ Wv, const float* __restrict__ Wo,
    const float* __restrict__ W1, const float* __restrict__ W2,
    unsigned short* __restrict__ Wvt, unsigned short* __restrict__ Wot,
    unsigned short* __restrict__ W1t, unsigned short* __restrict__ W2t) {
  const int bid = blockIdx.x;
  __shared__ float tile[32][33];
  if (bid < 4096) {
    const int i = (bid * 256 + threadIdx.x) * 4;
    const int m = i / D, k = i % D;
    const float4 v = *(const float4*)(x + i);
    ushort4 hi, lo, bb;
    hi.x = f2h(v.x); lo.x = f2h(v.x - h2f(hi.x)); bb.x = f2bf(v.x);
    hi.y = f2h(v.y); lo.y = f2h(v.y - h2f(hi.y)); bb.y = f2bf(v.y);
    hi.z = f2h(v.z); lo.z = f2h(v.z - h2f(hi.z)); bb.z = f2bf(v.z);
    hi.w = f2h(v.w); lo.w = f2h(v.w - h2f(hi.w)); bb.w = f2bf(v.w);
    unsigned short* row = A2 + (size_t)m * LDA2;
    *(ushort4*)(row + k)     = hi;
    *(ushort4*)(row + D + k) = lo;
    *(ushort4*)(xb + i) = bb;
    return;
  }
  const int tx = threadIdx.x & 31, ty = threadIdx.x >> 5;
  if (bid < 6144) {
    const int t = bid - 4096;
    const int z = t >> 10;
    const float* W = z ? Wk : Wq;
    unsigned short* outb = B2r + (size_t)z * D * LD3;
    const int bx = ((t & 1023) & 31) * 32;
    const int by = ((t & 1023) >> 5) * 32;
    #pragma unroll
    for (int i = ty; i < 32; i += 8)
      tile[i][tx] = W[(size_t)(by + i) * D + bx + tx];
    __syncthreads();
    #pragma unroll
    for (int i = ty; i < 32; i += 8) {
      const float v = tile[tx][i];
      const unsigned short hi = f2h(v);
      const unsigned short lo = f2h(v - h2f(hi));
      unsigned short* r = outb + (size_t)(bx + i) * LD3 + (by + tx);
      r[0]     = hi;
      r[D]     = lo;
      r[2 * D] = hi;
    }
    return;
  }
  const int tb = bid - 6144;
  const float* W; unsigned short* Wt; int K, N, t;
  if (tb < 1024)      { W = Wv; Wt = Wvt; K = D;   N = D;   t = tb; }
  else if (tb < 2048) { W = Wo; Wt = Wot; K = D;   N = D;   t = tb - 1024; }
  else if (tb < 6144) { W = W1; Wt = W1t; K = D;   N = FFD; t = tb - 2048; }
  else                { W = W2; Wt = W2t; K = FFD; N = D;   t = tb - 6144; }
  const int nx = N / 32;
  const int bx = (t % nx) * 32;
  const int by = (t / nx) * 32;
  #pragma unroll
  for (int i = ty; i < 32; i += 8)
    tile[i][tx] = W[(size_t)(by + i) * N + bx + tx];
  __syncthreads();
  #pragma unroll
  for (int i = ty; i < 32; i += 8)
    Wt[(size_t)(bx + i) * K + by + tx] = f2bf(tile[tx][i]);
}

// ------------- M[b,h,l] = max_s(Q[l]·K[idx[l,s]]) - sum_s(...)/L ------------
__global__ __launch_bounds__(256) void prob_m_kernel(
    const float* __restrict__ QK, const int* __restrict__ idx,
    float* __restrict__ M_) {
  const int combo = blockIdx.x;
  const int b = combo >> 2, hg = combo & 3;
  const int l = blockIdx.y;
  const int tid = threadIdx.x;
  const int wave = tid >> 6;
  const int lane = tid & 63;
  const int h = hg * 4 + wave;
  __shared__ int sidx[S];
  if (tid < S) sidx[tid] = idx[l * S + tid];
  __syncthreads();
  const int dsub = (lane & 15) * 4;
  const int sgrp = lane >> 4;
  const float4 q = *(const float4*)(QK + ((size_t)b * L + l) * LD2 + h * DH + dsub);
  float mx = -INFINITY, sm = 0.f;
  for (int s = sgrp; s < S; s += 4) {
    const float4 kv = *(const float4*)(QK + ((size_t)b * L + sidx[s]) * LD2 + D + h * DH + dsub);
    float p = q.x*kv.x + q.y*kv.y + q.z*kv.z + q.w*kv.w;
    p += __shfl_xor(p, 1);
    p += __shfl_xor(p, 2);
    p += __shfl_xor(p, 4);
    p += __shfl_xor(p, 8);
    mx = fmaxf(mx, p);
    sm += p;
  }
  mx = fmaxf(mx, __shfl_xor(mx, 16));
  mx = fmaxf(mx, __shfl_xor(mx, 32));
  sm += __shfl_xor(sm, 16);
  sm += __shfl_xor(sm, 32);
  if (lane == 0)
    M_[((size_t)b * H + h) * L + l] = mx - sm / (float)L;
}

// ---- exact top-k (k=40, n=2048): single wave, register-resident, no LDS ----
__global__ __launch_bounds__(64) void topk_kernel(
    const float* __restrict__ M_, int* __restrict__ Mtop) {
  const int bh = blockIdx.x;
  const float* row = M_ + (size_t)bh * L;
  const int lane = threadIdx.x;
  float v[32];
  #pragma unroll
  for (int k = 0; k < 32; ++k) v[k] = row[k * 64 + lane];
  for (int u = 0; u < U; ++u) {
    float best = v[0]; int bk = 0;
    #pragma unroll
    for (int k = 1; k < 32; ++k)
      if (v[k] > best) { best = v[k]; bk = k; }
    int bidx = bk * 64 + lane;
    #pragma unroll
    for (int off = 1; off < 64; off <<= 1) {
      const float ov = __shfl_xor(best, off);
      const int   oi = __shfl_xor(bidx, off);
      if (ov > best || (ov == best && oi < bidx)) { best = ov; bidx = oi; }
    }
    if (lane == 0) Mtop[bh * U + u] = bidx;
    if ((bidx & 63) == lane) {
      const int kk = bidx >> 6;
      #pragma unroll
      for (int k = 0; k < 32; ++k) if (k == kk) v[k] = -INFINITY;
    }
  }
}

// ------- attn phase 1: per (b,h,jc) partial softmax + PV over 128 keys ------
__global__ __launch_bounds__(320) void attn_p1_kernel(
    const float* __restrict__ QK, const unsigned short* __restrict__ V16,
    const int* __restrict__ Mtop,
    float* __restrict__ pmax, float* __restrict__ psum, float* __restrict__ pv) {
  const int jc = blockIdx.x, h = blockIdx.y, b = blockIdx.z;
  const int bh = b * H + h;
  const int tid = threadIdx.x;
  const int j0 = jc * JT;
  __shared__ float Qs[U][68];
  __shared__ float KVs[JT][68];
  __shared__ unsigned short ws[U][JT];

  for (int i = tid; i < U * 16; i += 320) {
    const int u = i >> 4, dq = (i & 15) << 2;
    const int row = Mtop[bh * U + u];
    *(float4*)&Qs[u][dq] =
        *(const float4*)(QK + ((size_t)b * L + row) * LD2 + h * DH + dq);
  }
  for (int i = tid; i < JT * 16; i += 320) {
    const int j = i >> 4, dq = (i & 15) << 2;
    *(float4*)&KVs[j][dq] =
        *(const float4*)(QK + ((size_t)b * L + j0 + j) * LD2 + D + h * DH + dq);
  }
  __syncthreads();

  const int u = tid >> 3, jg = tid & 7;
  const int mt = Mtop[bh * U + u];
  float sc[16];
  #pragma unroll
  for (int jt = 0; jt < 16; ++jt) sc[jt] = 0.f;
  for (int dq = 0; dq < 64; dq += 4) {
    const float4 q = *(const float4*)&Qs[u][dq];
    #pragma unroll
    for (int jt = 0; jt < 16; ++jt) {
      const float4 k = *(const float4*)&KVs[jt * 8 + jg][dq];
      sc[jt] += q.x*k.x + q.y*k.y + q.z*k.z + q.w*k.w;
    }
  }
  float m = -INFINITY;
  #pragma unroll
  for (int jt = 0; jt < 16; ++jt) {
    const int j = j0 + jt * 8 + jg;
    sc[jt] = (j <= mt) ? sc[jt] * 0.125f : -INFINITY;
    m = fmaxf(m, sc[jt]);
  }
  m = fmaxf(m, __shfl_xor(m, 1));
  m = fmaxf(m, __shfl_xor(m, 2));
  m = fmaxf(m, __shfl_xor(m, 4));
  float sum = 0.f;
  #pragma unroll
  for (int jt = 0; jt < 16; ++jt) {
    const float e = (sc[jt] == -INFINITY) ? 0.f : expf(sc[jt] - m);
    sum += e;
    ws[u][jt * 8 + jg] = f2bf(e);
  }
  sum += __shfl_xor(sum, 1);
  sum += __shfl_xor(sum, 2);
  sum += __shfl_xor(sum, 4);
  if (jg == 0) {
    pmax[(size_t)(bh * NJC + jc) * U + u] = m;
    psum[(size_t)(bh * NJC + jc) * U + u] = sum;
  }
  __syncthreads();
  for (int i = tid; i < JT * 8; i += 320) {
    const int j = i >> 3, d8 = (i & 7) << 3;
    short8 vv = *(const short8*)(V16 + ((size_t)b * L + j0 + j) * D + h * DH + d8);
    #pragma unroll
    for (int e = 0; e < 8; ++e)
      KVs[j][d8 + e] = bf2f((unsigned short)vv[e]);
  }
  __syncthreads();
  const int d = tid & 63, ug = tid >> 6;
  float acc[8] = {};
  for (int j = 0; j < JT; j += 2) {
    const float v0 = KVs[j][d], v1 = KVs[j + 1][d];
    #pragma unroll
    for (int k = 0; k < 8; ++k) {
      const int uu = ug + k * 5;
      const unsigned int wp = *(const unsigned int*)&ws[uu][j];
      acc[k] = fmaf(bf2f((unsigned short)(wp & 0xffff)), v0, acc[k]);
      acc[k] = fmaf(bf2f((unsigned short)(wp >> 16)), v1, acc[k]);
    }
  }
  #pragma unroll
  for (int k = 0; k < 8; ++k) {
    const int uu = ug + k * 5;
    pv[((size_t)(bh * NJC + jc) * U + uu) * DH + d] = acc[k];
  }
}

// -- attn phase 2: combine 16 chunks per (b,h,u), scatter into ctx16 (bf16) --
__global__ __launch_bounds__(64) void attn_p2_kernel(
    const float* __restrict__ pmax, const float* __restrict__ psum,
    const float* __restrict__ pv, const int* __restrict__ Mtop,
    unsigned short* __restrict__ ctx16) {
  const int bid = blockIdx.x;
  const int u = bid % U, bh = bid / U;
  const int d = threadIdx.x;
  float gmax = -INFINITY;
  for (int c = 0; c < NJC; ++c)
    gmax = fmaxf(gmax, pmax[(size_t)(bh * NJC + c) * U + u]);
  float den = 0.f, num = 0.f;
  for (int c = 0; c < NJC; ++c) {
    const float m = pmax[(size_t)(bh * NJC + c) * U + u];
    if (m == -INFINITY) continue;
    const float s = expf(m - gmax);
    den += psum[(size_t)(bh * NJC + c) * U + u] * s;
    num += pv[((size_t)(bh * NJC + c) * U + u) * DH + d] * s;
  }
  const int h = bh % H, b = bh / H;
  const int l = Mtop[bh * U + u];
  ctx16[((size_t)b * L + l) * D + h * DH + d] = f2bf(num / den);
}

// --------- cumsum(V16) over l: pass1 = per-chunk column sums only -----------
__global__ __launch_bounds__(256) void cumsum_pass1(
    const unsigned short* __restrict__ V16, float* __restrict__ csums) {
  const int cp = blockIdx.x * 256 + threadIdx.x;
  const int ch = blockIdx.y, b = blockIdx.z;
  size_t base = ((size_t)b * L + (size_t)ch * CHLEN) * D + cp * 2;
  float a0 = 0.f, a1 = 0.f;
  for (int i = 0; i < CHLEN; ++i) {
    const unsigned int u = *(const unsigned int*)(V16 + base + (size_t)i * D);
    a0 += bf2f((unsigned short)(u & 0xffff));
    a1 += bf2f((unsigned short)(u >> 16));
  }
  float* cs = csums + ((size_t)b * NCHUNK + ch) * D + cp * 2;
  cs[0] = a0; cs[1] = a1;
}

__global__ __launch_bounds__(256) void cumsum_pass2(
    const unsigned short* __restrict__ V16, const float* __restrict__ csums,
    unsigned short* __restrict__ ctx16) {
  const int cp = blockIdx.x * 256 + threadIdx.x;
  const int ch = blockIdx.y, b = blockIdx.z;
  float a0 = 0.f, a1 = 0.f;
  for (int j = 0; j < ch; ++j) {
    const float* cs = csums + ((size_t)b * NCHUNK + j) * D + cp * 2;
    a0 += cs[0]; a1 += cs[1];
  }
  size_t base = ((size_t)b * L + (size_t)ch * CHLEN) * D + cp * 2;
  for (int i = 0; i < CHLEN; ++i) {
    const size_t o = base + (size_t)i * D;
    const unsigned int u = *(const unsigned int*)(V16 + o);
    a0 += bf2f((unsigned short)(u & 0xffff));
    a1 += bf2f((unsigned short)(u >> 16));
    *(unsigned int*)(ctx16 + o) =
        (unsigned int)f2bf(a0) | ((unsigned int)f2bf(a1) << 16);
  }
}

// -- out = LayerNorm(a + r)*g + be; wave-per-row (4 rows/block, shfl reduce) -
template<bool ABF16>
__global__ __launch_bounds__(256) void add_ln_kernel(
    const void* __restrict__ a_, const unsigned short* __restrict__ r,
    const float* __restrict__ g, const float* __restrict__ be,
    float* __restrict__ out, unsigned short* __restrict__ out16) {
  const int row  = blockIdx.x * 4 + (threadIdx.x >> 6);
  const int lane = threadIdx.x & 63;
  float v[16];
  float s = 0.f;
  #pragma unroll
  for (int j = 0; j < 4; ++j) {
    const int c = j * 256 + lane * 4;
    float4 av;
    if (ABF16) {
      ushort4 ua = *(const ushort4*)((const unsigned short*)a_ + (size_t)row * D + c);
      av.x = bf2f(ua.x); av.y = bf2f(ua.y); av.z = bf2f(ua.z); av.w = bf2f(ua.w);
    } else {
      av = *(const float4*)((const float*)a_ + (size_t)row * D + c);
    }
    const ushort4 ur = *(const ushort4*)(r + (size_t)row * D + c);
    v[j*4+0] = av.x + bf2f(ur.x);
    v[j*4+1] = av.y + bf2f(ur.y);
    v[j*4+2] = av.z + bf2f(ur.z);
    v[j*4+3] = av.w + bf2f(ur.w);
    s += v[j*4+0] + v[j*4+1] + v[j*4+2] + v[j*4+3];
  }
  #pragma unroll
  for (int off = 1; off < 64; off <<= 1) s += __shfl_xor(s, off);
  const float mu = s / (float)D;
  float s2 = 0.f;
  #pragma unroll
  for (int k = 0; k < 16; ++k) { const float dv = v[k] - mu; s2 += dv * dv; }
  #pragma unroll
  for (int off = 1; off < 64; off <<= 1) s2 += __shfl_xor(s2, off);
  const float rstd = rsqrtf(s2 / (float)D + EPS);
  #pragma unroll
  for (int j = 0; j < 4; ++j) {
    const int c = j * 256 + lane * 4;
    const float4 gv = *(const float4*)(g + c);
    const float4 bv = *(const float4*)(be + c);
    float o0 = (v[j*4+0] - mu) * rstd * gv.x + bv.x;
    float o1 = (v[j*4+1] - mu) * rstd * gv.y + bv.y;
    float o2 = (v[j*4+2] - mu) * rstd * gv.z + bv.z;
    float o3 = (v[j*4+3] - mu) * rstd * gv.w + bv.w;
    if (out) {
      float4 ov; ov.x = o0; ov.y = o1; ov.z = o2; ov.w = o3;
      *(float4*)(out + (size_t)row * D + c) = ov;
    }
    if (out16) {
      ushort4 uo;
      uo.x = f2bf(o0); uo.y = f2bf(o1); uo.z = f2bf(o2); uo.w = f2bf(o3);
      *(ushort4*)(out16 + (size_t)row * D + c) = uo;
    }
  }
}

// ----------------------------------------------------------------------------
extern "C" void kernel_launch(void* const* d_in, const int* in_sizes, int n_in,
                              void* d_out, int out_size, void* d_ws, size_t ws_size,
                              hipStream_t stream) {
  const float* x   = (const float*)d_in[0];
  const float* Wq  = (const float*)d_in[1];
  const float* bq  = (const float*)d_in[2];
  const float* Wk  = (const float*)d_in[3];
  const float* bk  = (const float*)d_in[4];
  const float* Wv  = (const float*)d_in[5];
  const float* bv  = (const float*)d_in[6];
  const float* Wo  = (const float*)d_in[7];
  const float* bo  = (const float*)d_in[8];
  const float* g1  = (const float*)d_in[9];
  const float* be1 = (const float*)d_in[10];
  const float* W1  = (const float*)d_in[11];
  const float* b1  = (const float*)d_in[12];
  const float* W2  = (const float*)d_in[13];
  const float* b2  = (const float*)d_in[14];
  const float* g2  = (const float*)d_in[15];
  const float* be2 = (const float*)d_in[16];
  const int*   idx = (const int*)d_in[17];
  float* out = (float*)d_out;

  char* p = (char*)d_ws;
  unsigned short* A2     = (unsigned short*)p;
  unsigned short* AO16   = (unsigned short*)p;
  unsigned short* ff2_16 = (unsigned short*)(p + 8388608);
  unsigned short* xb    = (unsigned short*)(p + 16777216);
  unsigned short* ctx16 = (unsigned short*)(p + 16777216);
  unsigned short* B2 = (unsigned short*)(p + 25165824);
  char* scr = p + 25165824;
  float* Mbuf   = (float*)(scr);
  float* csum   = (float*)(scr + 262144);
  int*   Mtop   = (int*)  (scr + 524288);
  float* pmax   = (float*)(scr + 532480);
  float* psum   = (float*)(scr + 614400);
  float* pv     = (float*)(scr + 696320);
  float*          QKb = (float*)(p + 37748736);
  unsigned short* x1b = (unsigned short*)(p + 54525952);
  unsigned short* ff1b = (unsigned short*)(p + 62914560);
  unsigned short* Vb16 = (unsigned short*)(p + 96468992);
  unsigned short* Wvt = (unsigned short*)(p + 113246208);
  unsigned short* Wot = (unsigned short*)(p + 115343360);
  unsigned short* W1t = (unsigned short*)(p + 117440512);
  unsigned short* W2t = (unsigned short*)(p + 125829120);

  dim3 blk(256);
  const int M = B * L;   // 4096

  // 1) fused prep
  prep_kernel<<<16384, blk, 0, stream>>>(x, A2, xb, Wq, Wk, B2,
                                         Wv, Wo, W1, W2, Wvt, Wot, W1t, W2t);
  // 2) QK via f16 3-term split (fp32-accurate, selection-safe), A-dedup
  gemm_kernel<128,2,false,false,true,true><<<dim3(LD2/128, M/128), blk, 0, stream>>>(
      A2, B2, bq, bk, QKb, M, LD2, LD3, LDA2);
  // 3) V projection -> bf16
  gemm_kernel<64,3,false,true,false,false><<<dim3(D/64, M/128), blk, 0, stream>>>(
      xb, Wvt, bv, bv, Vb16, M, D, D, D);
  // 4-6) ProbSparse attention scoring
  prob_m_kernel<<<dim3(8, L), blk, 0, stream>>>(QKb, idx, Mbuf);
  topk_kernel<<<B*H, dim3(64), 0, stream>>>(Mbuf, Mtop);
  attn_p1_kernel<<<dim3(NJC, H, B), dim3(320), 0, stream>>>(QKb, Vb16, Mtop, pmax, psum, pv);
  // 7) context = cumsum(V)
  cumsum_pass1<<<dim3(D/512, NCHUNK, B), blk, 0, stream>>>(Vb16, csum);
  cumsum_pass2<<<dim3(D/512, NCHUNK, B), blk, 0, stream>>>(Vb16, csum, ctx16);
  // 8) attn combine + scatter
  attn_p2_kernel<<<B*H*U, dim3(64), 0, stream>>>(pmax, psum, pv, Mtop, ctx16);
  // 9) output projection -> bf16 AO
  gemm_kernel<64,3,false,true,false,false><<<dim3(D/64, M/128), blk, 0, stream>>>(
      ctx16, Wot, bo, bo, AO16, M, D, D, D);
  // 10) LN1 -> bf16 residual
  add_ln_kernel<false><<<B*L/4, blk, 0, stream>>>(x, AO16, g1, be1, nullptr, x1b);
  // 11) FF1 via 8-phase 256x256 (bias+ReLU, bf16 out)
  gemm_ff1_8ph_kernel<<<dim3(FFD/256, M/256), dim3(512), 0, stream>>>(
      x1b, W1t, b1, ff1b, M, FFD, D);
  // 12) FF2 -> bf16
  gemm_kernel<64,3,false,true,false,false><<<dim3(D/64, M/128), blk, 0, stream>>>(
      ff1b, W2t, b2, b2, ff2_16, M, D, FFD, FFD);
  // 13) LN2 -> f32 out
  add_ln_kernel<true><<<B*L/4, blk, 0, stream>>>(x1b, ff2_16, g2, be2, out,
                                                 (unsigned short*)nullptr);
}